// Round 14
// baseline (270.049 us; speedup 1.0000x reference)
//
#include <hip/hip_runtime.h>
#include <math.h>

typedef unsigned short u16;
using us4  = __attribute__((ext_vector_type(4))) unsigned short;
using us8  = __attribute__((ext_vector_type(8))) unsigned short;
using bf16x8 = __attribute__((ext_vector_type(8))) __bf16;
using f32x4v = __attribute__((ext_vector_type(4))) float;

// Problem constants
#define T_    1024
#define H_    2048
#define HK_   8
#define HV_   16
#define KD_   1024
#define VD_   2048
#define CD_   4096
#define QN_   6144   // 2*KD + 2*VD
#define NC_   16     // number of chunks
#define C_    64     // chunk length

__device__ __forceinline__ u16 f2bf(float f) {
  unsigned u = __float_as_uint(f);
  u += 0x7fffu + ((u >> 16) & 1u);   // RNE
  return (u16)(u >> 16);
}
__device__ __forceinline__ float bf2f(u16 h) {
  return __uint_as_float(((unsigned)h) << 16);
}
// staging layout for gemm: within each 64-elem k-group, 8-elem chunk c of
// row r is stored at chunk position c ^ (r&7).
__device__ __forceinline__ int permk3(int r, int k) {
  return (k & ~63) | ((((k >> 3) & 7) ^ (r & 7)) << 3) | (k & 7);
}

// ---------------------------------------------------------------------------
// x f32 -> bf16 with chunk permutation (row length 2048)
// ---------------------------------------------------------------------------
__global__ void cast_bf16(const float* __restrict__ in, u16* __restrict__ out,
                          int n8) {
  int i = blockIdx.x * 256 + threadIdx.x;   // 16B-chunk index
  if (i >= n8) return;
  float4 a = ((const float4*)in)[i * 2];
  float4 b = ((const float4*)in)[i * 2 + 1];
  us8 r = {f2bf(a.x), f2bf(a.y), f2bf(a.z), f2bf(a.w),
           f2bf(b.x), f2bf(b.y), f2bf(b.z), f2bf(b.w)};
  const int row = i >> 8;                   // 2048/8 = 256 chunks per row
  const int ip = (i & ~7) | ((i & 7) ^ (row & 7));
  *(us8*)&out[(size_t)ip * 8] = r;
}

// ---------------------------------------------------------------------------
// f32 [R][C] -> bf16 [C][R] transpose + cast + chunk permutation
// ---------------------------------------------------------------------------
__global__ __launch_bounds__(256) void transpose_bf16(
    const float* __restrict__ in, u16* __restrict__ out, int R, int C) {
  __shared__ float tile[64][65];
  const int r0 = blockIdx.x * 64, c0 = blockIdx.y * 64;
  const int t = threadIdx.x;
  const int tr = t >> 4, tc4 = (t & 15) * 4;
#pragma unroll
  for (int i = 0; i < 4; ++i) {
    float4 v = *(const float4*)&in[(size_t)(r0 + tr + i * 16) * C + c0 + tc4];
    tile[tr + i * 16][tc4 + 0] = v.x;
    tile[tr + i * 16][tc4 + 1] = v.y;
    tile[tr + i * 16][tc4 + 2] = v.z;
    tile[tr + i * 16][tc4 + 3] = v.w;
  }
  __syncthreads();
#pragma unroll
  for (int i = 0; i < 4; ++i) {
    int oc = tr + i * 16;
    int row = c0 + oc;
    int k = r0 + tc4;
    us4 w = {f2bf(tile[tc4 + 0][oc]), f2bf(tile[tc4 + 1][oc]),
             f2bf(tile[tc4 + 2][oc]), f2bf(tile[tc4 + 3][oc])};
    *(us4*)&out[(size_t)row * R + permk3(row, k)] = w;
  }
}

// ---------------------------------------------------------------------------
// bf16 MFMA GEMM: C = A[M,K] @ Bt[N,K]^T, f32 out. 128x64 tile, BK=64,
// 3-buffer counted-vmcnt pipeline (T4: never drain to 0 mid-loop),
// XCD-grouped 1D block mapping, 3-bit permuted staging.
// Output routed to Cq (cols < zsplit) or Cz.
// ---------------------------------------------------------------------------
__device__ __forceinline__ void gload_lds16(const void* g, void* l) {
  __builtin_amdgcn_global_load_lds(
      (const __attribute__((address_space(1))) void*)g,
      (__attribute__((address_space(3))) void*)l, 16, 0, 0);
}

__global__ __launch_bounds__(256) void gemm_bf16(
    const u16* __restrict__ A, const u16* __restrict__ Bt,
    float* __restrict__ Cq, int ldq, float* __restrict__ Cz, int ldz,
    int zsplit, int M, int N, int K) {
  __shared__ __align__(16) u16 As[3][8192];   // [128][64] x3
  __shared__ __align__(16) u16 Bs[3][4096];   // [64][64] x3
  const int tid  = threadIdx.x;
  const int wave = tid >> 6, lane = tid & 63;
  const int gy = N >> 6;
  const int ncolpx = gy >> 3;
  const int bid = blockIdx.x;
  const int xcd = bid & 7, idx = bid >> 3;
  const int row0 = (idx / ncolpx) * 128;
  const int col0 = (xcd * ncolpx + idx % ncolpx) * 64;
  const int wr = wave >> 1, wc = wave & 1;
  const int fr = lane & 15, fq = lane >> 4;

  const int sr8 = lane >> 3;
  const int sc8 = (lane & 7) * 8;
  const u16* gA = A  + (size_t)(row0 + wave * 32 + sr8) * K + sc8;
  const u16* gB = Bt + (size_t)(col0 + wave * 16 + sr8) * K + sc8;

  f32x4v acc[4][2] = {};
  const int nt = K >> 6;

  // one stage issues exactly 6 global_load_lds per wave (4 A + 2 B)
  auto stage = [&](int p, int k0) {
#pragma unroll
    for (int j = 0; j < 4; ++j)
      gload_lds16(gA + (size_t)(j * 8) * K + k0,
                  &As[p][(wave * 32 + j * 8) * 64]);
#pragma unroll
    for (int j = 0; j < 2; ++j)
      gload_lds16(gB + (size_t)(j * 8) * K + k0,
                  &Bs[p][(wave * 16 + j * 8) * 64]);
  };

  stage(0, 0);
  if (nt > 1) stage(1, 64);

  for (int it = 0; it < nt; ++it) {
    if (it + 2 < nt) stage((it + 2) % 3, (it + 2) * 64);
    // counted wait: tile `it`'s 6 loads done; up to 12 (tiles it+1, it+2)
    // stay in flight across the barrier (T4 idiom).
    if (it + 2 < nt)      asm volatile("s_waitcnt vmcnt(12)" ::: "memory");
    else if (it + 1 < nt) asm volatile("s_waitcnt vmcnt(6)" ::: "memory");
    else                  asm volatile("s_waitcnt vmcnt(0)" ::: "memory");
    __builtin_amdgcn_s_barrier();

    const int p = it % 3;
#pragma unroll
    for (int kt = 0; kt < 2; ++kt) {
      bf16x8 af[4], bff[2];
#pragma unroll
      for (int mi = 0; mi < 4; ++mi) {
        const int r = wr * 64 + mi * 16 + fr;
        af[mi] = *(const bf16x8*)
            &As[p][r * 64 + kt * 32 + (((kt * 4 + fq) ^ (r & 7)) & 3) * 8
                   + ((((kt * 4 + fq) ^ (r & 7)) >> 2) - kt) * 32];
      }
#pragma unroll
      for (int ni = 0; ni < 2; ++ni) {
        const int r = wc * 32 + ni * 16 + fr;
        bff[ni] = *(const bf16x8*)
            &Bs[p][r * 64 + kt * 32 + (((kt * 4 + fq) ^ (r & 7)) & 3) * 8
                   + ((((kt * 4 + fq) ^ (r & 7)) >> 2) - kt) * 32];
      }
#pragma unroll
      for (int mi = 0; mi < 4; ++mi)
#pragma unroll
        for (int ni = 0; ni < 2; ++ni)
          acc[mi][ni] = __builtin_amdgcn_mfma_f32_16x16x32_bf16(
              af[mi], bff[ni], acc[mi][ni], 0, 0, 0);
    }
    // protect buffer (it)%3: iter it+1 stages tile it+3 into buf (it)%3
    if (it + 1 < nt) __builtin_amdgcn_s_barrier();
  }

  float* Cp; int ldc, cb;
  if (col0 < zsplit) { Cp = Cq; ldc = ldq; cb = col0; }
  else               { Cp = Cz; ldc = ldz; cb = col0 - zsplit; }
#pragma unroll
  for (int mi = 0; mi < 4; ++mi)
#pragma unroll
    for (int ni = 0; ni < 2; ++ni) {
      const int r  = row0 + wr * 64 + mi * 16 + fq * 4;
      const int cc = cb + wc * 32 + ni * 16 + fr;
#pragma unroll
      for (int j = 0; j < 4; ++j)
        Cp[(size_t)(r + j) * ldc + cc] = acc[mi][ni][j];
    }
}

// ---------------------------------------------------------------------------
// ba = x @ w_ba -> beta = sigmoid(b), g = -exp(a_log)*softplus(a+dt_bias)
// ---------------------------------------------------------------------------
__global__ __launch_bounds__(256) void ba_gbeta(
    const float* __restrict__ x, const float* __restrict__ w_ba,
    const float* __restrict__ a_log, const float* __restrict__ dt_bias,
    float* __restrict__ g, float* __restrict__ beta) {
  const int t = blockIdx.x;
  const int tid = threadIdx.x;
  __shared__ float xs[2048];
  __shared__ float red[8][32];
  {
    float4 v = *(const float4*)&x[(size_t)t * H_ + tid * 4];
    *(float4*)&xs[tid * 4] = v;
    float4 w = *(const float4*)&x[(size_t)t * H_ + 1024 + tid * 4];
    *(float4*)&xs[1024 + tid * 4] = w;
  }
  __syncthreads();
  const int c = tid & 31;
  const int chunk = tid >> 5;
  float p = 0.f;
  const int kb = chunk * 256;
#pragma unroll 4
  for (int k = kb; k < kb + 256; ++k) p = fmaf(xs[k], w_ba[k * 32 + c], p);
  red[chunk][c] = p;
  __syncthreads();
  if (tid < 32) {
    float s = 0.f;
#pragma unroll
    for (int i = 0; i < 8; ++i) s += red[i][c];
    if (c < 16) {
      beta[t * 16 + c] = 1.f / (1.f + expf(-s));
    } else {
      int h = c - 16;
      float xx = s + dt_bias[h];
      float sp = xx > 20.f ? xx : log1pf(expf(xx));
      g[t * 16 + h] = -expf(a_log[h]) * sp;
    }
  }
}

// ---------------------------------------------------------------------------
// fused causal depthwise conv1d (K=4) + SiLU + k-l2norm.
// ---------------------------------------------------------------------------
__global__ __launch_bounds__(512) void conv_silu_k(
    const float* __restrict__ qkvraw, const float* __restrict__ conv_w,
    const float* __restrict__ conv_b, float* __restrict__ qkvc,
    float* __restrict__ khat) {
  const int t = blockIdx.x;
  const int tid = threadIdx.x;
  const int c0 = tid * 8;
  float acc[8];
  float4 cb0 = *(const float4*)&conv_b[c0];
  float4 cb1 = *(const float4*)&conv_b[c0 + 4];
  acc[0] = cb0.x; acc[1] = cb0.y; acc[2] = cb0.z; acc[3] = cb0.w;
  acc[4] = cb1.x; acc[5] = cb1.y; acc[6] = cb1.z; acc[7] = cb1.w;
  float wv[8][4];
#pragma unroll
  for (int i = 0; i < 8; i += 2) {
    float4 w0 = *(const float4*)&conv_w[(c0 + i) * 4];
    float4 w1 = *(const float4*)&conv_w[(c0 + i + 1) * 4];
    wv[i][0] = w0.x; wv[i][1] = w0.y; wv[i][2] = w0.z; wv[i][3] = w0.w;
    wv[i+1][0] = w1.x; wv[i+1][1] = w1.y; wv[i+1][2] = w1.z; wv[i+1][3] = w1.w;
  }
#pragma unroll
  for (int j = 0; j < 4; ++j) {
    int tt = t - 3 + j;
    if (tt >= 0) {
      float4 a = *(const float4*)&qkvraw[(size_t)tt * CD_ + c0];
      float4 b = *(const float4*)&qkvraw[(size_t)tt * CD_ + c0 + 4];
      float xv[8] = {a.x, a.y, a.z, a.w, b.x, b.y, b.z, b.w};
#pragma unroll
      for (int i = 0; i < 8; ++i) acc[i] = fmaf(xv[i], wv[i][j], acc[i]);
    }
  }
  float y[8];
#pragma unroll
  for (int i = 0; i < 8; ++i) y[i] = acc[i] / (1.f + expf(-acc[i]));

  if (tid < 128 || tid >= 256) {
    float4 o0 = {y[0], y[1], y[2], y[3]};
    float4 o1 = {y[4], y[5], y[6], y[7]};
    *(float4*)&qkvc[(size_t)t * CD_ + c0]     = o0;
    *(float4*)&qkvc[(size_t)t * CD_ + c0 + 4] = o1;
  } else {
    float ss = 0.f;
#pragma unroll
    for (int i = 0; i < 8; ++i) ss = fmaf(y[i], y[i], ss);
#pragma unroll
    for (int off = 1; off < 16; off <<= 1) ss += __shfl_xor(ss, off);
    float rs = rsqrtf(ss + 1e-6f);
    const int head = (c0 - 1024) >> 7;
    const int d0 = (c0 - 1024) & 127;
    float4 o0 = {y[0] * rs, y[1] * rs, y[2] * rs, y[3] * rs};
    float4 o1 = {y[4] * rs, y[5] * rs, y[6] * rs, y[7] * rs};
    float* kout = &khat[((size_t)t * HK_ + head) * 128 + d0];
    *(float4*)&kout[0] = o0;
    *(float4*)&kout[4] = o1;
  }
}

// ---------------------------------------------------------------------------
// Chunked gated delta rule, phase A (parallel over 16 chunks x 16 heads).
// 512 threads (8 waves). Dot phase 4x2 tiles/thread; during the serial
// forward substitution (waves 0-3), waves 4-7 write Mqg and pQg.
// ---------------------------------------------------------------------------
#define SWZ(r) (((r) >> 2) & 7)

__device__ __forceinline__ float4 ldsw4(const float* base, int r, int dblk) {
  return *(const float4*)&base[r * 128 + ((dblk ^ SWZ(r)) << 2)];
}
__device__ __forceinline__ float ldsw1(const float* base, int r, int d) {
  return base[r * 128 + ((((d) >> 2) ^ SWZ(r)) << 2) + ((d) & 3)];
}

__global__ __launch_bounds__(512) void chunk_prep(
    const float* __restrict__ qkvc, const float* __restrict__ khat,
    const float* __restrict__ g, const float* __restrict__ beta,
    float* __restrict__ cgbuf, float* __restrict__ Wtg, float* __restrict__ Ug,
    float* __restrict__ Mqg, float* __restrict__ pQg) {
  const int c = blockIdx.x, hv = blockIdx.y, hk = hv >> 1;
  const int cid = c * 16 + hv;
  const int tid = threadIdx.x;
  __shared__ float Kl[8192], Ql[8192];   // swizzled [64][128]
  __shared__ float AM[8320];             // At[64][65] | Mq[64][65]; later Utr
  __shared__ float cgl[64], bl[64], bp[64], rsl[64];
  float* At = AM;
  float* Mq = AM + 4160;

#pragma unroll
  for (int it = 0; it < 4; ++it) {
    int flat = it * 2048 + tid * 4;
    int row = flat >> 7, d = flat & 127;
    int pb = ((d >> 2) ^ SWZ(row)) << 2;
    int gt = c * 64 + row;
    float4 kv = *(const float4*)&khat[((size_t)gt * HK_ + hk) * 128 + d];
    float4 qv = *(const float4*)&qkvc[(size_t)gt * CD_ + hk * 128 + d];
    *(float4*)&Kl[row * 128 + pb] = kv;
    *(float4*)&Ql[row * 128 + pb] = qv;
  }
  if (tid < 64) {
    float s = g[(size_t)(c * 64 + tid) * HV_ + hv];
#pragma unroll
    for (int off = 1; off < 64; off <<= 1) {
      float t = __shfl_up(s, off);
      if (tid >= off) s += t;
    }
    cgl[tid] = s;
    cgbuf[cid * 64 + tid] = s;
    bl[tid] = beta[(size_t)(c * 64 + tid) * HV_ + hv];
  }
  __syncthreads();
  if (tid < 64) {
    float sq = 0.f;
#pragma unroll
    for (int dblk = 0; dblk < 32; ++dblk) {
      float4 q4 = ldsw4(Ql, tid, dblk);
      sq = fmaf(q4.x, q4.x, sq); sq = fmaf(q4.y, q4.y, sq);
      sq = fmaf(q4.z, q4.z, sq); sq = fmaf(q4.w, q4.w, sq);
    }
    rsl[tid] = rsqrtf(sq + 1e-6f) * 0.08838834764831845f;
    bp[tid] = bl[tid] * expf(cgl[tid]);
  }
  __syncthreads();

  // dot phase: 4x2 tile of (i,j) pairs per thread (512 threads)
  const int i0 = (tid >> 5) * 4, j0 = (tid & 31) * 2;
  float kk[4][2], qk[4][2];
#pragma unroll
  for (int a = 0; a < 4; ++a)
#pragma unroll
    for (int b = 0; b < 2; ++b) { kk[a][b] = 0.f; qk[a][b] = 0.f; }
  for (int dblk = 0; dblk < 32; ++dblk) {
    float4 ka[4], qa[4], kb[2];
#pragma unroll
    for (int a = 0; a < 4; ++a) {
      ka[a] = ldsw4(Kl, i0 + a, dblk);
      qa[a] = ldsw4(Ql, i0 + a, dblk);
    }
#pragma unroll
    for (int b = 0; b < 2; ++b) kb[b] = ldsw4(Kl, j0 + b, dblk);
#pragma unroll
    for (int a = 0; a < 4; ++a)
#pragma unroll
      for (int b = 0; b < 2; ++b) {
        kk[a][b] = fmaf(ka[a].x, kb[b].x, kk[a][b]);
        kk[a][b] = fmaf(ka[a].y, kb[b].y, kk[a][b]);
        kk[a][b] = fmaf(ka[a].z, kb[b].z, kk[a][b]);
        kk[a][b] = fmaf(ka[a].w, kb[b].w, kk[a][b]);
        qk[a][b] = fmaf(qa[a].x, kb[b].x, qk[a][b]);
        qk[a][b] = fmaf(qa[a].y, kb[b].y, qk[a][b]);
        qk[a][b] = fmaf(qa[a].z, kb[b].z, qk[a][b]);
        qk[a][b] = fmaf(qa[a].w, kb[b].w, qk[a][b]);
      }
  }
#pragma unroll
  for (int a = 0; a < 4; ++a)
#pragma unroll
    for (int b = 0; b < 2; ++b) {
      int i = i0 + a, j = j0 + b;
      float e = expf(cgl[i] - cgl[j]);
      At[j * 65 + i] = (j < i) ? (-bl[i] * e * kk[a][b]) : 0.f;
      Mq[j * 65 + i] = (j <= i) ? (rsl[i] * e * qk[a][b]) : 0.f;
    }
  __syncthreads();

  float X[64];
  if (tid < 256) {
    // ---- waves 0-3: X init + forward substitution ----
    if (tid < 128) {
#pragma unroll
      for (int j = 0; j < 64; ++j) X[j] = bp[j] * ldsw1(Kl, j, tid);
    } else {
      const int m = tid - 128;
#pragma unroll
      for (int j = 0; j < 64; ++j)
        X[j] = bl[j] * qkvc[(size_t)(c * 64 + j) * CD_ + 2 * KD_ + hv * 128 + m];
    }
#pragma unroll
    for (int j = 0; j < 63; ++j) {
      float xj = X[j];
#pragma unroll
      for (int i = j + 1; i < 64; ++i) X[i] = fmaf(At[j * 65 + i], xj, X[i]);
    }
    if (tid < 128) {
      size_t baseo = ((size_t)cid * 128 + tid) * 64;
#pragma unroll
      for (int j4 = 0; j4 < 16; ++j4) {
        float4 v = {X[j4 * 4], X[j4 * 4 + 1], X[j4 * 4 + 2], X[j4 * 4 + 3]};
        *(float4*)&Wtg[baseo + j4 * 4] = v;
      }
    }
  } else {
    // ---- waves 4-7: Mqg + pQg writes (independent of solve) ----
    const int t2 = tid - 256;
#pragma unroll
    for (int it = 0; it < 16; ++it) {
      int f = it * 256 + t2;
      int j = f >> 6, i = f & 63;
      Mqg[(size_t)cid * 4096 + f] = Mq[j * 65 + i];
    }
    const int i = t2 & 63;
    const float ei = expf(cgl[i]) * rsl[i];
#pragma unroll
    for (int it = 0; it < 32; ++it) {
      int d = it * 4 + (t2 >> 6);
      pQg[(size_t)cid * 8192 + d * 64 + i] = ei * ldsw1(Ql, i, d);
    }
  }
  __syncthreads();   // At/Mq dead; X (U cols) ready

  if (tid >= 128 && tid < 256) {
    const int m = tid - 128;
    float* Utr = AM;
#pragma unroll
    for (int j = 0; j < 64; ++j) Utr[j * 128 + m] = X[j];
  }
  __syncthreads();
  {
    const float* Utr = AM;
#pragma unroll
    for (int it = 0; it < 4; ++it) {
      int flat = it * 2048 + tid * 4;
      *(float4*)&Ug[(size_t)cid * 8192 + flat] = *(const float4*)&Utr[flat];
    }
  }
}

// ---------------------------------------------------------------------------
// make_MBG (parallel, 256 blocks, 512 threads)
// ---------------------------------------------------------------------------
__global__ __launch_bounds__(512) void make_MBG(
    const float* __restrict__ Wtg, const float* __restrict__ pQg,
    const float* __restrict__ Ug, const float* __restrict__ Mqg,
    const float* __restrict__ khat, const float* __restrict__ cgbuf,
    u16* __restrict__ Mhi, u16* __restrict__ Mlo,
    float* __restrict__ Bg, float* __restrict__ Gtg) {
  const int c = blockIdx.x, hv = blockIdx.y, hk = hv >> 1;
  const int cid = c * 16 + hv;
  const int tid = threadIdx.x;
  __shared__ float Wl[64 * 128];   // W[j][d]
  __shared__ float Kel[64 * 128];  // esc_j * khat_j[d]
  __shared__ float Ul[64 * 128];
  __shared__ float Mql[64 * 64];
  const float cg63 = cgbuf[cid * 64 + 63];
  const float pC = expf(cg63);
#pragma unroll
  for (int it = 0; it < 4; ++it) {
    int f = it * 2048 + tid * 4;       // f = d*64 + j
    int d = f >> 6, j = f & 63;
    float4 w = *(const float4*)&Wtg[(size_t)cid * 8192 + f];
    Wl[(j + 0) * 128 + d] = w.x;
    Wl[(j + 1) * 128 + d] = w.y;
    Wl[(j + 2) * 128 + d] = w.z;
    Wl[(j + 3) * 128 + d] = w.w;
  }
#pragma unroll
  for (int it = 0; it < 4; ++it) {
    int f = it * 2048 + tid * 4;       // f = j*128 + d
    int j = f >> 7, d = f & 127;
    float esc = expf(cg63 - cgbuf[cid * 64 + j]);
    float4 kv = *(const float4*)&khat[((size_t)(c * 64 + j) * HK_ + hk) * 128 + d];
    float4 uv = *(const float4*)&Ug[(size_t)cid * 8192 + f];
    kv.x *= esc; kv.y *= esc; kv.z *= esc; kv.w *= esc;
    *(float4*)&Kel[f] = kv;
    *(float4*)&Ul[f] = uv;
  }
#pragma unroll
  for (int it = 0; it < 2; ++it) {
    int f = it * 2048 + tid * 4;
    *(float4*)&Mql[f] = *(const float4*)&Mqg[(size_t)cid * 4096 + f];
  }
  __syncthreads();

  // fused M+B: tile rows d0..d0+7, cols n0..n0+3
  const int d0 = (tid & 15) * 8, n0 = (tid >> 4) * 4;
  float ma[8][4] = {}, ba[8][4] = {};
  for (int j = 0; j < 64; ++j) {
    float4 k0 = *(const float4*)&Kel[j * 128 + d0];
    float4 k1 = *(const float4*)&Kel[j * 128 + d0 + 4];
    float4 w0 = *(const float4*)&Wl[j * 128 + n0];
    float4 u0 = *(const float4*)&Ul[j * 128 + n0];
    float ke[8] = {k0.x, k0.y, k0.z, k0.w, k1.x, k1.y, k1.z, k1.w};
    float wv[4] = {w0.x, w0.y, w0.z, w0.w};
    float uv[4] = {u0.x, u0.y, u0.z, u0.w};
#pragma unroll
    for (int a = 0; a < 8; ++a)
#pragma unroll
      for (int b = 0; b < 4; ++b) {
        ma[a][b] = fmaf(ke[a], wv[b], ma[a][b]);
        ba[a][b] = fmaf(ke[a], uv[b], ba[a][b]);
      }
  }
#pragma unroll
  for (int a = 0; a < 8; ++a) {
    const int d = d0 + a;
    us4 hi, lo;
#pragma unroll
    for (int b = 0; b < 4; ++b) {
      float m = ((d == n0 + b) ? pC : 0.f) - ma[a][b];
      u16 h = f2bf(m);
      hi[b] = h;
      lo[b] = f2bf(m - bf2f(h));
    }
    *(us4*)&Mhi[(size_t)cid * 16384 + d * 128 + n0] = hi;
    *(us4*)&Mlo[(size_t)cid * 16384 + d * 128 + n0] = lo;
    float4 b0 = {ba[a][0], ba[a][1], ba[a][2], ba[a][3]};
    *(float4*)&Bg[(size_t)cid * 16384 + d * 128 + n0] = b0;
  }

  // G phase: Gt[d][i] tile 4d x 4i
  const int dg = (tid & 31) * 4, ig = (tid >> 5) * 4;
  float ga[4][4] = {};
  for (int j = 0; j < 64; ++j) {
    float4 w4 = *(const float4*)&Wl[j * 128 + dg];
    float4 m0 = *(const float4*)&Mql[j * 64 + ig];
    float wv[4] = {w4.x, w4.y, w4.z, w4.w};
    float mv[4] = {m0.x, m0.y, m0.z, m0.w};
#pragma unroll
    for (int a = 0; a < 4; ++a)
#pragma unroll
      for (int b = 0; b < 4; ++b) ga[a][b] = fmaf(wv[a], mv[b], ga[a][b]);
  }
#pragma unroll
  for (int a = 0; a < 4; ++a) {
    const int d = dg + a;
    float4 p0 = *(const float4*)&pQg[(size_t)cid * 8192 + d * 64 + ig];
    float4 g0 = {p0.x - ga[a][0], p0.y - ga[a][1], p0.z - ga[a][2], p0.w - ga[a][3]};
    *(float4*)&Gtg[(size_t)cid * 8192 + d * 64 + ig] = g0;
  }
}

// ---------------------------------------------------------------------------
// scan_S v4: 128 blocks = 16 heads x 8 col-slices of 16, XCD-grouped
// (flat%8 == hv%8 so all 8 slices of a head share one L2 copy of M).
// M AND B both register-prefetched one chunk ahead (named double buffers).
// ---------------------------------------------------------------------------
__global__ __launch_bounds__(512) void scan_S(
    const u16* __restrict__ Mhi, const u16* __restrict__ Mlo,
    const float* __restrict__ Bg, float* __restrict__ Sg) {
  const int flat = blockIdx.x;
  const int hv = (flat & 7) + 8 * (flat >> 6);
  const int vs = (flat >> 3) & 7;
  const int tid = threadIdx.x;
  const int wave = tid >> 6, lane = tid & 63;
  const int fr = lane & 15, fq = lane >> 4;
  const int wr = wave * 16;       // this wave's 16 output rows
  const int m0 = vs * 16;         // col-slice base

  __shared__ u16 Sh[2][2048];     // [16 m][128 k] bf16-hi, XOR-swizzled
  __shared__ u16 Sl[2][2048];

  for (int i = tid; i < 2048; i += 512) { Sh[0][i] = 0; Sl[0][i] = 0; }
  {
    float* s0 = Sg + (size_t)hv * 16384 + m0;
#pragma unroll
    for (int it = 0; it < 4; ++it) {
      int idx = it * 512 + tid;          // 2048 = 128 d x 16 m
      s0[(size_t)(idx >> 4) * 128 + (idx & 15)] = 0.f;
    }
  }
  __syncthreads();

  bf16x8 MhA[4], MlA[4], MhB[4], MlB[4];
  float bvA[4], bvB[4];
  {
    const u16* Mh0 = Mhi + (size_t)hv * 16384;
    const u16* Ml0 = Mlo + (size_t)hv * 16384;
#pragma unroll
    for (int kt = 0; kt < 4; ++kt) {
      size_t off = (size_t)(wr + fr) * 128 + kt * 32 + fq * 8;
      MhA[kt] = *(const bf16x8*)&Mh0[off];
      MlA[kt] = *(const bf16x8*)&Ml0[off];
    }
    const float* Bc = Bg + (size_t)hv * 16384 + m0;
#pragma unroll
    for (int j = 0; j < 4; ++j)
      bvA[j] = Bc[(size_t)(wr + fq * 4 + j) * 128 + fr];
  }
  int p = 0;

  auto step = [&](int c, bf16x8 (&MhC)[4], bf16x8 (&MlC)[4], float (&bvC)[4],
                  bf16x8 (&MhN)[4], bf16x8 (&MlN)[4], float (&bvN)[4]) {
    // prefetch next chunk's M frags + B values (consumed next step)
    if (c + 1 < NC_ - 1) {
      const u16* MhP = Mhi + (size_t)((c + 1) * 16 + hv) * 16384;
      const u16* MlP = Mlo + (size_t)((c + 1) * 16 + hv) * 16384;
#pragma unroll
      for (int kt = 0; kt < 4; ++kt) {
        size_t off = (size_t)(wr + fr) * 128 + kt * 32 + fq * 8;
        MhN[kt] = *(const bf16x8*)&MhP[off];
        MlN[kt] = *(const bf16x8*)&MlP[off];
      }
      const float* BcN = Bg + (size_t)((c + 1) * 16 + hv) * 16384 + m0;
#pragma unroll
      for (int j = 0; j < 4; ++j)
        bvN[j] = BcN[(size_t)(wr + fq * 4 + j) * 128 + fr];
    }

    // acc = M_c @ S_c  (bf16 hi/lo x3), 16-col slice: single B fragment
    f32x4v acc = {};
#pragma unroll
    for (int kt = 0; kt < 4; ++kt) {
      const int m = fr;
      const int byte = m * 256 + ((kt * 64 + fq * 16) ^ ((m & 7) << 4));
      bf16x8 BhF = *(const bf16x8*)((const char*)&Sh[p][0] + byte);
      bf16x8 BlF = *(const bf16x8*)((const char*)&Sl[p][0] + byte);
      acc = __builtin_amdgcn_mfma_f32_16x16x32_bf16(MlC[kt], BhF, acc, 0, 0, 0);
      acc = __builtin_amdgcn_mfma_f32_16x16x32_bf16(MhC[kt], BlF, acc, 0, 0, 0);
      acc = __builtin_amdgcn_mfma_f32_16x16x32_bf16(MhC[kt], BhF, acc, 0, 0, 0);
    }

    // S_{c+1} = acc + B (B from registers, prefetched last step)
    float* Sn = Sg + (size_t)((c + 1) * 16 + hv) * 16384 + m0;
    const int k0 = wr + fq * 4;
    const int m = fr;
    us4 h4, l4;
#pragma unroll
    for (int j = 0; j < 4; ++j) {
      float v = acc[j] + bvC[j];
      Sn[(size_t)(k0 + j) * 128 + m] = v;
      u16 h = f2bf(v);
      h4[j] = h;
      l4[j] = f2bf(v - bf2f(h));
    }
    const int wbyte = m * 256 + ((k0 * 2) ^ ((m & 7) << 4));
    *(us4*)((char*)&Sh[p ^ 1][0] + wbyte) = h4;
    *(us4*)((char*)&Sl[p ^ 1][0] + wbyte) = l4;
    __syncthreads();
    p ^= 1;
  };

  for (int cc = 0; cc < NC_ - 1; cc += 2) {
    step(cc, MhA, MlA, bvA, MhB, MlB, bvB);
    if (cc + 1 < NC_ - 1) step(cc + 1, MhB, MlB, bvB, MhA, MlA, bvA);
  }
}

// ---------------------------------------------------------------------------
// chunk_out (parallel, 256 blocks): o = Mq^T U + G*S
// ---------------------------------------------------------------------------
__global__ __launch_bounds__(256) void chunk_out(
    const float* __restrict__ Mqg, const float* __restrict__ Ug,
    const float* __restrict__ Gtg, const float* __restrict__ Sg,
    float* __restrict__ o) {
  const int c = blockIdx.x, hv = blockIdx.y;
  const int cid = c * 16 + hv;
  const int tid = threadIdx.x;
  __shared__ float Mql[64 * 64];
  __shared__ float Ul[64 * 128];
  __shared__ float Gtl[128 * 64];
  __shared__ float Sl[128 * 128];
#pragma unroll
  for (int it = 0; it < 4; ++it) {
    int f = it * 1024 + tid * 4;
    *(float4*)&Mql[f] = *(const float4*)&Mqg[(size_t)cid * 4096 + f];
  }
#pragma unroll
  for (int it = 0; it < 8; ++it) {
    int f = it * 1024 + tid * 4;
    *(float4*)&Ul[f]  = *(const float4*)&Ug[(size_t)cid * 8192 + f];
    *(float4*)&Gtl[f] = *(const float4*)&Gtg[(size_t)cid * 8192 + f];
  }
#pragma unroll
  for (int it = 0; it < 16; ++it) {
    int f = it * 1024 + tid * 4;
    *(float4*)&Sl[f] = *(const float4*)&Sg[(size_t)cid * 16384 + f];
  }
  __syncthreads();

  const int i0 = (tid & 15) * 4, m0 = (tid >> 4) * 8;
  float oa[4][8] = {};
  for (int j = 0; j < 64; ++j) {
    float4 mq = *(const float4*)&Mql[j * 64 + i0];
    float4 u0 = *(const float4*)&Ul[j * 128 + m0];
    float4 u1 = *(const float4*)&Ul[j * 128 + m0 + 4];
    float mv[4] = {mq.x, mq.y, mq.z, mq.w};
    float uv[8] = {u0.x, u0.y, u0.z, u0.w, u1.x, u1.y, u1.z, u1.w};
#pragma unroll
    for (int a = 0; a < 4; ++a)
#pragma unroll
      for (int b = 0; b < 8; ++b) oa[a][b] = fmaf(mv[a], uv[b], oa[a][b]);
  }
  for (int d = 0; d < 128; ++d) {
    float4 gt = *(const float4*)&Gtl[d * 64 + i0];
    float4 s0 = *(const float4*)&Sl[d * 128 + m0];
    float4 s1 = *(const float4*)&Sl[d * 128 + m0 + 4];
    float gv[4] = {gt.x, gt.y, gt.z, gt.w};
    float sv[8] = {s0.x, s0.y, s0.z, s0.w, s1.x, s1.y, s1.z, s1.w};
#pragma unroll
    for (int a = 0; a < 4; ++a)
#pragma unroll
      for (int b = 0; b < 8; ++b) oa[a][b] = fmaf(gv[a], sv[b], oa[a][b]);
  }
#pragma unroll
  for (int a = 0; a < 4; ++a) {
    const int t = c * 64 + i0 + a;
    float4 o0 = {oa[a][0], oa[a][1], oa[a][2], oa[a][3]};
    float4 o1 = {oa[a][4], oa[a][5], oa[a][6], oa[a][7]};
    *(float4*)&o[((size_t)t * HV_ + hv) * 128 + m0]     = o0;
    *(float4*)&o[((size_t)t * HV_ + hv) * 128 + m0 + 4] = o1;
  }
}

// ---------------------------------------------------------------------------
// h = o * silu(z); rmsnorm; -> bf16 (permuted staging layout for gemm2)
// ---------------------------------------------------------------------------
__global__ void gated_rmsnorm(const float* __restrict__ o,
                              const float* __restrict__ zbuf,
                              const float* __restrict__ norm_w,
                              u16* __restrict__ h) {
  const int t = blockIdx.x, hv = blockIdx.y, d = threadIdx.x;
  float ov = o[((size_t)t * HV_ + hv) * 128 + d];
  float zv = zbuf[(size_t)t * VD_ + hv * 128 + d];
  float hc = ov * (zv / (1.f + expf(-zv)));
  float ss = hc * hc;
#pragma unroll
  for (int off = 32; off >= 1; off >>= 1) ss += __shfl_xor(ss, off);
  __shared__ float s2[2];
  if ((d & 63) == 0) s2[d >> 6] = ss;
  __syncthreads();
  float tot = s2[0] + s2[1];
  float r = rsqrtf(tot * (1.f / 128.f) + 1e-6f);
  const int k = hv * 128 + d;
  h[(size_t)t * VD_ + permk3(t, k)] = f2bf(hc * r * norm_w[d]);
}

// ---------------------------------------------------------------------------
extern "C" void kernel_launch(void* const* d_in, const int* in_sizes, int n_in,
                              void* d_out, int out_size, void* d_ws, size_t ws_size,
                              hipStream_t stream) {
  const float* x       = (const float*)d_in[0];
  const float* w_qkvz  = (const float*)d_in[1];
  const float* w_ba    = (const float*)d_in[2];
  const float* conv_w  = (const float*)d_in[3];
  const float* conv_b  = (const float*)d_in[4];
  const float* a_log   = (const float*)d_in[5];
  const float* dt_bias = (const float*)d_in[6];
  const float* norm_w  = (const float*)d_in[7];
  const float* w_o     = (const float*)d_in[8];
  float* out = (float*)d_out;

  float* ws = (float*)d_ws;
  float* qkvraw = ws;                  // 4,194,304  (-> Bg)
  float* zbuf   = ws + 4194304;        // 2,097,152
  float* qkvc   = ws + 6291456;        // 4,194,304  (-> Mhi|Mlo, -> wot)
  float* khat   = ws + 10485760;       // 1,048,576  (-> hb)
  float* gbuf   = ws + 11534336;       // 16,384
  float* bbuf   = ws + 11550720;       // 16,384
  float* cgbuf  = ws + 11567104;       // 16,384
  float* obuf   = ws + 11583488;       // 2,097,152  (xb early)
  float* Wtg    = ws + 13680640;       // 2,097,152 ┐ -> Sg (4,194,304)
  float* pQg    = ws + 15777792;       // 2,097,152 ┘
  float* Ug     = ws + 17874944;       // 2,097,152
  float* Mqg    = ws + 19972096;       // 1,048,576
  float* Gtg    = ws + 21020672;       // 2,097,152

  u16* xb   = (u16*)obuf;      // x bf16 (dead after gemm1)
  u16* wqt  = (u16*)Wtg;       // w_qkvz^T bf16 (dead after gemm1)
  u16* Mhi  = (u16*)qkvc;
  u16* Mlo  = (u16*)(qkvc + 2097152);
  float* Bg = qkvraw;
  float* Sg = Wtg;
  u16* wot  = (u16*)qkvc;      // after scan_S (Mhi dead)
  u16* hb   = (u16*)khat;      // after make_MBG (khat dead)

  // 0) casts (permuted staging layout)
  cast_bf16<<<1024, 256, 0, stream>>>(x, xb, 262144);
  transpose_bf16<<<dim3(32, 96), 256, 0, stream>>>(w_qkvz, wqt, H_, QN_);
  // 1) qkv|z = x @ w_qkvz
  gemm_bf16<<<768, 256, 0, stream>>>(xb, wqt, qkvraw, CD_, zbuf, VD_,
                                     CD_, T_, QN_, H_);
  // 2) beta / g
  ba_gbeta<<<T_, 256, 0, stream>>>(x, w_ba, a_log, dt_bias, gbuf, bbuf);
  // 3) fused conv + silu + k-l2norm
  conv_silu_k<<<T_, 512, 0, stream>>>(qkvraw, conv_w, conv_b, qkvc, khat);
  // 4) chunk-local precompute (parallel, 512 thr)
  chunk_prep<<<dim3(NC_, HV_), 512, 0, stream>>>(
      qkvc, khat, gbuf, bbuf, cgbuf, Wtg, Ug, Mqg, pQg);
  // 5) per-chunk transition/output operators (parallel, 512 thr)
  make_MBG<<<dim3(NC_, HV_), 512, 0, stream>>>(
      Wtg, pQg, Ug, Mqg, khat, cgbuf, Mhi, Mlo, Bg, Gtg);
  // 6) sequential state scan (128 blocks, M+B reg-prefetched)
  scan_S<<<128, 512, 0, stream>>>(Mhi, Mlo, Bg, Sg);
  // 7) w_o^T cast (Mhi region now dead)
  transpose_bf16<<<dim3(32, 32), 256, 0, stream>>>(w_o, wot, VD_, H_);
  // 8) per-chunk outputs (parallel)
  chunk_out<<<dim3(NC_, HV_), 256, 0, stream>>>(Mqg, Ug, Gtg, Sg, obuf);
  // 9) gated rmsnorm -> bf16 h (permuted)
  gated_rmsnorm<<<dim3(T_, HV_), 128, 0, stream>>>(obuf, zbuf, norm_w, hb);
  // 10) out = h @ w_o
  gemm_bf16<<<256, 256, 0, stream>>>(hb, wot, out, VD_, out, VD_,
                                     VD_, T_, VD_, H_);
}

// Round 15
// 246.881 us; speedup vs baseline: 1.0938x; 1.0938x over previous
//
#include <hip/hip_runtime.h>
#include <math.h>

typedef unsigned short u16;
using us4  = __attribute__((ext_vector_type(4))) unsigned short;
using us8  = __attribute__((ext_vector_type(8))) unsigned short;
using bf16x8 = __attribute__((ext_vector_type(8))) __bf16;
using f32x4v = __attribute__((ext_vector_type(4))) float;

// Problem constants
#define T_    1024
#define H_    2048
#define HK_   8
#define HV_   16
#define KD_   1024
#define VD_   2048
#define CD_   4096
#define QN_   6144   // 2*KD + 2*VD
#define NC_   16     // number of chunks
#define C_    64     // chunk length

__device__ __forceinline__ u16 f2bf(float f) {
  unsigned u = __float_as_uint(f);
  u += 0x7fffu + ((u >> 16) & 1u);   // RNE
  return (u16)(u >> 16);
}
__device__ __forceinline__ float bf2f(u16 h) {
  return __uint_as_float(((unsigned)h) << 16);
}
// staging layout for gemm: within each 64-elem k-group, 8-elem chunk c of
// row r is stored at chunk position c ^ (r&7).
__device__ __forceinline__ int permk3(int r, int k) {
  return (k & ~63) | ((((k >> 3) & 7) ^ (r & 7)) << 3) | (k & 7);
}

// ---------------------------------------------------------------------------
// x f32 -> bf16 with chunk permutation (row length 2048)
// ---------------------------------------------------------------------------
__global__ void cast_bf16(const float* __restrict__ in, u16* __restrict__ out,
                          int n8) {
  int i = blockIdx.x * 256 + threadIdx.x;   // 16B-chunk index
  if (i >= n8) return;
  float4 a = ((const float4*)in)[i * 2];
  float4 b = ((const float4*)in)[i * 2 + 1];
  us8 r = {f2bf(a.x), f2bf(a.y), f2bf(a.z), f2bf(a.w),
           f2bf(b.x), f2bf(b.y), f2bf(b.z), f2bf(b.w)};
  const int row = i >> 8;                   // 2048/8 = 256 chunks per row
  const int ip = (i & ~7) | ((i & 7) ^ (row & 7));
  *(us8*)&out[(size_t)ip * 8] = r;
}

// ---------------------------------------------------------------------------
// f32 [R][C] -> bf16 [C][R] transpose + cast + chunk permutation
// ---------------------------------------------------------------------------
__global__ __launch_bounds__(256) void transpose_bf16(
    const float* __restrict__ in, u16* __restrict__ out, int R, int C) {
  __shared__ float tile[64][65];
  const int r0 = blockIdx.x * 64, c0 = blockIdx.y * 64;
  const int t = threadIdx.x;
  const int tr = t >> 4, tc4 = (t & 15) * 4;
#pragma unroll
  for (int i = 0; i < 4; ++i) {
    float4 v = *(const float4*)&in[(size_t)(r0 + tr + i * 16) * C + c0 + tc4];
    tile[tr + i * 16][tc4 + 0] = v.x;
    tile[tr + i * 16][tc4 + 1] = v.y;
    tile[tr + i * 16][tc4 + 2] = v.z;
    tile[tr + i * 16][tc4 + 3] = v.w;
  }
  __syncthreads();
#pragma unroll
  for (int i = 0; i < 4; ++i) {
    int oc = tr + i * 16;
    int row = c0 + oc;
    int k = r0 + tc4;
    us4 w = {f2bf(tile[tc4 + 0][oc]), f2bf(tile[tc4 + 1][oc]),
             f2bf(tile[tc4 + 2][oc]), f2bf(tile[tc4 + 3][oc])};
    *(us4*)&out[(size_t)row * R + permk3(row, k)] = w;
  }
}

// ---------------------------------------------------------------------------
// bf16 MFMA GEMM: C = A[M,K] @ Bt[N,K]^T, f32 out. 128x64 tile, BK=64,
// 2-buffer counted-vmcnt pipeline (48KB LDS keeps 3 blocks/CU; tile it+1's
// 6 loads stay in flight across the barrier), XCD-grouped 1D block mapping,
// 3-bit permuted staging. Output routed to Cq (cols < zsplit) or Cz.
// ---------------------------------------------------------------------------
__device__ __forceinline__ void gload_lds16(const void* g, void* l) {
  __builtin_amdgcn_global_load_lds(
      (const __attribute__((address_space(1))) void*)g,
      (__attribute__((address_space(3))) void*)l, 16, 0, 0);
}

__global__ __launch_bounds__(256) void gemm_bf16(
    const u16* __restrict__ A, const u16* __restrict__ Bt,
    float* __restrict__ Cq, int ldq, float* __restrict__ Cz, int ldz,
    int zsplit, int M, int N, int K) {
  __shared__ __align__(16) u16 As[2][8192];   // [128][64]
  __shared__ __align__(16) u16 Bs[2][4096];   // [64][64]
  const int tid  = threadIdx.x;
  const int wave = tid >> 6, lane = tid & 63;
  const int gy = N >> 6;
  const int ncolpx = gy >> 3;
  const int bid = blockIdx.x;
  const int xcd = bid & 7, idx = bid >> 3;
  const int row0 = (idx / ncolpx) * 128;
  const int col0 = (xcd * ncolpx + idx % ncolpx) * 64;
  const int wr = wave >> 1, wc = wave & 1;
  const int fr = lane & 15, fq = lane >> 4;

  const int sr8 = lane >> 3;
  const int sc8 = (lane & 7) * 8;
  const u16* gA = A  + (size_t)(row0 + wave * 32 + sr8) * K + sc8;
  const u16* gB = Bt + (size_t)(col0 + wave * 16 + sr8) * K + sc8;

  f32x4v acc[4][2] = {};
  const int nt = K >> 6;

  // one stage issues exactly 6 global_load_lds per wave (4 A + 2 B)
  auto stage = [&](int p, int k0) {
#pragma unroll
    for (int j = 0; j < 4; ++j)
      gload_lds16(gA + (size_t)(j * 8) * K + k0,
                  &As[p][(wave * 32 + j * 8) * 64]);
#pragma unroll
    for (int j = 0; j < 2; ++j)
      gload_lds16(gB + (size_t)(j * 8) * K + k0,
                  &Bs[p][(wave * 16 + j * 8) * 64]);
  };

  stage(0, 0);

  int p = 0;
  for (int it = 0; it < nt; ++it) {
    if (it + 1 < nt) stage(p ^ 1, (it + 1) * 64);
    // counted wait: tile it's 6 loads done; tile it+1's 6 stay in flight
    if (it + 1 < nt) asm volatile("s_waitcnt vmcnt(6)" ::: "memory");
    else             asm volatile("s_waitcnt vmcnt(0)" ::: "memory");
    __builtin_amdgcn_s_barrier();

#pragma unroll
    for (int kt = 0; kt < 2; ++kt) {
      bf16x8 af[4], bff[2];
#pragma unroll
      for (int mi = 0; mi < 4; ++mi) {
        const int r = wr * 64 + mi * 16 + fr;
        af[mi] = *(const bf16x8*)
            &As[p][r * 64 + kt * 32 + (((kt * 4 + fq) ^ (r & 7)) & 3) * 8
                   + ((((kt * 4 + fq) ^ (r & 7)) >> 2) - kt) * 32];
      }
#pragma unroll
      for (int ni = 0; ni < 2; ++ni) {
        const int r = wc * 32 + ni * 16 + fr;
        bff[ni] = *(const bf16x8*)
            &Bs[p][r * 64 + kt * 32 + (((kt * 4 + fq) ^ (r & 7)) & 3) * 8
                   + ((((kt * 4 + fq) ^ (r & 7)) >> 2) - kt) * 32];
      }
#pragma unroll
      for (int mi = 0; mi < 4; ++mi)
#pragma unroll
        for (int ni = 0; ni < 2; ++ni)
          acc[mi][ni] = __builtin_amdgcn_mfma_f32_16x16x32_bf16(
              af[mi], bff[ni], acc[mi][ni], 0, 0, 0);
    }
    // all waves done reading buffer p before iter it+1 stages tile it+2 into p
    if (it + 1 < nt) {
      asm volatile("s_waitcnt lgkmcnt(0)" ::: "memory");
      __builtin_amdgcn_s_barrier();
    }
    p ^= 1;
  }

  float* Cp; int ldc, cb;
  if (col0 < zsplit) { Cp = Cq; ldc = ldq; cb = col0; }
  else               { Cp = Cz; ldc = ldz; cb = col0 - zsplit; }
#pragma unroll
  for (int mi = 0; mi < 4; ++mi)
#pragma unroll
    for (int ni = 0; ni < 2; ++ni) {
      const int r  = row0 + wr * 64 + mi * 16 + fq * 4;
      const int cc = cb + wc * 32 + ni * 16 + fr;
#pragma unroll
      for (int j = 0; j < 4; ++j)
        Cp[(size_t)(r + j) * ldc + cc] = acc[mi][ni][j];
    }
}

// ---------------------------------------------------------------------------
// ba = x @ w_ba -> beta = sigmoid(b), g = -exp(a_log)*softplus(a+dt_bias)
// ---------------------------------------------------------------------------
__global__ __launch_bounds__(256) void ba_gbeta(
    const float* __restrict__ x, const float* __restrict__ w_ba,
    const float* __restrict__ a_log, const float* __restrict__ dt_bias,
    float* __restrict__ g, float* __restrict__ beta) {
  const int t = blockIdx.x;
  const int tid = threadIdx.x;
  __shared__ float xs[2048];
  __shared__ float red[8][32];
  {
    float4 v = *(const float4*)&x[(size_t)t * H_ + tid * 4];
    *(float4*)&xs[tid * 4] = v;
    float4 w = *(const float4*)&x[(size_t)t * H_ + 1024 + tid * 4];
    *(float4*)&xs[1024 + tid * 4] = w;
  }
  __syncthreads();
  const int c = tid & 31;
  const int chunk = tid >> 5;
  float p = 0.f;
  const int kb = chunk * 256;
#pragma unroll 4
  for (int k = kb; k < kb + 256; ++k) p = fmaf(xs[k], w_ba[k * 32 + c], p);
  red[chunk][c] = p;
  __syncthreads();
  if (tid < 32) {
    float s = 0.f;
#pragma unroll
    for (int i = 0; i < 8; ++i) s += red[i][c];
    if (c < 16) {
      beta[t * 16 + c] = 1.f / (1.f + expf(-s));
    } else {
      int h = c - 16;
      float xx = s + dt_bias[h];
      float sp = xx > 20.f ? xx : log1pf(expf(xx));
      g[t * 16 + h] = -expf(a_log[h]) * sp;
    }
  }
}

// ---------------------------------------------------------------------------
// fused causal depthwise conv1d (K=4) + SiLU + k-l2norm.
// ---------------------------------------------------------------------------
__global__ __launch_bounds__(512) void conv_silu_k(
    const float* __restrict__ qkvraw, const float* __restrict__ conv_w,
    const float* __restrict__ conv_b, float* __restrict__ qkvc,
    float* __restrict__ khat) {
  const int t = blockIdx.x;
  const int tid = threadIdx.x;
  const int c0 = tid * 8;
  float acc[8];
  float4 cb0 = *(const float4*)&conv_b[c0];
  float4 cb1 = *(const float4*)&conv_b[c0 + 4];
  acc[0] = cb0.x; acc[1] = cb0.y; acc[2] = cb0.z; acc[3] = cb0.w;
  acc[4] = cb1.x; acc[5] = cb1.y; acc[6] = cb1.z; acc[7] = cb1.w;
  float wv[8][4];
#pragma unroll
  for (int i = 0; i < 8; i += 2) {
    float4 w0 = *(const float4*)&conv_w[(c0 + i) * 4];
    float4 w1 = *(const float4*)&conv_w[(c0 + i + 1) * 4];
    wv[i][0] = w0.x; wv[i][1] = w0.y; wv[i][2] = w0.z; wv[i][3] = w0.w;
    wv[i+1][0] = w1.x; wv[i+1][1] = w1.y; wv[i+1][2] = w1.z; wv[i+1][3] = w1.w;
  }
#pragma unroll
  for (int j = 0; j < 4; ++j) {
    int tt = t - 3 + j;
    if (tt >= 0) {
      float4 a = *(const float4*)&qkvraw[(size_t)tt * CD_ + c0];
      float4 b = *(const float4*)&qkvraw[(size_t)tt * CD_ + c0 + 4];
      float xv[8] = {a.x, a.y, a.z, a.w, b.x, b.y, b.z, b.w};
#pragma unroll
      for (int i = 0; i < 8; ++i) acc[i] = fmaf(xv[i], wv[i][j], acc[i]);
    }
  }
  float y[8];
#pragma unroll
  for (int i = 0; i < 8; ++i) y[i] = acc[i] / (1.f + expf(-acc[i]));

  if (tid < 128 || tid >= 256) {
    float4 o0 = {y[0], y[1], y[2], y[3]};
    float4 o1 = {y[4], y[5], y[6], y[7]};
    *(float4*)&qkvc[(size_t)t * CD_ + c0]     = o0;
    *(float4*)&qkvc[(size_t)t * CD_ + c0 + 4] = o1;
  } else {
    float ss = 0.f;
#pragma unroll
    for (int i = 0; i < 8; ++i) ss = fmaf(y[i], y[i], ss);
#pragma unroll
    for (int off = 1; off < 16; off <<= 1) ss += __shfl_xor(ss, off);
    float rs = rsqrtf(ss + 1e-6f);
    const int head = (c0 - 1024) >> 7;
    const int d0 = (c0 - 1024) & 127;
    float4 o0 = {y[0] * rs, y[1] * rs, y[2] * rs, y[3] * rs};
    float4 o1 = {y[4] * rs, y[5] * rs, y[6] * rs, y[7] * rs};
    float* kout = &khat[((size_t)t * HK_ + head) * 128 + d0];
    *(float4*)&kout[0] = o0;
    *(float4*)&kout[4] = o1;
  }
}

// ---------------------------------------------------------------------------
// Chunked gated delta rule, phase A (parallel over 16 chunks x 16 heads).
// 512 threads (8 waves). Dot phase 4x2 tiles/thread; during the serial
// forward substitution (waves 0-3), waves 4-7 write Mqg and pQg.
// ---------------------------------------------------------------------------
#define SWZ(r) (((r) >> 2) & 7)

__device__ __forceinline__ float4 ldsw4(const float* base, int r, int dblk) {
  return *(const float4*)&base[r * 128 + ((dblk ^ SWZ(r)) << 2)];
}
__device__ __forceinline__ float ldsw1(const float* base, int r, int d) {
  return base[r * 128 + ((((d) >> 2) ^ SWZ(r)) << 2) + ((d) & 3)];
}

__global__ __launch_bounds__(512) void chunk_prep(
    const float* __restrict__ qkvc, const float* __restrict__ khat,
    const float* __restrict__ g, const float* __restrict__ beta,
    float* __restrict__ cgbuf, float* __restrict__ Wtg, float* __restrict__ Ug,
    float* __restrict__ Mqg, float* __restrict__ pQg) {
  const int c = blockIdx.x, hv = blockIdx.y, hk = hv >> 1;
  const int cid = c * 16 + hv;
  const int tid = threadIdx.x;
  __shared__ float Kl[8192], Ql[8192];   // swizzled [64][128]
  __shared__ float AM[8320];             // At[64][65] | Mq[64][65]; later Utr
  __shared__ float cgl[64], bl[64], bp[64], rsl[64];
  float* At = AM;
  float* Mq = AM + 4160;

#pragma unroll
  for (int it = 0; it < 4; ++it) {
    int flat = it * 2048 + tid * 4;
    int row = flat >> 7, d = flat & 127;
    int pb = ((d >> 2) ^ SWZ(row)) << 2;
    int gt = c * 64 + row;
    float4 kv = *(const float4*)&khat[((size_t)gt * HK_ + hk) * 128 + d];
    float4 qv = *(const float4*)&qkvc[(size_t)gt * CD_ + hk * 128 + d];
    *(float4*)&Kl[row * 128 + pb] = kv;
    *(float4*)&Ql[row * 128 + pb] = qv;
  }
  if (tid < 64) {
    float s = g[(size_t)(c * 64 + tid) * HV_ + hv];
#pragma unroll
    for (int off = 1; off < 64; off <<= 1) {
      float t = __shfl_up(s, off);
      if (tid >= off) s += t;
    }
    cgl[tid] = s;
    cgbuf[cid * 64 + tid] = s;
    bl[tid] = beta[(size_t)(c * 64 + tid) * HV_ + hv];
  }
  __syncthreads();
  if (tid < 64) {
    float sq = 0.f;
#pragma unroll
    for (int dblk = 0; dblk < 32; ++dblk) {
      float4 q4 = ldsw4(Ql, tid, dblk);
      sq = fmaf(q4.x, q4.x, sq); sq = fmaf(q4.y, q4.y, sq);
      sq = fmaf(q4.z, q4.z, sq); sq = fmaf(q4.w, q4.w, sq);
    }
    rsl[tid] = rsqrtf(sq + 1e-6f) * 0.08838834764831845f;
    bp[tid] = bl[tid] * expf(cgl[tid]);
  }
  __syncthreads();

  // dot phase: 4x2 tile of (i,j) pairs per thread (512 threads)
  const int i0 = (tid >> 5) * 4, j0 = (tid & 31) * 2;
  float kk[4][2], qk[4][2];
#pragma unroll
  for (int a = 0; a < 4; ++a)
#pragma unroll
    for (int b = 0; b < 2; ++b) { kk[a][b] = 0.f; qk[a][b] = 0.f; }
  for (int dblk = 0; dblk < 32; ++dblk) {
    float4 ka[4], qa[4], kb[2];
#pragma unroll
    for (int a = 0; a < 4; ++a) {
      ka[a] = ldsw4(Kl, i0 + a, dblk);
      qa[a] = ldsw4(Ql, i0 + a, dblk);
    }
#pragma unroll
    for (int b = 0; b < 2; ++b) kb[b] = ldsw4(Kl, j0 + b, dblk);
#pragma unroll
    for (int a = 0; a < 4; ++a)
#pragma unroll
      for (int b = 0; b < 2; ++b) {
        kk[a][b] = fmaf(ka[a].x, kb[b].x, kk[a][b]);
        kk[a][b] = fmaf(ka[a].y, kb[b].y, kk[a][b]);
        kk[a][b] = fmaf(ka[a].z, kb[b].z, kk[a][b]);
        kk[a][b] = fmaf(ka[a].w, kb[b].w, kk[a][b]);
        qk[a][b] = fmaf(qa[a].x, kb[b].x, qk[a][b]);
        qk[a][b] = fmaf(qa[a].y, kb[b].y, qk[a][b]);
        qk[a][b] = fmaf(qa[a].z, kb[b].z, qk[a][b]);
        qk[a][b] = fmaf(qa[a].w, kb[b].w, qk[a][b]);
      }
  }
#pragma unroll
  for (int a = 0; a < 4; ++a)
#pragma unroll
    for (int b = 0; b < 2; ++b) {
      int i = i0 + a, j = j0 + b;
      float e = expf(cgl[i] - cgl[j]);
      At[j * 65 + i] = (j < i) ? (-bl[i] * e * kk[a][b]) : 0.f;
      Mq[j * 65 + i] = (j <= i) ? (rsl[i] * e * qk[a][b]) : 0.f;
    }
  __syncthreads();

  float X[64];
  if (tid < 256) {
    // ---- waves 0-3: X init + forward substitution ----
    if (tid < 128) {
#pragma unroll
      for (int j = 0; j < 64; ++j) X[j] = bp[j] * ldsw1(Kl, j, tid);
    } else {
      const int m = tid - 128;
#pragma unroll
      for (int j = 0; j < 64; ++j)
        X[j] = bl[j] * qkvc[(size_t)(c * 64 + j) * CD_ + 2 * KD_ + hv * 128 + m];
    }
#pragma unroll
    for (int j = 0; j < 63; ++j) {
      float xj = X[j];
#pragma unroll
      for (int i = j + 1; i < 64; ++i) X[i] = fmaf(At[j * 65 + i], xj, X[i]);
    }
    if (tid < 128) {
      size_t baseo = ((size_t)cid * 128 + tid) * 64;
#pragma unroll
      for (int j4 = 0; j4 < 16; ++j4) {
        float4 v = {X[j4 * 4], X[j4 * 4 + 1], X[j4 * 4 + 2], X[j4 * 4 + 3]};
        *(float4*)&Wtg[baseo + j4 * 4] = v;
      }
    }
  } else {
    // ---- waves 4-7: Mqg + pQg writes (independent of solve) ----
    const int t2 = tid - 256;
#pragma unroll
    for (int it = 0; it < 16; ++it) {
      int f = it * 256 + t2;
      int j = f >> 6, i = f & 63;
      Mqg[(size_t)cid * 4096 + f] = Mq[j * 65 + i];
    }
    const int i = t2 & 63;
    const float ei = expf(cgl[i]) * rsl[i];
#pragma unroll
    for (int it = 0; it < 32; ++it) {
      int d = it * 4 + (t2 >> 6);
      pQg[(size_t)cid * 8192 + d * 64 + i] = ei * ldsw1(Ql, i, d);
    }
  }
  __syncthreads();   // At/Mq dead; X (U cols) ready

  if (tid >= 128 && tid < 256) {
    const int m = tid - 128;
    float* Utr = AM;
#pragma unroll
    for (int j = 0; j < 64; ++j) Utr[j * 128 + m] = X[j];
  }
  __syncthreads();
  {
    const float* Utr = AM;
#pragma unroll
    for (int it = 0; it < 4; ++it) {
      int flat = it * 2048 + tid * 4;
      *(float4*)&Ug[(size_t)cid * 8192 + flat] = *(const float4*)&Utr[flat];
    }
  }
}

// ---------------------------------------------------------------------------
// make_MBG (parallel, 256 blocks, 512 threads)
// ---------------------------------------------------------------------------
__global__ __launch_bounds__(512) void make_MBG(
    const float* __restrict__ Wtg, const float* __restrict__ pQg,
    const float* __restrict__ Ug, const float* __restrict__ Mqg,
    const float* __restrict__ khat, const float* __restrict__ cgbuf,
    u16* __restrict__ Mhi, u16* __restrict__ Mlo,
    float* __restrict__ Bg, float* __restrict__ Gtg) {
  const int c = blockIdx.x, hv = blockIdx.y, hk = hv >> 1;
  const int cid = c * 16 + hv;
  const int tid = threadIdx.x;
  __shared__ float Wl[64 * 128];   // W[j][d]
  __shared__ float Kel[64 * 128];  // esc_j * khat_j[d]
  __shared__ float Ul[64 * 128];
  __shared__ float Mql[64 * 64];
  const float cg63 = cgbuf[cid * 64 + 63];
  const float pC = expf(cg63);
#pragma unroll
  for (int it = 0; it < 4; ++it) {
    int f = it * 2048 + tid * 4;       // f = d*64 + j
    int d = f >> 6, j = f & 63;
    float4 w = *(const float4*)&Wtg[(size_t)cid * 8192 + f];
    Wl[(j + 0) * 128 + d] = w.x;
    Wl[(j + 1) * 128 + d] = w.y;
    Wl[(j + 2) * 128 + d] = w.z;
    Wl[(j + 3) * 128 + d] = w.w;
  }
#pragma unroll
  for (int it = 0; it < 4; ++it) {
    int f = it * 2048 + tid * 4;       // f = j*128 + d
    int j = f >> 7, d = f & 127;
    float esc = expf(cg63 - cgbuf[cid * 64 + j]);
    float4 kv = *(const float4*)&khat[((size_t)(c * 64 + j) * HK_ + hk) * 128 + d];
    float4 uv = *(const float4*)&Ug[(size_t)cid * 8192 + f];
    kv.x *= esc; kv.y *= esc; kv.z *= esc; kv.w *= esc;
    *(float4*)&Kel[f] = kv;
    *(float4*)&Ul[f] = uv;
  }
#pragma unroll
  for (int it = 0; it < 2; ++it) {
    int f = it * 2048 + tid * 4;
    *(float4*)&Mql[f] = *(const float4*)&Mqg[(size_t)cid * 4096 + f];
  }
  __syncthreads();

  // fused M+B: tile rows d0..d0+7, cols n0..n0+3
  const int d0 = (tid & 15) * 8, n0 = (tid >> 4) * 4;
  float ma[8][4] = {}, ba[8][4] = {};
  for (int j = 0; j < 64; ++j) {
    float4 k0 = *(const float4*)&Kel[j * 128 + d0];
    float4 k1 = *(const float4*)&Kel[j * 128 + d0 + 4];
    float4 w0 = *(const float4*)&Wl[j * 128 + n0];
    float4 u0 = *(const float4*)&Ul[j * 128 + n0];
    float ke[8] = {k0.x, k0.y, k0.z, k0.w, k1.x, k1.y, k1.z, k1.w};
    float wv[4] = {w0.x, w0.y, w0.z, w0.w};
    float uv[4] = {u0.x, u0.y, u0.z, u0.w};
#pragma unroll
    for (int a = 0; a < 8; ++a)
#pragma unroll
      for (int b = 0; b < 4; ++b) {
        ma[a][b] = fmaf(ke[a], wv[b], ma[a][b]);
        ba[a][b] = fmaf(ke[a], uv[b], ba[a][b]);
      }
  }
#pragma unroll
  for (int a = 0; a < 8; ++a) {
    const int d = d0 + a;
    us4 hi, lo;
#pragma unroll
    for (int b = 0; b < 4; ++b) {
      float m = ((d == n0 + b) ? pC : 0.f) - ma[a][b];
      u16 h = f2bf(m);
      hi[b] = h;
      lo[b] = f2bf(m - bf2f(h));
    }
    *(us4*)&Mhi[(size_t)cid * 16384 + d * 128 + n0] = hi;
    *(us4*)&Mlo[(size_t)cid * 16384 + d * 128 + n0] = lo;
    float4 b0 = {ba[a][0], ba[a][1], ba[a][2], ba[a][3]};
    *(float4*)&Bg[(size_t)cid * 16384 + d * 128 + n0] = b0;
  }

  // G phase: Gt[d][i] tile 4d x 4i
  const int dg = (tid & 31) * 4, ig = (tid >> 5) * 4;
  float ga[4][4] = {};
  for (int j = 0; j < 64; ++j) {
    float4 w4 = *(const float4*)&Wl[j * 128 + dg];
    float4 m0 = *(const float4*)&Mql[j * 64 + ig];
    float wv[4] = {w4.x, w4.y, w4.z, w4.w};
    float mv[4] = {m0.x, m0.y, m0.z, m0.w};
#pragma unroll
    for (int a = 0; a < 4; ++a)
#pragma unroll
      for (int b = 0; b < 4; ++b) ga[a][b] = fmaf(wv[a], mv[b], ga[a][b]);
  }
#pragma unroll
  for (int a = 0; a < 4; ++a) {
    const int d = dg + a;
    float4 p0 = *(const float4*)&pQg[(size_t)cid * 8192 + d * 64 + ig];
    float4 g0 = {p0.x - ga[a][0], p0.y - ga[a][1], p0.z - ga[a][2], p0.w - ga[a][3]};
    *(float4*)&Gtg[(size_t)cid * 8192 + d * 64 + ig] = g0;
  }
}

// ---------------------------------------------------------------------------
// scan_S v4: 128 blocks = 16 heads x 8 col-slices of 16, XCD-grouped
// (flat%8 == hv%8 so all 8 slices of a head share one L2 copy of M).
// M AND B both register-prefetched one chunk ahead (named double buffers).
// ---------------------------------------------------------------------------
__global__ __launch_bounds__(512) void scan_S(
    const u16* __restrict__ Mhi, const u16* __restrict__ Mlo,
    const float* __restrict__ Bg, float* __restrict__ Sg) {
  const int flat = blockIdx.x;
  const int hv = (flat & 7) + 8 * (flat >> 6);
  const int vs = (flat >> 3) & 7;
  const int tid = threadIdx.x;
  const int wave = tid >> 6, lane = tid & 63;
  const int fr = lane & 15, fq = lane >> 4;
  const int wr = wave * 16;       // this wave's 16 output rows
  const int m0 = vs * 16;         // col-slice base

  __shared__ u16 Sh[2][2048];     // [16 m][128 k] bf16-hi, XOR-swizzled
  __shared__ u16 Sl[2][2048];

  for (int i = tid; i < 2048; i += 512) { Sh[0][i] = 0; Sl[0][i] = 0; }
  {
    float* s0 = Sg + (size_t)hv * 16384 + m0;
#pragma unroll
    for (int it = 0; it < 4; ++it) {
      int idx = it * 512 + tid;          // 2048 = 128 d x 16 m
      s0[(size_t)(idx >> 4) * 128 + (idx & 15)] = 0.f;
    }
  }
  __syncthreads();

  bf16x8 MhA[4], MlA[4], MhB[4], MlB[4];
  float bvA[4], bvB[4];
  {
    const u16* Mh0 = Mhi + (size_t)hv * 16384;
    const u16* Ml0 = Mlo + (size_t)hv * 16384;
#pragma unroll
    for (int kt = 0; kt < 4; ++kt) {
      size_t off = (size_t)(wr + fr) * 128 + kt * 32 + fq * 8;
      MhA[kt] = *(const bf16x8*)&Mh0[off];
      MlA[kt] = *(const bf16x8*)&Ml0[off];
    }
    const float* Bc = Bg + (size_t)hv * 16384 + m0;
#pragma unroll
    for (int j = 0; j < 4; ++j)
      bvA[j] = Bc[(size_t)(wr + fq * 4 + j) * 128 + fr];
  }
  int p = 0;

  auto step = [&](int c, bf16x8 (&MhC)[4], bf16x8 (&MlC)[4], float (&bvC)[4],
                  bf16x8 (&MhN)[4], bf16x8 (&MlN)[4], float (&bvN)[4]) {
    // prefetch next chunk's M frags + B values (consumed next step)
    if (c + 1 < NC_ - 1) {
      const u16* MhP = Mhi + (size_t)((c + 1) * 16 + hv) * 16384;
      const u16* MlP = Mlo + (size_t)((c + 1) * 16 + hv) * 16384;
#pragma unroll
      for (int kt = 0; kt < 4; ++kt) {
        size_t off = (size_t)(wr + fr) * 128 + kt * 32 + fq * 8;
        MhN[kt] = *(const bf16x8*)&MhP[off];
        MlN[kt] = *(const bf16x8*)&MlP[off];
      }
      const float* BcN = Bg + (size_t)((c + 1) * 16 + hv) * 16384 + m0;
#pragma unroll
      for (int j = 0; j < 4; ++j)
        bvN[j] = BcN[(size_t)(wr + fq * 4 + j) * 128 + fr];
    }

    // acc = M_c @ S_c  (bf16 hi/lo x3), 16-col slice: single B fragment
    f32x4v acc = {};
#pragma unroll
    for (int kt = 0; kt < 4; ++kt) {
      const int m = fr;
      const int byte = m * 256 + ((kt * 64 + fq * 16) ^ ((m & 7) << 4));
      bf16x8 BhF = *(const bf16x8*)((const char*)&Sh[p][0] + byte);
      bf16x8 BlF = *(const bf16x8*)((const char*)&Sl[p][0] + byte);
      acc = __builtin_amdgcn_mfma_f32_16x16x32_bf16(MlC[kt], BhF, acc, 0, 0, 0);
      acc = __builtin_amdgcn_mfma_f32_16x16x32_bf16(MhC[kt], BlF, acc, 0, 0, 0);
      acc = __builtin_amdgcn_mfma_f32_16x16x32_bf16(MhC[kt], BhF, acc, 0, 0, 0);
    }

    // S_{c+1} = acc + B (B from registers, prefetched last step)
    float* Sn = Sg + (size_t)((c + 1) * 16 + hv) * 16384 + m0;
    const int k0 = wr + fq * 4;
    const int m = fr;
    us4 h4, l4;
#pragma unroll
    for (int j = 0; j < 4; ++j) {
      float v = acc[j] + bvC[j];
      Sn[(size_t)(k0 + j) * 128 + m] = v;
      u16 h = f2bf(v);
      h4[j] = h;
      l4[j] = f2bf(v - bf2f(h));
    }
    const int wbyte = m * 256 + ((k0 * 2) ^ ((m & 7) << 4));
    *(us4*)((char*)&Sh[p ^ 1][0] + wbyte) = h4;
    *(us4*)((char*)&Sl[p ^ 1][0] + wbyte) = l4;
    __syncthreads();
    p ^= 1;
  };

  for (int cc = 0; cc < NC_ - 1; cc += 2) {
    step(cc, MhA, MlA, bvA, MhB, MlB, bvB);
    if (cc + 1 < NC_ - 1) step(cc + 1, MhB, MlB, bvB, MhA, MlA, bvA);
  }
}

// ---------------------------------------------------------------------------
// chunk_out (parallel, 256 blocks): o = Mq^T U + G*S
// ---------------------------------------------------------------------------
__global__ __launch_bounds__(256) void chunk_out(
    const float* __restrict__ Mqg, const float* __restrict__ Ug,
    const float* __restrict__ Gtg, const float* __restrict__ Sg,
    float* __restrict__ o) {
  const int c = blockIdx.x, hv = blockIdx.y;
  const int cid = c * 16 + hv;
  const int tid = threadIdx.x;
  __shared__ float Mql[64 * 64];
  __shared__ float Ul[64 * 128];
  __shared__ float Gtl[128 * 64];
  __shared__ float Sl[128 * 128];
#pragma unroll
  for (int it = 0; it < 4; ++it) {
    int f = it * 1024 + tid * 4;
    *(float4*)&Mql[f] = *(const float4*)&Mqg[(size_t)cid * 4096 + f];
  }
#pragma unroll
  for (int it = 0; it < 8; ++it) {
    int f = it * 1024 + tid * 4;
    *(float4*)&Ul[f]  = *(const float4*)&Ug[(size_t)cid * 8192 + f];
    *(float4*)&Gtl[f] = *(const float4*)&Gtg[(size_t)cid * 8192 + f];
  }
#pragma unroll
  for (int it = 0; it < 16; ++it) {
    int f = it * 1024 + tid * 4;
    *(float4*)&Sl[f] = *(const float4*)&Sg[(size_t)cid * 16384 + f];
  }
  __syncthreads();

  const int i0 = (tid & 15) * 4, m0 = (tid >> 4) * 8;
  float oa[4][8] = {};
  for (int j = 0; j < 64; ++j) {
    float4 mq = *(const float4*)&Mql[j * 64 + i0];
    float4 u0 = *(const float4*)&Ul[j * 128 + m0];
    float4 u1 = *(const float4*)&Ul[j * 128 + m0 + 4];
    float mv[4] = {mq.x, mq.y, mq.z, mq.w};
    float uv[8] = {u0.x, u0.y, u0.z, u0.w, u1.x, u1.y, u1.z, u1.w};
#pragma unroll
    for (int a = 0; a < 4; ++a)
#pragma unroll
      for (int b = 0; b < 8; ++b) oa[a][b] = fmaf(mv[a], uv[b], oa[a][b]);
  }
  for (int d = 0; d < 128; ++d) {
    float4 gt = *(const float4*)&Gtl[d * 64 + i0];
    float4 s0 = *(const float4*)&Sl[d * 128 + m0];
    float4 s1 = *(const float4*)&Sl[d * 128 + m0 + 4];
    float gv[4] = {gt.x, gt.y, gt.z, gt.w};
    float sv[8] = {s0.x, s0.y, s0.z, s0.w, s1.x, s1.y, s1.z, s1.w};
#pragma unroll
    for (int a = 0; a < 4; ++a)
#pragma unroll
      for (int b = 0; b < 8; ++b) oa[a][b] = fmaf(gv[a], sv[b], oa[a][b]);
  }
#pragma unroll
  for (int a = 0; a < 4; ++a) {
    const int t = c * 64 + i0 + a;
    float4 o0 = {oa[a][0], oa[a][1], oa[a][2], oa[a][3]};
    float4 o1 = {oa[a][4], oa[a][5], oa[a][6], oa[a][7]};
    *(float4*)&o[((size_t)t * HV_ + hv) * 128 + m0]     = o0;
    *(float4*)&o[((size_t)t * HV_ + hv) * 128 + m0 + 4] = o1;
  }
}

// ---------------------------------------------------------------------------
// h = o * silu(z); rmsnorm; -> bf16 (permuted staging layout for gemm2)
// ---------------------------------------------------------------------------
__global__ void gated_rmsnorm(const float* __restrict__ o,
                              const float* __restrict__ zbuf,
                              const float* __restrict__ norm_w,
                              u16* __restrict__ h) {
  const int t = blockIdx.x, hv = blockIdx.y, d = threadIdx.x;
  float ov = o[((size_t)t * HV_ + hv) * 128 + d];
  float zv = zbuf[(size_t)t * VD_ + hv * 128 + d];
  float hc = ov * (zv / (1.f + expf(-zv)));
  float ss = hc * hc;
#pragma unroll
  for (int off = 32; off >= 1; off >>= 1) ss += __shfl_xor(ss, off);
  __shared__ float s2[2];
  if ((d & 63) == 0) s2[d >> 6] = ss;
  __syncthreads();
  float tot = s2[0] + s2[1];
  float r = rsqrtf(tot * (1.f / 128.f) + 1e-6f);
  const int k = hv * 128 + d;
  h[(size_t)t * VD_ + permk3(t, k)] = f2bf(hc * r * norm_w[d]);
}

// ---------------------------------------------------------------------------
extern "C" void kernel_launch(void* const* d_in, const int* in_sizes, int n_in,
                              void* d_out, int out_size, void* d_ws, size_t ws_size,
                              hipStream_t stream) {
  const float* x       = (const float*)d_in[0];
  const float* w_qkvz  = (const float*)d_in[1];
  const float* w_ba    = (const float*)d_in[2];
  const float* conv_w  = (const float*)d_in[3];
  const float* conv_b  = (const float*)d_in[4];
  const float* a_log   = (const float*)d_in[5];
  const float* dt_bias = (const float*)d_in[6];
  const float* norm_w  = (const float*)d_in[7];
  const float* w_o     = (const float*)d_in[8];
  float* out = (float*)d_out;

  float* ws = (float*)d_ws;
  float* qkvraw = ws;                  // 4,194,304  (-> Bg)
  float* zbuf   = ws + 4194304;        // 2,097,152
  float* qkvc   = ws + 6291456;        // 4,194,304  (-> Mhi|Mlo, -> wot)
  float* khat   = ws + 10485760;       // 1,048,576  (-> hb)
  float* gbuf   = ws + 11534336;       // 16,384
  float* bbuf   = ws + 11550720;       // 16,384
  float* cgbuf  = ws + 11567104;       // 16,384
  float* obuf   = ws + 11583488;       // 2,097,152  (xb early)
  float* Wtg    = ws + 13680640;       // 2,097,152 ┐ -> Sg (4,194,304)
  float* pQg    = ws + 15777792;       // 2,097,152 ┘
  float* Ug     = ws + 17874944;       // 2,097,152
  float* Mqg    = ws + 19972096;       // 1,048,576
  float* Gtg    = ws + 21020672;       // 2,097,152

  u16* xb   = (u16*)obuf;      // x bf16 (dead after gemm1)
  u16* wqt  = (u16*)Wtg;       // w_qkvz^T bf16 (dead after gemm1)
  u16* Mhi  = (u16*)qkvc;
  u16* Mlo  = (u16*)(qkvc + 2097152);
  float* Bg = qkvraw;
  float* Sg = Wtg;
  u16* wot  = (u16*)qkvc;      // after scan_S (Mhi dead)
  u16* hb   = (u16*)khat;      // after make_MBG (khat dead)

  // 0) casts (permuted staging layout)
  cast_bf16<<<1024, 256, 0, stream>>>(x, xb, 262144);
  transpose_bf16<<<dim3(32, 96), 256, 0, stream>>>(w_qkvz, wqt, H_, QN_);
  // 1) qkv|z = x @ w_qkvz
  gemm_bf16<<<768, 256, 0, stream>>>(xb, wqt, qkvraw, CD_, zbuf, VD_,
                                     CD_, T_, QN_, H_);
  // 2) beta / g
  ba_gbeta<<<T_, 256, 0, stream>>>(x, w_ba, a_log, dt_bias, gbuf, bbuf);
  // 3) fused conv + silu + k-l2norm
  conv_silu_k<<<T_, 512, 0, stream>>>(qkvraw, conv_w, conv_b, qkvc, khat);
  // 4) chunk-local precompute (parallel, 512 thr)
  chunk_prep<<<dim3(NC_, HV_), 512, 0, stream>>>(
      qkvc, khat, gbuf, bbuf, cgbuf, Wtg, Ug, Mqg, pQg);
  // 5) per-chunk transition/output operators (parallel, 512 thr)
  make_MBG<<<dim3(NC_, HV_), 512, 0, stream>>>(
      Wtg, pQg, Ug, Mqg, khat, cgbuf, Mhi, Mlo, Bg, Gtg);
  // 6) sequential state scan (128 blocks, M+B reg-prefetched)
  scan_S<<<128, 512, 0, stream>>>(Mhi, Mlo, Bg, Sg);
  // 7) w_o^T cast (Mhi region now dead)
  transpose_bf16<<<dim3(32, 32), 256, 0, stream>>>(w_o, wot, VD_, H_);
  // 8) per-chunk outputs (parallel)
  chunk_out<<<dim3(NC_, HV_), 256, 0, stream>>>(Mqg, Ug, Gtg, Sg, obuf);
  // 9) gated rmsnorm -> bf16 h (permuted)
  gated_rmsnorm<<<dim3(T_, HV_), 128, 0, stream>>>(obuf, zbuf, norm_w, hb);
  // 10) out = h @ w_o
  gemm_bf16<<<256, 256, 0, stream>>>(hb, wot, out, VD_, out, VD_,
                                     VD_, T_, VD_, H_);
}

// Round 16
// 243.327 us; speedup vs baseline: 1.1098x; 1.0146x over previous
//
#include <hip/hip_runtime.h>
#include <math.h>

typedef unsigned short u16;
using us4  = __attribute__((ext_vector_type(4))) unsigned short;
using us8  = __attribute__((ext_vector_type(8))) unsigned short;
using bf16x8 = __attribute__((ext_vector_type(8))) __bf16;
using f32x4v = __attribute__((ext_vector_type(4))) float;

// Problem constants
#define T_    1024
#define H_    2048
#define HK_   8
#define HV_   16
#define KD_   1024
#define VD_   2048
#define CD_   4096
#define QN_   6144   // 2*KD + 2*VD
#define NC_   16     // number of chunks
#define C_    64     // chunk length

__device__ __forceinline__ u16 f2bf(float f) {
  unsigned u = __float_as_uint(f);
  u += 0x7fffu + ((u >> 16) & 1u);   // RNE
  return (u16)(u >> 16);
}
__device__ __forceinline__ float bf2f(u16 h) {
  return __uint_as_float(((unsigned)h) << 16);
}
// staging layout for gemm: within each 64-elem k-group, 8-elem chunk c of
// row r is stored at chunk position c ^ (r&7).
__device__ __forceinline__ int permk3(int r, int k) {
  return (k & ~63) | ((((k >> 3) & 7) ^ (r & 7)) << 3) | (k & 7);
}

// ---------------------------------------------------------------------------
// x f32 -> bf16 with chunk permutation (row length 2048)
// ---------------------------------------------------------------------------
__global__ void cast_bf16(const float* __restrict__ in, u16* __restrict__ out,
                          int n8) {
  int i = blockIdx.x * 256 + threadIdx.x;   // 16B-chunk index
  if (i >= n8) return;
  float4 a = ((const float4*)in)[i * 2];
  float4 b = ((const float4*)in)[i * 2 + 1];
  us8 r = {f2bf(a.x), f2bf(a.y), f2bf(a.z), f2bf(a.w),
           f2bf(b.x), f2bf(b.y), f2bf(b.z), f2bf(b.w)};
  const int row = i >> 8;                   // 2048/8 = 256 chunks per row
  const int ip = (i & ~7) | ((i & 7) ^ (row & 7));
  *(us8*)&out[(size_t)ip * 8] = r;
}

// ---------------------------------------------------------------------------
// f32 [R][C] -> bf16 [C][R] transpose + cast + chunk permutation
// ---------------------------------------------------------------------------
__global__ __launch_bounds__(256) void transpose_bf16(
    const float* __restrict__ in, u16* __restrict__ out, int R, int C) {
  __shared__ float tile[64][65];
  const int r0 = blockIdx.x * 64, c0 = blockIdx.y * 64;
  const int t = threadIdx.x;
  const int tr = t >> 4, tc4 = (t & 15) * 4;
#pragma unroll
  for (int i = 0; i < 4; ++i) {
    float4 v = *(const float4*)&in[(size_t)(r0 + tr + i * 16) * C + c0 + tc4];
    tile[tr + i * 16][tc4 + 0] = v.x;
    tile[tr + i * 16][tc4 + 1] = v.y;
    tile[tr + i * 16][tc4 + 2] = v.z;
    tile[tr + i * 16][tc4 + 3] = v.w;
  }
  __syncthreads();
#pragma unroll
  for (int i = 0; i < 4; ++i) {
    int oc = tr + i * 16;
    int row = c0 + oc;
    int k = r0 + tc4;
    us4 w = {f2bf(tile[tc4 + 0][oc]), f2bf(tile[tc4 + 1][oc]),
             f2bf(tile[tc4 + 2][oc]), f2bf(tile[tc4 + 3][oc])};
    *(us4*)&out[(size_t)row * R + permk3(row, k)] = w;
  }
}

// ---------------------------------------------------------------------------
// bf16 MFMA GEMM: C = A[M,K] @ Bt[N,K]^T, f32 out. 128x64 tile, BK=64,
// 2-buffer counted-vmcnt pipeline, XCD-grouped 1D block mapping,
// 3-bit permuted staging. Output routed to Cq (cols < zsplit) or Cz.
// ---------------------------------------------------------------------------
__device__ __forceinline__ void gload_lds16(const void* g, void* l) {
  __builtin_amdgcn_global_load_lds(
      (const __attribute__((address_space(1))) void*)g,
      (__attribute__((address_space(3))) void*)l, 16, 0, 0);
}

__global__ __launch_bounds__(256) void gemm_bf16(
    const u16* __restrict__ A, const u16* __restrict__ Bt,
    float* __restrict__ Cq, int ldq, float* __restrict__ Cz, int ldz,
    int zsplit, int M, int N, int K) {
  __shared__ __align__(16) u16 As[2][8192];   // [128][64]
  __shared__ __align__(16) u16 Bs[2][4096];   // [64][64]
  const int tid  = threadIdx.x;
  const int wave = tid >> 6, lane = tid & 63;
  const int gy = N >> 6;
  const int ncolpx = gy >> 3;
  const int bid = blockIdx.x;
  const int xcd = bid & 7, idx = bid >> 3;
  const int row0 = (idx / ncolpx) * 128;
  const int col0 = (xcd * ncolpx + idx % ncolpx) * 64;
  const int wr = wave >> 1, wc = wave & 1;
  const int fr = lane & 15, fq = lane >> 4;

  const int sr8 = lane >> 3;
  const int sc8 = (lane & 7) * 8;
  const u16* gA = A  + (size_t)(row0 + wave * 32 + sr8) * K + sc8;
  const u16* gB = Bt + (size_t)(col0 + wave * 16 + sr8) * K + sc8;

  f32x4v acc[4][2] = {};
  const int nt = K >> 6;

  auto stage = [&](int p, int k0) {
#pragma unroll
    for (int j = 0; j < 4; ++j)
      gload_lds16(gA + (size_t)(j * 8) * K + k0,
                  &As[p][(wave * 32 + j * 8) * 64]);
#pragma unroll
    for (int j = 0; j < 2; ++j)
      gload_lds16(gB + (size_t)(j * 8) * K + k0,
                  &Bs[p][(wave * 16 + j * 8) * 64]);
  };

  stage(0, 0);

  int p = 0;
  for (int it = 0; it < nt; ++it) {
    if (it + 1 < nt) stage(p ^ 1, (it + 1) * 64);
    if (it + 1 < nt) asm volatile("s_waitcnt vmcnt(6)" ::: "memory");
    else             asm volatile("s_waitcnt vmcnt(0)" ::: "memory");
    __builtin_amdgcn_s_barrier();

#pragma unroll
    for (int kt = 0; kt < 2; ++kt) {
      bf16x8 af[4], bff[2];
#pragma unroll
      for (int mi = 0; mi < 4; ++mi) {
        const int r = wr * 64 + mi * 16 + fr;
        af[mi] = *(const bf16x8*)
            &As[p][r * 64 + kt * 32 + (((kt * 4 + fq) ^ (r & 7)) & 3) * 8
                   + ((((kt * 4 + fq) ^ (r & 7)) >> 2) - kt) * 32];
      }
#pragma unroll
      for (int ni = 0; ni < 2; ++ni) {
        const int r = wc * 32 + ni * 16 + fr;
        bff[ni] = *(const bf16x8*)
            &Bs[p][r * 64 + kt * 32 + (((kt * 4 + fq) ^ (r & 7)) & 3) * 8
                   + ((((kt * 4 + fq) ^ (r & 7)) >> 2) - kt) * 32];
      }
#pragma unroll
      for (int mi = 0; mi < 4; ++mi)
#pragma unroll
        for (int ni = 0; ni < 2; ++ni)
          acc[mi][ni] = __builtin_amdgcn_mfma_f32_16x16x32_bf16(
              af[mi], bff[ni], acc[mi][ni], 0, 0, 0);
    }
    if (it + 1 < nt) {
      asm volatile("s_waitcnt lgkmcnt(0)" ::: "memory");
      __builtin_amdgcn_s_barrier();
    }
    p ^= 1;
  }

  float* Cp; int ldc, cb;
  if (col0 < zsplit) { Cp = Cq; ldc = ldq; cb = col0; }
  else               { Cp = Cz; ldc = ldz; cb = col0 - zsplit; }
#pragma unroll
  for (int mi = 0; mi < 4; ++mi)
#pragma unroll
    for (int ni = 0; ni < 2; ++ni) {
      const int r  = row0 + wr * 64 + mi * 16 + fq * 4;
      const int cc = cb + wc * 32 + ni * 16 + fr;
#pragma unroll
      for (int j = 0; j < 4; ++j)
        Cp[(size_t)(r + j) * ldc + cc] = acc[mi][ni][j];
    }
}

// ---------------------------------------------------------------------------
// ba = x @ w_ba -> beta = sigmoid(b), g = -exp(a_log)*softplus(a+dt_bias)
// ---------------------------------------------------------------------------
__global__ __launch_bounds__(256) void ba_gbeta(
    const float* __restrict__ x, const float* __restrict__ w_ba,
    const float* __restrict__ a_log, const float* __restrict__ dt_bias,
    float* __restrict__ g, float* __restrict__ beta) {
  const int t = blockIdx.x;
  const int tid = threadIdx.x;
  __shared__ float xs[2048];
  __shared__ float red[8][32];
  {
    float4 v = *(const float4*)&x[(size_t)t * H_ + tid * 4];
    *(float4*)&xs[tid * 4] = v;
    float4 w = *(const float4*)&x[(size_t)t * H_ + 1024 + tid * 4];
    *(float4*)&xs[1024 + tid * 4] = w;
  }
  __syncthreads();
  const int c = tid & 31;
  const int chunk = tid >> 5;
  float p = 0.f;
  const int kb = chunk * 256;
#pragma unroll 4
  for (int k = kb; k < kb + 256; ++k) p = fmaf(xs[k], w_ba[k * 32 + c], p);
  red[chunk][c] = p;
  __syncthreads();
  if (tid < 32) {
    float s = 0.f;
#pragma unroll
    for (int i = 0; i < 8; ++i) s += red[i][c];
    if (c < 16) {
      beta[t * 16 + c] = 1.f / (1.f + expf(-s));
    } else {
      int h = c - 16;
      float xx = s + dt_bias[h];
      float sp = xx > 20.f ? xx : log1pf(expf(xx));
      g[t * 16 + h] = -expf(a_log[h]) * sp;
    }
  }
}

// ---------------------------------------------------------------------------
// fused causal depthwise conv1d (K=4) + SiLU + k-l2norm.
// ---------------------------------------------------------------------------
__global__ __launch_bounds__(512) void conv_silu_k(
    const float* __restrict__ qkvraw, const float* __restrict__ conv_w,
    const float* __restrict__ conv_b, float* __restrict__ qkvc,
    float* __restrict__ khat) {
  const int t = blockIdx.x;
  const int tid = threadIdx.x;
  const int c0 = tid * 8;
  float acc[8];
  float4 cb0 = *(const float4*)&conv_b[c0];
  float4 cb1 = *(const float4*)&conv_b[c0 + 4];
  acc[0] = cb0.x; acc[1] = cb0.y; acc[2] = cb0.z; acc[3] = cb0.w;
  acc[4] = cb1.x; acc[5] = cb1.y; acc[6] = cb1.z; acc[7] = cb1.w;
  float wv[8][4];
#pragma unroll
  for (int i = 0; i < 8; i += 2) {
    float4 w0 = *(const float4*)&conv_w[(c0 + i) * 4];
    float4 w1 = *(const float4*)&conv_w[(c0 + i + 1) * 4];
    wv[i][0] = w0.x; wv[i][1] = w0.y; wv[i][2] = w0.z; wv[i][3] = w0.w;
    wv[i+1][0] = w1.x; wv[i+1][1] = w1.y; wv[i+1][2] = w1.z; wv[i+1][3] = w1.w;
  }
#pragma unroll
  for (int j = 0; j < 4; ++j) {
    int tt = t - 3 + j;
    if (tt >= 0) {
      float4 a = *(const float4*)&qkvraw[(size_t)tt * CD_ + c0];
      float4 b = *(const float4*)&qkvraw[(size_t)tt * CD_ + c0 + 4];
      float xv[8] = {a.x, a.y, a.z, a.w, b.x, b.y, b.z, b.w};
#pragma unroll
      for (int i = 0; i < 8; ++i) acc[i] = fmaf(xv[i], wv[i][j], acc[i]);
    }
  }
  float y[8];
#pragma unroll
  for (int i = 0; i < 8; ++i) y[i] = acc[i] / (1.f + expf(-acc[i]));

  if (tid < 128 || tid >= 256) {
    float4 o0 = {y[0], y[1], y[2], y[3]};
    float4 o1 = {y[4], y[5], y[6], y[7]};
    *(float4*)&qkvc[(size_t)t * CD_ + c0]     = o0;
    *(float4*)&qkvc[(size_t)t * CD_ + c0 + 4] = o1;
  } else {
    float ss = 0.f;
#pragma unroll
    for (int i = 0; i < 8; ++i) ss = fmaf(y[i], y[i], ss);
#pragma unroll
    for (int off = 1; off < 16; off <<= 1) ss += __shfl_xor(ss, off);
    float rs = rsqrtf(ss + 1e-6f);
    const int head = (c0 - 1024) >> 7;
    const int d0 = (c0 - 1024) & 127;
    float4 o0 = {y[0] * rs, y[1] * rs, y[2] * rs, y[3] * rs};
    float4 o1 = {y[4] * rs, y[5] * rs, y[6] * rs, y[7] * rs};
    float* kout = &khat[((size_t)t * HK_ + head) * 128 + d0];
    *(float4*)&kout[0] = o0;
    *(float4*)&kout[4] = o1;
  }
}

// ---------------------------------------------------------------------------
// Chunked gated delta rule, phase A (parallel over 16 chunks x 16 heads).
// 512 threads (8 waves). Dot phase 4x2 tiles/thread; during the serial
// forward substitution (waves 0-3), waves 4-7 write Mqg and pQg.
// ---------------------------------------------------------------------------
#define SWZ(r) (((r) >> 2) & 7)

__device__ __forceinline__ float4 ldsw4(const float* base, int r, int dblk) {
  return *(const float4*)&base[r * 128 + ((dblk ^ SWZ(r)) << 2)];
}
__device__ __forceinline__ float ldsw1(const float* base, int r, int d) {
  return base[r * 128 + ((((d) >> 2) ^ SWZ(r)) << 2) + ((d) & 3)];
}

__global__ __launch_bounds__(512) void chunk_prep(
    const float* __restrict__ qkvc, const float* __restrict__ khat,
    const float* __restrict__ g, const float* __restrict__ beta,
    float* __restrict__ cgbuf, float* __restrict__ Wtg, float* __restrict__ Ug,
    float* __restrict__ Mqg, float* __restrict__ pQg) {
  const int c = blockIdx.x, hv = blockIdx.y, hk = hv >> 1;
  const int cid = c * 16 + hv;
  const int tid = threadIdx.x;
  __shared__ float Kl[8192], Ql[8192];   // swizzled [64][128]
  __shared__ float AM[8320];             // At[64][65] | Mq[64][65]; later Utr
  __shared__ float cgl[64], bl[64], bp[64], rsl[64];
  float* At = AM;
  float* Mq = AM + 4160;

#pragma unroll
  for (int it = 0; it < 4; ++it) {
    int flat = it * 2048 + tid * 4;
    int row = flat >> 7, d = flat & 127;
    int pb = ((d >> 2) ^ SWZ(row)) << 2;
    int gt = c * 64 + row;
    float4 kv = *(const float4*)&khat[((size_t)gt * HK_ + hk) * 128 + d];
    float4 qv = *(const float4*)&qkvc[(size_t)gt * CD_ + hk * 128 + d];
    *(float4*)&Kl[row * 128 + pb] = kv;
    *(float4*)&Ql[row * 128 + pb] = qv;
  }
  if (tid < 64) {
    float s = g[(size_t)(c * 64 + tid) * HV_ + hv];
#pragma unroll
    for (int off = 1; off < 64; off <<= 1) {
      float t = __shfl_up(s, off);
      if (tid >= off) s += t;
    }
    cgl[tid] = s;
    cgbuf[cid * 64 + tid] = s;
    bl[tid] = beta[(size_t)(c * 64 + tid) * HV_ + hv];
  }
  __syncthreads();
  if (tid < 64) {
    float sq = 0.f;
#pragma unroll
    for (int dblk = 0; dblk < 32; ++dblk) {
      float4 q4 = ldsw4(Ql, tid, dblk);
      sq = fmaf(q4.x, q4.x, sq); sq = fmaf(q4.y, q4.y, sq);
      sq = fmaf(q4.z, q4.z, sq); sq = fmaf(q4.w, q4.w, sq);
    }
    rsl[tid] = rsqrtf(sq + 1e-6f) * 0.08838834764831845f;
    bp[tid] = bl[tid] * expf(cgl[tid]);
  }
  __syncthreads();

  // dot phase: 4x2 tile of (i,j) pairs per thread (512 threads)
  const int i0 = (tid >> 5) * 4, j0 = (tid & 31) * 2;
  float kk[4][2], qk[4][2];
#pragma unroll
  for (int a = 0; a < 4; ++a)
#pragma unroll
    for (int b = 0; b < 2; ++b) { kk[a][b] = 0.f; qk[a][b] = 0.f; }
  for (int dblk = 0; dblk < 32; ++dblk) {
    float4 ka[4], qa[4], kb[2];
#pragma unroll
    for (int a = 0; a < 4; ++a) {
      ka[a] = ldsw4(Kl, i0 + a, dblk);
      qa[a] = ldsw4(Ql, i0 + a, dblk);
    }
#pragma unroll
    for (int b = 0; b < 2; ++b) kb[b] = ldsw4(Kl, j0 + b, dblk);
#pragma unroll
    for (int a = 0; a < 4; ++a)
#pragma unroll
      for (int b = 0; b < 2; ++b) {
        kk[a][b] = fmaf(ka[a].x, kb[b].x, kk[a][b]);
        kk[a][b] = fmaf(ka[a].y, kb[b].y, kk[a][b]);
        kk[a][b] = fmaf(ka[a].z, kb[b].z, kk[a][b]);
        kk[a][b] = fmaf(ka[a].w, kb[b].w, kk[a][b]);
        qk[a][b] = fmaf(qa[a].x, kb[b].x, qk[a][b]);
        qk[a][b] = fmaf(qa[a].y, kb[b].y, qk[a][b]);
        qk[a][b] = fmaf(qa[a].z, kb[b].z, qk[a][b]);
        qk[a][b] = fmaf(qa[a].w, kb[b].w, qk[a][b]);
      }
  }
#pragma unroll
  for (int a = 0; a < 4; ++a)
#pragma unroll
    for (int b = 0; b < 2; ++b) {
      int i = i0 + a, j = j0 + b;
      float e = expf(cgl[i] - cgl[j]);
      At[j * 65 + i] = (j < i) ? (-bl[i] * e * kk[a][b]) : 0.f;
      Mq[j * 65 + i] = (j <= i) ? (rsl[i] * e * qk[a][b]) : 0.f;
    }
  __syncthreads();

  float X[64];
  if (tid < 256) {
    // ---- waves 0-3: X init + forward substitution ----
    if (tid < 128) {
#pragma unroll
      for (int j = 0; j < 64; ++j) X[j] = bp[j] * ldsw1(Kl, j, tid);
    } else {
      const int m = tid - 128;
#pragma unroll
      for (int j = 0; j < 64; ++j)
        X[j] = bl[j] * qkvc[(size_t)(c * 64 + j) * CD_ + 2 * KD_ + hv * 128 + m];
    }
#pragma unroll
    for (int j = 0; j < 63; ++j) {
      float xj = X[j];
#pragma unroll
      for (int i = j + 1; i < 64; ++i) X[i] = fmaf(At[j * 65 + i], xj, X[i]);
    }
    if (tid < 128) {
      size_t baseo = ((size_t)cid * 128 + tid) * 64;
#pragma unroll
      for (int j4 = 0; j4 < 16; ++j4) {
        float4 v = {X[j4 * 4], X[j4 * 4 + 1], X[j4 * 4 + 2], X[j4 * 4 + 3]};
        *(float4*)&Wtg[baseo + j4 * 4] = v;
      }
    }
  } else {
    // ---- waves 4-7: Mqg + pQg writes (independent of solve) ----
    const int t2 = tid - 256;
#pragma unroll
    for (int it = 0; it < 16; ++it) {
      int f = it * 256 + t2;
      int j = f >> 6, i = f & 63;
      Mqg[(size_t)cid * 4096 + f] = Mq[j * 65 + i];
    }
    const int i = t2 & 63;
    const float ei = expf(cgl[i]) * rsl[i];
#pragma unroll
    for (int it = 0; it < 32; ++it) {
      int d = it * 4 + (t2 >> 6);
      pQg[(size_t)cid * 8192 + d * 64 + i] = ei * ldsw1(Ql, i, d);
    }
  }
  __syncthreads();   // At/Mq dead; X (U cols) ready

  if (tid >= 128 && tid < 256) {
    const int m = tid - 128;
    float* Utr = AM;
#pragma unroll
    for (int j = 0; j < 64; ++j) Utr[j * 128 + m] = X[j];
  }
  __syncthreads();
  {
    const float* Utr = AM;
#pragma unroll
    for (int it = 0; it < 4; ++it) {
      int flat = it * 2048 + tid * 4;
      *(float4*)&Ug[(size_t)cid * 8192 + flat] = *(const float4*)&Utr[flat];
    }
  }
}

// ---------------------------------------------------------------------------
// make_MBG (parallel, 256 blocks, 512 threads)
// ---------------------------------------------------------------------------
__global__ __launch_bounds__(512) void make_MBG(
    const float* __restrict__ Wtg, const float* __restrict__ pQg,
    const float* __restrict__ Ug, const float* __restrict__ Mqg,
    const float* __restrict__ khat, const float* __restrict__ cgbuf,
    u16* __restrict__ Mhi, u16* __restrict__ Mlo,
    float* __restrict__ Bg, float* __restrict__ Gtg) {
  const int c = blockIdx.x, hv = blockIdx.y, hk = hv >> 1;
  const int cid = c * 16 + hv;
  const int tid = threadIdx.x;
  __shared__ float Wl[64 * 128];   // W[j][d]
  __shared__ float Kel[64 * 128];  // esc_j * khat_j[d]
  __shared__ float Ul[64 * 128];
  __shared__ float Mql[64 * 64];
  const float cg63 = cgbuf[cid * 64 + 63];
  const float pC = expf(cg63);
#pragma unroll
  for (int it = 0; it < 4; ++it) {
    int f = it * 2048 + tid * 4;       // f = d*64 + j
    int d = f >> 6, j = f & 63;
    float4 w = *(const float4*)&Wtg[(size_t)cid * 8192 + f];
    Wl[(j + 0) * 128 + d] = w.x;
    Wl[(j + 1) * 128 + d] = w.y;
    Wl[(j + 2) * 128 + d] = w.z;
    Wl[(j + 3) * 128 + d] = w.w;
  }
#pragma unroll
  for (int it = 0; it < 4; ++it) {
    int f = it * 2048 + tid * 4;       // f = j*128 + d
    int j = f >> 7, d = f & 127;
    float esc = expf(cg63 - cgbuf[cid * 64 + j]);
    float4 kv = *(const float4*)&khat[((size_t)(c * 64 + j) * HK_ + hk) * 128 + d];
    float4 uv = *(const float4*)&Ug[(size_t)cid * 8192 + f];
    kv.x *= esc; kv.y *= esc; kv.z *= esc; kv.w *= esc;
    *(float4*)&Kel[f] = kv;
    *(float4*)&Ul[f] = uv;
  }
#pragma unroll
  for (int it = 0; it < 2; ++it) {
    int f = it * 2048 + tid * 4;
    *(float4*)&Mql[f] = *(const float4*)&Mqg[(size_t)cid * 4096 + f];
  }
  __syncthreads();

  // fused M+B: tile rows d0..d0+7, cols n0..n0+3
  const int d0 = (tid & 15) * 8, n0 = (tid >> 4) * 4;
  float ma[8][4] = {}, ba[8][4] = {};
  for (int j = 0; j < 64; ++j) {
    float4 k0 = *(const float4*)&Kel[j * 128 + d0];
    float4 k1 = *(const float4*)&Kel[j * 128 + d0 + 4];
    float4 w0 = *(const float4*)&Wl[j * 128 + n0];
    float4 u0 = *(const float4*)&Ul[j * 128 + n0];
    float ke[8] = {k0.x, k0.y, k0.z, k0.w, k1.x, k1.y, k1.z, k1.w};
    float wv[4] = {w0.x, w0.y, w0.z, w0.w};
    float uv[4] = {u0.x, u0.y, u0.z, u0.w};
#pragma unroll
    for (int a = 0; a < 8; ++a)
#pragma unroll
      for (int b = 0; b < 4; ++b) {
        ma[a][b] = fmaf(ke[a], wv[b], ma[a][b]);
        ba[a][b] = fmaf(ke[a], uv[b], ba[a][b]);
      }
  }
#pragma unroll
  for (int a = 0; a < 8; ++a) {
    const int d = d0 + a;
    us4 hi, lo;
#pragma unroll
    for (int b = 0; b < 4; ++b) {
      float m = ((d == n0 + b) ? pC : 0.f) - ma[a][b];
      u16 h = f2bf(m);
      hi[b] = h;
      lo[b] = f2bf(m - bf2f(h));
    }
    *(us4*)&Mhi[(size_t)cid * 16384 + d * 128 + n0] = hi;
    *(us4*)&Mlo[(size_t)cid * 16384 + d * 128 + n0] = lo;
    float4 b0 = {ba[a][0], ba[a][1], ba[a][2], ba[a][3]};
    *(float4*)&Bg[(size_t)cid * 16384 + d * 128 + n0] = b0;
  }

  // G phase: Gt[d][i] tile 4d x 4i
  const int dg = (tid & 31) * 4, ig = (tid >> 5) * 4;
  float ga[4][4] = {};
  for (int j = 0; j < 64; ++j) {
    float4 w4 = *(const float4*)&Wl[j * 128 + dg];
    float4 m0 = *(const float4*)&Mql[j * 64 + ig];
    float wv[4] = {w4.x, w4.y, w4.z, w4.w};
    float mv[4] = {m0.x, m0.y, m0.z, m0.w};
#pragma unroll
    for (int a = 0; a < 4; ++a)
#pragma unroll
      for (int b = 0; b < 4; ++b) ga[a][b] = fmaf(wv[a], mv[b], ga[a][b]);
  }
#pragma unroll
  for (int a = 0; a < 4; ++a) {
    const int d = dg + a;
    float4 p0 = *(const float4*)&pQg[(size_t)cid * 8192 + d * 64 + ig];
    float4 g0 = {p0.x - ga[a][0], p0.y - ga[a][1], p0.z - ga[a][2], p0.w - ga[a][3]};
    *(float4*)&Gtg[(size_t)cid * 8192 + d * 64 + ig] = g0;
  }
}

// ---------------------------------------------------------------------------
// scan_S v4: 128 blocks = 16 heads x 8 col-slices of 16, XCD-grouped
// (flat%8 == hv%8 so all 8 slices of a head share one L2 copy of M).
// M AND B both register-prefetched one chunk ahead (named double buffers).
// ---------------------------------------------------------------------------
__global__ __launch_bounds__(512) void scan_S(
    const u16* __restrict__ Mhi, const u16* __restrict__ Mlo,
    const float* __restrict__ Bg, float* __restrict__ Sg) {
  const int flat = blockIdx.x;
  const int hv = (flat & 7) + 8 * (flat >> 6);
  const int vs = (flat >> 3) & 7;
  const int tid = threadIdx.x;
  const int wave = tid >> 6, lane = tid & 63;
  const int fr = lane & 15, fq = lane >> 4;
  const int wr = wave * 16;       // this wave's 16 output rows
  const int m0 = vs * 16;         // col-slice base

  __shared__ u16 Sh[2][2048];     // [16 m][128 k] bf16-hi, XOR-swizzled
  __shared__ u16 Sl[2][2048];

  for (int i = tid; i < 2048; i += 512) { Sh[0][i] = 0; Sl[0][i] = 0; }
  {
    float* s0 = Sg + (size_t)hv * 16384 + m0;
#pragma unroll
    for (int it = 0; it < 4; ++it) {
      int idx = it * 512 + tid;          // 2048 = 128 d x 16 m
      s0[(size_t)(idx >> 4) * 128 + (idx & 15)] = 0.f;
    }
  }
  __syncthreads();

  bf16x8 MhA[4], MlA[4], MhB[4], MlB[4];
  float bvA[4], bvB[4];
  {
    const u16* Mh0 = Mhi + (size_t)hv * 16384;
    const u16* Ml0 = Mlo + (size_t)hv * 16384;
#pragma unroll
    for (int kt = 0; kt < 4; ++kt) {
      size_t off = (size_t)(wr + fr) * 128 + kt * 32 + fq * 8;
      MhA[kt] = *(const bf16x8*)&Mh0[off];
      MlA[kt] = *(const bf16x8*)&Ml0[off];
    }
    const float* Bc = Bg + (size_t)hv * 16384 + m0;
#pragma unroll
    for (int j = 0; j < 4; ++j)
      bvA[j] = Bc[(size_t)(wr + fq * 4 + j) * 128 + fr];
  }
  int p = 0;

  auto step = [&](int c, bf16x8 (&MhC)[4], bf16x8 (&MlC)[4], float (&bvC)[4],
                  bf16x8 (&MhN)[4], bf16x8 (&MlN)[4], float (&bvN)[4]) {
    // prefetch next chunk's M frags + B values (consumed next step)
    if (c + 1 < NC_ - 1) {
      const u16* MhP = Mhi + (size_t)((c + 1) * 16 + hv) * 16384;
      const u16* MlP = Mlo + (size_t)((c + 1) * 16 + hv) * 16384;
#pragma unroll
      for (int kt = 0; kt < 4; ++kt) {
        size_t off = (size_t)(wr + fr) * 128 + kt * 32 + fq * 8;
        MhN[kt] = *(const bf16x8*)&MhP[off];
        MlN[kt] = *(const bf16x8*)&MlP[off];
      }
      const float* BcN = Bg + (size_t)((c + 1) * 16 + hv) * 16384 + m0;
#pragma unroll
      for (int j = 0; j < 4; ++j)
        bvN[j] = BcN[(size_t)(wr + fq * 4 + j) * 128 + fr];
    }

    // acc = M_c @ S_c  (bf16 hi/lo x3), 16-col slice: single B fragment
    f32x4v acc = {};
#pragma unroll
    for (int kt = 0; kt < 4; ++kt) {
      const int m = fr;
      const int byte = m * 256 + ((kt * 64 + fq * 16) ^ ((m & 7) << 4));
      bf16x8 BhF = *(const bf16x8*)((const char*)&Sh[p][0] + byte);
      bf16x8 BlF = *(const bf16x8*)((const char*)&Sl[p][0] + byte);
      acc = __builtin_amdgcn_mfma_f32_16x16x32_bf16(MlC[kt], BhF, acc, 0, 0, 0);
      acc = __builtin_amdgcn_mfma_f32_16x16x32_bf16(MhC[kt], BlF, acc, 0, 0, 0);
      acc = __builtin_amdgcn_mfma_f32_16x16x32_bf16(MhC[kt], BhF, acc, 0, 0, 0);
    }

    // S_{c+1} = acc + B (B from registers, prefetched last step)
    float* Sn = Sg + (size_t)((c + 1) * 16 + hv) * 16384 + m0;
    const int k0 = wr + fq * 4;
    const int m = fr;
    us4 h4, l4;
#pragma unroll
    for (int j = 0; j < 4; ++j) {
      float v = acc[j] + bvC[j];
      Sn[(size_t)(k0 + j) * 128 + m] = v;
      u16 h = f2bf(v);
      h4[j] = h;
      l4[j] = f2bf(v - bf2f(h));
    }
    const int wbyte = m * 256 + ((k0 * 2) ^ ((m & 7) << 4));
    *(us4*)((char*)&Sh[p ^ 1][0] + wbyte) = h4;
    *(us4*)((char*)&Sl[p ^ 1][0] + wbyte) = l4;
    __syncthreads();
    p ^= 1;
  };

  for (int cc = 0; cc < NC_ - 1; cc += 2) {
    step(cc, MhA, MlA, bvA, MhB, MlB, bvB);
    if (cc + 1 < NC_ - 1) step(cc + 1, MhB, MlB, bvB, MhA, MlA, bvA);
  }
}

// ---------------------------------------------------------------------------
// chunk_out + fused gated rmsnorm (parallel, 256 blocks):
//   o_i[m] = sum_j Mq[j][i] U[j][m] + sum_d Gt[d][i] S[d][m]
//   h = o*silu(z); h *= rsqrt(mean_m(h^2)+eps)*norm_w; -> bf16 (permuted)
// ---------------------------------------------------------------------------
__global__ __launch_bounds__(256) void chunk_out(
    const float* __restrict__ Mqg, const float* __restrict__ Ug,
    const float* __restrict__ Gtg, const float* __restrict__ Sg,
    const float* __restrict__ zbuf, const float* __restrict__ norm_w,
    u16* __restrict__ h) {
  const int c = blockIdx.x, hv = blockIdx.y;
  const int cid = c * 16 + hv;
  const int tid = threadIdx.x;
  __shared__ float Mql[64 * 64];
  __shared__ float Ul[64 * 128];
  __shared__ float Gtl[128 * 64];
  __shared__ float Sl[128 * 128];
  __shared__ float red[64][16];
#pragma unroll
  for (int it = 0; it < 4; ++it) {
    int f = it * 1024 + tid * 4;
    *(float4*)&Mql[f] = *(const float4*)&Mqg[(size_t)cid * 4096 + f];
  }
#pragma unroll
  for (int it = 0; it < 8; ++it) {
    int f = it * 1024 + tid * 4;
    *(float4*)&Ul[f]  = *(const float4*)&Ug[(size_t)cid * 8192 + f];
    *(float4*)&Gtl[f] = *(const float4*)&Gtg[(size_t)cid * 8192 + f];
  }
#pragma unroll
  for (int it = 0; it < 16; ++it) {
    int f = it * 1024 + tid * 4;
    *(float4*)&Sl[f] = *(const float4*)&Sg[(size_t)cid * 16384 + f];
  }
  __syncthreads();

  const int i0 = (tid & 15) * 4, m0 = (tid >> 4) * 8;
  float oa[4][8] = {};
  for (int j = 0; j < 64; ++j) {
    float4 mq = *(const float4*)&Mql[j * 64 + i0];
    float4 u0 = *(const float4*)&Ul[j * 128 + m0];
    float4 u1 = *(const float4*)&Ul[j * 128 + m0 + 4];
    float mv[4] = {mq.x, mq.y, mq.z, mq.w};
    float uv[8] = {u0.x, u0.y, u0.z, u0.w, u1.x, u1.y, u1.z, u1.w};
#pragma unroll
    for (int a = 0; a < 4; ++a)
#pragma unroll
      for (int b = 0; b < 8; ++b) oa[a][b] = fmaf(mv[a], uv[b], oa[a][b]);
  }
  for (int d = 0; d < 128; ++d) {
    float4 gt = *(const float4*)&Gtl[d * 64 + i0];
    float4 s0 = *(const float4*)&Sl[d * 128 + m0];
    float4 s1 = *(const float4*)&Sl[d * 128 + m0 + 4];
    float gv[4] = {gt.x, gt.y, gt.z, gt.w};
    float sv[8] = {s0.x, s0.y, s0.z, s0.w, s1.x, s1.y, s1.z, s1.w};
#pragma unroll
    for (int a = 0; a < 4; ++a)
#pragma unroll
      for (int b = 0; b < 8; ++b) oa[a][b] = fmaf(gv[a], sv[b], oa[a][b]);
  }

  // ---- fused gated rmsnorm over the m-dimension (per row) ----
  float hva[4][8];
#pragma unroll
  for (int a = 0; a < 4; ++a) {
    const int t = c * 64 + i0 + a;
    float4 z0 = *(const float4*)&zbuf[(size_t)t * VD_ + hv * 128 + m0];
    float4 z1 = *(const float4*)&zbuf[(size_t)t * VD_ + hv * 128 + m0 + 4];
    float zv[8] = {z0.x, z0.y, z0.z, z0.w, z1.x, z1.y, z1.z, z1.w};
    float ss = 0.f;
#pragma unroll
    for (int b = 0; b < 8; ++b) {
      float hc = oa[a][b] * (zv[b] / (1.f + expf(-zv[b])));
      hva[a][b] = hc;
      ss = fmaf(hc, hc, ss);
    }
    red[i0 + a][tid >> 4] = ss;
  }
  __syncthreads();
  float4 nw0 = *(const float4*)&norm_w[m0];
  float4 nw1 = *(const float4*)&norm_w[m0 + 4];
  float nw[8] = {nw0.x, nw0.y, nw0.z, nw0.w, nw1.x, nw1.y, nw1.z, nw1.w};
#pragma unroll
  for (int a = 0; a < 4; ++a) {
    const int t = c * 64 + i0 + a;
    float tot = 0.f;
#pragma unroll
    for (int w = 0; w < 16; ++w) tot += red[i0 + a][w];
    float r = rsqrtf(tot * (1.f / 128.f) + 1e-6f);
    us8 hv8;
#pragma unroll
    for (int b = 0; b < 8; ++b) hv8[b] = f2bf(hva[a][b] * r * nw[b]);
    *(us8*)&h[(size_t)t * VD_ + permk3(t, hv * 128 + m0)] = hv8;
  }
}

// ---------------------------------------------------------------------------
extern "C" void kernel_launch(void* const* d_in, const int* in_sizes, int n_in,
                              void* d_out, int out_size, void* d_ws, size_t ws_size,
                              hipStream_t stream) {
  const float* x       = (const float*)d_in[0];
  const float* w_qkvz  = (const float*)d_in[1];
  const float* w_ba    = (const float*)d_in[2];
  const float* conv_w  = (const float*)d_in[3];
  const float* conv_b  = (const float*)d_in[4];
  const float* a_log   = (const float*)d_in[5];
  const float* dt_bias = (const float*)d_in[6];
  const float* norm_w  = (const float*)d_in[7];
  const float* w_o     = (const float*)d_in[8];
  float* out = (float*)d_out;

  float* ws = (float*)d_ws;
  float* qkvraw = ws;                  // 4,194,304  (-> Bg)
  float* zbuf   = ws + 4194304;        // 2,097,152
  float* qkvc   = ws + 6291456;        // 4,194,304  (-> Mhi|Mlo, -> wot)
  float* khat   = ws + 10485760;       // 1,048,576  (-> hb)
  float* gbuf   = ws + 11534336;       // 16,384
  float* bbuf   = ws + 11550720;       // 16,384
  float* cgbuf  = ws + 11567104;       // 16,384
  float* obuf   = ws + 11583488;       // 2,097,152  (xb early)
  float* Wtg    = ws + 13680640;       // 2,097,152 ┐ -> Sg (4,194,304)
  float* pQg    = ws + 15777792;       // 2,097,152 ┘
  float* Ug     = ws + 17874944;       // 2,097,152
  float* Mqg    = ws + 19972096;       // 1,048,576
  float* Gtg    = ws + 21020672;       // 2,097,152

  u16* xb   = (u16*)obuf;      // x bf16 (dead after gemm1)
  u16* wqt  = (u16*)Wtg;       // w_qkvz^T bf16 (dead after gemm1)
  u16* Mhi  = (u16*)qkvc;
  u16* Mlo  = (u16*)(qkvc + 2097152);
  float* Bg = qkvraw;
  float* Sg = Wtg;
  u16* wot  = (u16*)qkvc;      // after scan_S (Mhi dead)
  u16* hb   = (u16*)khat;      // after make_MBG (khat dead)

  // 0) casts (permuted staging layout)
  cast_bf16<<<1024, 256, 0, stream>>>(x, xb, 262144);
  transpose_bf16<<<dim3(32, 96), 256, 0, stream>>>(w_qkvz, wqt, H_, QN_);
  // 1) qkv|z = x @ w_qkvz
  gemm_bf16<<<768, 256, 0, stream>>>(xb, wqt, qkvraw, CD_, zbuf, VD_,
                                     CD_, T_, QN_, H_);
  // 2) beta / g
  ba_gbeta<<<T_, 256, 0, stream>>>(x, w_ba, a_log, dt_bias, gbuf, bbuf);
  // 3) fused conv + silu + k-l2norm
  conv_silu_k<<<T_, 512, 0, stream>>>(qkvraw, conv_w, conv_b, qkvc, khat);
  // 4) chunk-local precompute (parallel, 512 thr)
  chunk_prep<<<dim3(NC_, HV_), 512, 0, stream>>>(
      qkvc, khat, gbuf, bbuf, cgbuf, Wtg, Ug, Mqg, pQg);
  // 5) per-chunk transition/output operators (parallel, 512 thr)
  make_MBG<<<dim3(NC_, HV_), 512, 0, stream>>>(
      Wtg, pQg, Ug, Mqg, khat, cgbuf, Mhi, Mlo, Bg, Gtg);
  // 6) sequential state scan (128 blocks, M+B reg-prefetched)
  scan_S<<<128, 512, 0, stream>>>(Mhi, Mlo, Bg, Sg);
  // 7) w_o^T cast (Mhi region now dead)
  transpose_bf16<<<dim3(32, 32), 256, 0, stream>>>(w_o, wot, VD_, H_);
  // 8) per-chunk outputs + fused gated rmsnorm -> bf16 h (permuted)
  chunk_out<<<dim3(NC_, HV_), 256, 0, stream>>>(
      Mqg, Ug, Gtg, Sg, zbuf, norm_w, hb);
  // 9) out = h @ w_o
  gemm_bf16<<<256, 256, 0, stream>>>(hb, wot, out, VD_, out, VD_,
                                     VD_, T_, VD_, H_);
}

// Round 17
// 237.627 us; speedup vs baseline: 1.1364x; 1.0240x over previous
//
#include <hip/hip_runtime.h>
#include <math.h>

typedef unsigned short u16;
using us4  = __attribute__((ext_vector_type(4))) unsigned short;
using us8  = __attribute__((ext_vector_type(8))) unsigned short;
using bf16x8 = __attribute__((ext_vector_type(8))) __bf16;
using f32x4v = __attribute__((ext_vector_type(4))) float;

// Problem constants
#define T_    1024
#define H_    2048
#define HK_   8
#define HV_   16
#define KD_   1024
#define VD_   2048
#define CD_   4096
#define QN_   6144   // 2*KD + 2*VD
#define NC_   16     // number of chunks
#define C_    64     // chunk length

__device__ __forceinline__ u16 f2bf(float f) {
  unsigned u = __float_as_uint(f);
  u += 0x7fffu + ((u >> 16) & 1u);   // RNE
  return (u16)(u >> 16);
}
__device__ __forceinline__ float bf2f(u16 h) {
  return __uint_as_float(((unsigned)h) << 16);
}
// staging layout for gemm: within each 64-elem k-group, 8-elem chunk c of
// row r is stored at chunk position c ^ (r&7).
__device__ __forceinline__ int permk3(int r, int k) {
  return (k & ~63) | ((((k >> 3) & 7) ^ (r & 7)) << 3) | (k & 7);
}

// ---------------------------------------------------------------------------
// x f32 -> bf16 with chunk permutation (row length 2048)
// ---------------------------------------------------------------------------
__global__ void cast_bf16(const float* __restrict__ in, u16* __restrict__ out,
                          int n8) {
  int i = blockIdx.x * 256 + threadIdx.x;   // 16B-chunk index
  if (i >= n8) return;
  float4 a = ((const float4*)in)[i * 2];
  float4 b = ((const float4*)in)[i * 2 + 1];
  us8 r = {f2bf(a.x), f2bf(a.y), f2bf(a.z), f2bf(a.w),
           f2bf(b.x), f2bf(b.y), f2bf(b.z), f2bf(b.w)};
  const int row = i >> 8;                   // 2048/8 = 256 chunks per row
  const int ip = (i & ~7) | ((i & 7) ^ (row & 7));
  *(us8*)&out[(size_t)ip * 8] = r;
}

// ---------------------------------------------------------------------------
// f32 [R][C] -> bf16 [C][R] transpose + cast + chunk permutation
// ---------------------------------------------------------------------------
__global__ __launch_bounds__(256) void transpose_bf16(
    const float* __restrict__ in, u16* __restrict__ out, int R, int C) {
  __shared__ float tile[64][65];
  const int r0 = blockIdx.x * 64, c0 = blockIdx.y * 64;
  const int t = threadIdx.x;
  const int tr = t >> 4, tc4 = (t & 15) * 4;
#pragma unroll
  for (int i = 0; i < 4; ++i) {
    float4 v = *(const float4*)&in[(size_t)(r0 + tr + i * 16) * C + c0 + tc4];
    tile[tr + i * 16][tc4 + 0] = v.x;
    tile[tr + i * 16][tc4 + 1] = v.y;
    tile[tr + i * 16][tc4 + 2] = v.z;
    tile[tr + i * 16][tc4 + 3] = v.w;
  }
  __syncthreads();
#pragma unroll
  for (int i = 0; i < 4; ++i) {
    int oc = tr + i * 16;
    int row = c0 + oc;
    int k = r0 + tc4;
    us4 w = {f2bf(tile[tc4 + 0][oc]), f2bf(tile[tc4 + 1][oc]),
             f2bf(tile[tc4 + 2][oc]), f2bf(tile[tc4 + 3][oc])};
    *(us4*)&out[(size_t)row * R + permk3(row, k)] = w;
  }
}

// ---------------------------------------------------------------------------
// bf16 MFMA GEMM: C = A[M,K] @ Bt[N,K]^T, f32 out. BMx64 tile, BK=64,
// 2-buffer counted-vmcnt pipeline, XCD-grouped 1D block mapping,
// 3-bit permuted staging. BM=128 (3 blk/CU) or BM=64 (more blocks, 2/CU).
// Output routed to Cq (cols < zsplit) or Cz.
// ---------------------------------------------------------------------------
__device__ __forceinline__ void gload_lds16(const void* g, void* l) {
  __builtin_amdgcn_global_load_lds(
      (const __attribute__((address_space(1))) void*)g,
      (__attribute__((address_space(3))) void*)l, 16, 0, 0);
}

template <int BM>
__global__ __launch_bounds__(256) void gemm_bf16(
    const u16* __restrict__ A, const u16* __restrict__ Bt,
    float* __restrict__ Cq, int ldq, float* __restrict__ Cz, int ldz,
    int zsplit, int M, int N, int K) {
  constexpr int MI = BM / 32;               // A-frags per wave
  __shared__ __align__(16) u16 As[2][BM * 64];
  __shared__ __align__(16) u16 Bs[2][4096];   // [64][64]
  const int tid  = threadIdx.x;
  const int wave = tid >> 6, lane = tid & 63;
  const int gy = N >> 6;
  const int ncolpx = gy >> 3;
  const int bid = blockIdx.x;
  const int xcd = bid & 7, idx = bid >> 3;
  const int row0 = (idx / ncolpx) * BM;
  const int col0 = (xcd * ncolpx + idx % ncolpx) * 64;
  const int wr = wave >> 1, wc = wave & 1;
  const int fr = lane & 15, fq = lane >> 4;

  const int sr8 = lane >> 3;
  const int sc8 = (lane & 7) * 8;
  const u16* gA = A  + (size_t)(row0 + wave * (BM / 4) + sr8) * K + sc8;
  const u16* gB = Bt + (size_t)(col0 + wave * 16 + sr8) * K + sc8;

  f32x4v acc[MI][2] = {};
  const int nt = K >> 6;

  // one stage issues (BM/32 + 2) global_load_lds per wave
  auto stage = [&](int p, int k0) {
#pragma unroll
    for (int j = 0; j < BM / 32; ++j)
      gload_lds16(gA + (size_t)(j * 8) * K + k0,
                  &As[p][(wave * (BM / 4) + j * 8) * 64]);
#pragma unroll
    for (int j = 0; j < 2; ++j)
      gload_lds16(gB + (size_t)(j * 8) * K + k0,
                  &Bs[p][(wave * 16 + j * 8) * 64]);
  };

  stage(0, 0);

  int p = 0;
  for (int it = 0; it < nt; ++it) {
    if (it + 1 < nt) stage(p ^ 1, (it + 1) * 64);
    if (it + 1 < nt) {
      if constexpr (BM == 128)
        asm volatile("s_waitcnt vmcnt(6)" ::: "memory");
      else
        asm volatile("s_waitcnt vmcnt(4)" ::: "memory");
    } else {
      asm volatile("s_waitcnt vmcnt(0)" ::: "memory");
    }
    __builtin_amdgcn_s_barrier();

#pragma unroll
    for (int kt = 0; kt < 2; ++kt) {
      bf16x8 af[MI], bff[2];
#pragma unroll
      for (int mi = 0; mi < MI; ++mi) {
        const int r = wr * (BM / 2) + mi * 16 + fr;
        af[mi] = *(const bf16x8*)
            &As[p][r * 64 + kt * 32 + (((kt * 4 + fq) ^ (r & 7)) & 3) * 8
                   + ((((kt * 4 + fq) ^ (r & 7)) >> 2) - kt) * 32];
      }
#pragma unroll
      for (int ni = 0; ni < 2; ++ni) {
        const int r = wc * 32 + ni * 16 + fr;
        bff[ni] = *(const bf16x8*)
            &Bs[p][r * 64 + kt * 32 + (((kt * 4 + fq) ^ (r & 7)) & 3) * 8
                   + ((((kt * 4 + fq) ^ (r & 7)) >> 2) - kt) * 32];
      }
#pragma unroll
      for (int mi = 0; mi < MI; ++mi)
#pragma unroll
        for (int ni = 0; ni < 2; ++ni)
          acc[mi][ni] = __builtin_amdgcn_mfma_f32_16x16x32_bf16(
              af[mi], bff[ni], acc[mi][ni], 0, 0, 0);
    }
    if (it + 1 < nt) {
      asm volatile("s_waitcnt lgkmcnt(0)" ::: "memory");
      __builtin_amdgcn_s_barrier();
    }
    p ^= 1;
  }

  float* Cp; int ldc, cb;
  if (col0 < zsplit) { Cp = Cq; ldc = ldq; cb = col0; }
  else               { Cp = Cz; ldc = ldz; cb = col0 - zsplit; }
#pragma unroll
  for (int mi = 0; mi < MI; ++mi)
#pragma unroll
    for (int ni = 0; ni < 2; ++ni) {
      const int r  = row0 + wr * (BM / 2) + mi * 16 + fq * 4;
      const int cc = cb + wc * 32 + ni * 16 + fr;
#pragma unroll
      for (int j = 0; j < 4; ++j)
        Cp[(size_t)(r + j) * ldc + cc] = acc[mi][ni][j];
    }
}

// ---------------------------------------------------------------------------
// ba = x @ w_ba -> beta = sigmoid(b), g = -exp(a_log)*softplus(a+dt_bias)
// ---------------------------------------------------------------------------
__global__ __launch_bounds__(256) void ba_gbeta(
    const float* __restrict__ x, const float* __restrict__ w_ba,
    const float* __restrict__ a_log, const float* __restrict__ dt_bias,
    float* __restrict__ g, float* __restrict__ beta) {
  const int t = blockIdx.x;
  const int tid = threadIdx.x;
  __shared__ float xs[2048];
  __shared__ float red[8][32];
  {
    float4 v = *(const float4*)&x[(size_t)t * H_ + tid * 4];
    *(float4*)&xs[tid * 4] = v;
    float4 w = *(const float4*)&x[(size_t)t * H_ + 1024 + tid * 4];
    *(float4*)&xs[1024 + tid * 4] = w;
  }
  __syncthreads();
  const int c = tid & 31;
  const int chunk = tid >> 5;
  float p = 0.f;
  const int kb = chunk * 256;
#pragma unroll 4
  for (int k = kb; k < kb + 256; ++k) p = fmaf(xs[k], w_ba[k * 32 + c], p);
  red[chunk][c] = p;
  __syncthreads();
  if (tid < 32) {
    float s = 0.f;
#pragma unroll
    for (int i = 0; i < 8; ++i) s += red[i][c];
    if (c < 16) {
      beta[t * 16 + c] = 1.f / (1.f + expf(-s));
    } else {
      int h = c - 16;
      float xx = s + dt_bias[h];
      float sp = xx > 20.f ? xx : log1pf(expf(xx));
      g[t * 16 + h] = -expf(a_log[h]) * sp;
    }
  }
}

// ---------------------------------------------------------------------------
// fused causal depthwise conv1d (K=4) + SiLU + k-l2norm.
// ---------------------------------------------------------------------------
__global__ __launch_bounds__(512) void conv_silu_k(
    const float* __restrict__ qkvraw, const float* __restrict__ conv_w,
    const float* __restrict__ conv_b, float* __restrict__ qkvc,
    float* __restrict__ khat) {
  const int t = blockIdx.x;
  const int tid = threadIdx.x;
  const int c0 = tid * 8;
  float acc[8];
  float4 cb0 = *(const float4*)&conv_b[c0];
  float4 cb1 = *(const float4*)&conv_b[c0 + 4];
  acc[0] = cb0.x; acc[1] = cb0.y; acc[2] = cb0.z; acc[3] = cb0.w;
  acc[4] = cb1.x; acc[5] = cb1.y; acc[6] = cb1.z; acc[7] = cb1.w;
  float wv[8][4];
#pragma unroll
  for (int i = 0; i < 8; i += 2) {
    float4 w0 = *(const float4*)&conv_w[(c0 + i) * 4];
    float4 w1 = *(const float4*)&conv_w[(c0 + i + 1) * 4];
    wv[i][0] = w0.x; wv[i][1] = w0.y; wv[i][2] = w0.z; wv[i][3] = w0.w;
    wv[i+1][0] = w1.x; wv[i+1][1] = w1.y; wv[i+1][2] = w1.z; wv[i+1][3] = w1.w;
  }
#pragma unroll
  for (int j = 0; j < 4; ++j) {
    int tt = t - 3 + j;
    if (tt >= 0) {
      float4 a = *(const float4*)&qkvraw[(size_t)tt * CD_ + c0];
      float4 b = *(const float4*)&qkvraw[(size_t)tt * CD_ + c0 + 4];
      float xv[8] = {a.x, a.y, a.z, a.w, b.x, b.y, b.z, b.w};
#pragma unroll
      for (int i = 0; i < 8; ++i) acc[i] = fmaf(xv[i], wv[i][j], acc[i]);
    }
  }
  float y[8];
#pragma unroll
  for (int i = 0; i < 8; ++i) y[i] = acc[i] / (1.f + expf(-acc[i]));

  if (tid < 128 || tid >= 256) {
    float4 o0 = {y[0], y[1], y[2], y[3]};
    float4 o1 = {y[4], y[5], y[6], y[7]};
    *(float4*)&qkvc[(size_t)t * CD_ + c0]     = o0;
    *(float4*)&qkvc[(size_t)t * CD_ + c0 + 4] = o1;
  } else {
    float ss = 0.f;
#pragma unroll
    for (int i = 0; i < 8; ++i) ss = fmaf(y[i], y[i], ss);
#pragma unroll
    for (int off = 1; off < 16; off <<= 1) ss += __shfl_xor(ss, off);
    float rs = rsqrtf(ss + 1e-6f);
    const int head = (c0 - 1024) >> 7;
    const int d0 = (c0 - 1024) & 127;
    float4 o0 = {y[0] * rs, y[1] * rs, y[2] * rs, y[3] * rs};
    float4 o1 = {y[4] * rs, y[5] * rs, y[6] * rs, y[7] * rs};
    float* kout = &khat[((size_t)t * HK_ + head) * 128 + d0];
    *(float4*)&kout[0] = o0;
    *(float4*)&kout[4] = o1;
  }
}

// ---------------------------------------------------------------------------
// Chunked gated delta rule, phase A (parallel over 16 chunks x 16 heads).
// 512 threads (8 waves). Dot phase 4x2 tiles/thread; during the serial
// forward substitution (waves 0-3), waves 4-7 write Mqg and pQg.
// ---------------------------------------------------------------------------
#define SWZ(r) (((r) >> 2) & 7)

__device__ __forceinline__ float4 ldsw4(const float* base, int r, int dblk) {
  return *(const float4*)&base[r * 128 + ((dblk ^ SWZ(r)) << 2)];
}
__device__ __forceinline__ float ldsw1(const float* base, int r, int d) {
  return base[r * 128 + ((((d) >> 2) ^ SWZ(r)) << 2) + ((d) & 3)];
}

__global__ __launch_bounds__(512) void chunk_prep(
    const float* __restrict__ qkvc, const float* __restrict__ khat,
    const float* __restrict__ g, const float* __restrict__ beta,
    float* __restrict__ cgbuf, float* __restrict__ Wtg, float* __restrict__ Ug,
    float* __restrict__ Mqg, float* __restrict__ pQg) {
  const int c = blockIdx.x, hv = blockIdx.y, hk = hv >> 1;
  const int cid = c * 16 + hv;
  const int tid = threadIdx.x;
  __shared__ float Kl[8192], Ql[8192];   // swizzled [64][128]
  __shared__ float AM[8320];             // At[64][65] | Mq[64][65]; later Utr
  __shared__ float cgl[64], bl[64], bp[64], rsl[64];
  float* At = AM;
  float* Mq = AM + 4160;

#pragma unroll
  for (int it = 0; it < 4; ++it) {
    int flat = it * 2048 + tid * 4;
    int row = flat >> 7, d = flat & 127;
    int pb = ((d >> 2) ^ SWZ(row)) << 2;
    int gt = c * 64 + row;
    float4 kv = *(const float4*)&khat[((size_t)gt * HK_ + hk) * 128 + d];
    float4 qv = *(const float4*)&qkvc[(size_t)gt * CD_ + hk * 128 + d];
    *(float4*)&Kl[row * 128 + pb] = kv;
    *(float4*)&Ql[row * 128 + pb] = qv;
  }
  if (tid < 64) {
    float s = g[(size_t)(c * 64 + tid) * HV_ + hv];
#pragma unroll
    for (int off = 1; off < 64; off <<= 1) {
      float t = __shfl_up(s, off);
      if (tid >= off) s += t;
    }
    cgl[tid] = s;
    cgbuf[cid * 64 + tid] = s;
    bl[tid] = beta[(size_t)(c * 64 + tid) * HV_ + hv];
  }
  __syncthreads();
  if (tid < 64) {
    float sq = 0.f;
#pragma unroll
    for (int dblk = 0; dblk < 32; ++dblk) {
      float4 q4 = ldsw4(Ql, tid, dblk);
      sq = fmaf(q4.x, q4.x, sq); sq = fmaf(q4.y, q4.y, sq);
      sq = fmaf(q4.z, q4.z, sq); sq = fmaf(q4.w, q4.w, sq);
    }
    rsl[tid] = rsqrtf(sq + 1e-6f) * 0.08838834764831845f;
    bp[tid] = bl[tid] * expf(cgl[tid]);
  }
  __syncthreads();

  // dot phase: 4x2 tile of (i,j) pairs per thread (512 threads)
  const int i0 = (tid >> 5) * 4, j0 = (tid & 31) * 2;
  float kk[4][2], qk[4][2];
#pragma unroll
  for (int a = 0; a < 4; ++a)
#pragma unroll
    for (int b = 0; b < 2; ++b) { kk[a][b] = 0.f; qk[a][b] = 0.f; }
  for (int dblk = 0; dblk < 32; ++dblk) {
    float4 ka[4], qa[4], kb[2];
#pragma unroll
    for (int a = 0; a < 4; ++a) {
      ka[a] = ldsw4(Kl, i0 + a, dblk);
      qa[a] = ldsw4(Ql, i0 + a, dblk);
    }
#pragma unroll
    for (int b = 0; b < 2; ++b) kb[b] = ldsw4(Kl, j0 + b, dblk);
#pragma unroll
    for (int a = 0; a < 4; ++a)
#pragma unroll
      for (int b = 0; b < 2; ++b) {
        kk[a][b] = fmaf(ka[a].x, kb[b].x, kk[a][b]);
        kk[a][b] = fmaf(ka[a].y, kb[b].y, kk[a][b]);
        kk[a][b] = fmaf(ka[a].z, kb[b].z, kk[a][b]);
        kk[a][b] = fmaf(ka[a].w, kb[b].w, kk[a][b]);
        qk[a][b] = fmaf(qa[a].x, kb[b].x, qk[a][b]);
        qk[a][b] = fmaf(qa[a].y, kb[b].y, qk[a][b]);
        qk[a][b] = fmaf(qa[a].z, kb[b].z, qk[a][b]);
        qk[a][b] = fmaf(qa[a].w, kb[b].w, qk[a][b]);
      }
  }
#pragma unroll
  for (int a = 0; a < 4; ++a)
#pragma unroll
    for (int b = 0; b < 2; ++b) {
      int i = i0 + a, j = j0 + b;
      float e = expf(cgl[i] - cgl[j]);
      At[j * 65 + i] = (j < i) ? (-bl[i] * e * kk[a][b]) : 0.f;
      Mq[j * 65 + i] = (j <= i) ? (rsl[i] * e * qk[a][b]) : 0.f;
    }
  __syncthreads();

  float X[64];
  if (tid < 256) {
    // ---- waves 0-3: X init + forward substitution ----
    if (tid < 128) {
#pragma unroll
      for (int j = 0; j < 64; ++j) X[j] = bp[j] * ldsw1(Kl, j, tid);
    } else {
      const int m = tid - 128;
#pragma unroll
      for (int j = 0; j < 64; ++j)
        X[j] = bl[j] * qkvc[(size_t)(c * 64 + j) * CD_ + 2 * KD_ + hv * 128 + m];
    }
#pragma unroll
    for (int j = 0; j < 63; ++j) {
      float xj = X[j];
#pragma unroll
      for (int i = j + 1; i < 64; ++i) X[i] = fmaf(At[j * 65 + i], xj, X[i]);
    }
    if (tid < 128) {
      size_t baseo = ((size_t)cid * 128 + tid) * 64;
#pragma unroll
      for (int j4 = 0; j4 < 16; ++j4) {
        float4 v = {X[j4 * 4], X[j4 * 4 + 1], X[j4 * 4 + 2], X[j4 * 4 + 3]};
        *(float4*)&Wtg[baseo + j4 * 4] = v;
      }
    }
  } else {
    // ---- waves 4-7: Mqg + pQg writes (independent of solve) ----
    const int t2 = tid - 256;
#pragma unroll
    for (int it = 0; it < 16; ++it) {
      int f = it * 256 + t2;
      int j = f >> 6, i = f & 63;
      Mqg[(size_t)cid * 4096 + f] = Mq[j * 65 + i];
    }
    const int i = t2 & 63;
    const float ei = expf(cgl[i]) * rsl[i];
#pragma unroll
    for (int it = 0; it < 32; ++it) {
      int d = it * 4 + (t2 >> 6);
      pQg[(size_t)cid * 8192 + d * 64 + i] = ei * ldsw1(Ql, i, d);
    }
  }
  __syncthreads();   // At/Mq dead; X (U cols) ready

  if (tid >= 128 && tid < 256) {
    const int m = tid - 128;
    float* Utr = AM;
#pragma unroll
    for (int j = 0; j < 64; ++j) Utr[j * 128 + m] = X[j];
  }
  __syncthreads();
  {
    const float* Utr = AM;
#pragma unroll
    for (int it = 0; it < 4; ++it) {
      int flat = it * 2048 + tid * 4;
      *(float4*)&Ug[(size_t)cid * 8192 + flat] = *(const float4*)&Utr[flat];
    }
  }
}

// ---------------------------------------------------------------------------
// make_MBG (parallel, 256 blocks, 512 threads)
// ---------------------------------------------------------------------------
__global__ __launch_bounds__(512) void make_MBG(
    const float* __restrict__ Wtg, const float* __restrict__ pQg,
    const float* __restrict__ Ug, const float* __restrict__ Mqg,
    const float* __restrict__ khat, const float* __restrict__ cgbuf,
    u16* __restrict__ Mhi, u16* __restrict__ Mlo,
    float* __restrict__ Bg, float* __restrict__ Gtg) {
  const int c = blockIdx.x, hv = blockIdx.y, hk = hv >> 1;
  const int cid = c * 16 + hv;
  const int tid = threadIdx.x;
  __shared__ float Wl[64 * 128];   // W[j][d]
  __shared__ float Kel[64 * 128];  // esc_j * khat_j[d]
  __shared__ float Ul[64 * 128];
  __shared__ float Mql[64 * 64];
  const float cg63 = cgbuf[cid * 64 + 63];
  const float pC = expf(cg63);
#pragma unroll
  for (int it = 0; it < 4; ++it) {
    int f = it * 2048 + tid * 4;       // f = d*64 + j
    int d = f >> 6, j = f & 63;
    float4 w = *(const float4*)&Wtg[(size_t)cid * 8192 + f];
    Wl[(j + 0) * 128 + d] = w.x;
    Wl[(j + 1) * 128 + d] = w.y;
    Wl[(j + 2) * 128 + d] = w.z;
    Wl[(j + 3) * 128 + d] = w.w;
  }
#pragma unroll
  for (int it = 0; it < 4; ++it) {
    int f = it * 2048 + tid * 4;       // f = j*128 + d
    int j = f >> 7, d = f & 127;
    float esc = expf(cg63 - cgbuf[cid * 64 + j]);
    float4 kv = *(const float4*)&khat[((size_t)(c * 64 + j) * HK_ + hk) * 128 + d];
    float4 uv = *(const float4*)&Ug[(size_t)cid * 8192 + f];
    kv.x *= esc; kv.y *= esc; kv.z *= esc; kv.w *= esc;
    *(float4*)&Kel[f] = kv;
    *(float4*)&Ul[f] = uv;
  }
#pragma unroll
  for (int it = 0; it < 2; ++it) {
    int f = it * 2048 + tid * 4;
    *(float4*)&Mql[f] = *(const float4*)&Mqg[(size_t)cid * 4096 + f];
  }
  __syncthreads();

  // fused M+B: tile rows d0..d0+7, cols n0..n0+3
  const int d0 = (tid & 15) * 8, n0 = (tid >> 4) * 4;
  float ma[8][4] = {}, ba[8][4] = {};
  for (int j = 0; j < 64; ++j) {
    float4 k0 = *(const float4*)&Kel[j * 128 + d0];
    float4 k1 = *(const float4*)&Kel[j * 128 + d0 + 4];
    float4 w0 = *(const float4*)&Wl[j * 128 + n0];
    float4 u0 = *(const float4*)&Ul[j * 128 + n0];
    float ke[8] = {k0.x, k0.y, k0.z, k0.w, k1.x, k1.y, k1.z, k1.w};
    float wv[4] = {w0.x, w0.y, w0.z, w0.w};
    float uv[4] = {u0.x, u0.y, u0.z, u0.w};
#pragma unroll
    for (int a = 0; a < 8; ++a)
#pragma unroll
      for (int b = 0; b < 4; ++b) {
        ma[a][b] = fmaf(ke[a], wv[b], ma[a][b]);
        ba[a][b] = fmaf(ke[a], uv[b], ba[a][b]);
      }
  }
#pragma unroll
  for (int a = 0; a < 8; ++a) {
    const int d = d0 + a;
    us4 hi, lo;
#pragma unroll
    for (int b = 0; b < 4; ++b) {
      float m = ((d == n0 + b) ? pC : 0.f) - ma[a][b];
      u16 h = f2bf(m);
      hi[b] = h;
      lo[b] = f2bf(m - bf2f(h));
    }
    *(us4*)&Mhi[(size_t)cid * 16384 + d * 128 + n0] = hi;
    *(us4*)&Mlo[(size_t)cid * 16384 + d * 128 + n0] = lo;
    float4 b0 = {ba[a][0], ba[a][1], ba[a][2], ba[a][3]};
    *(float4*)&Bg[(size_t)cid * 16384 + d * 128 + n0] = b0;
  }

  // G phase: Gt[d][i] tile 4d x 4i
  const int dg = (tid & 31) * 4, ig = (tid >> 5) * 4;
  float ga[4][4] = {};
  for (int j = 0; j < 64; ++j) {
    float4 w4 = *(const float4*)&Wl[j * 128 + dg];
    float4 m0 = *(const float4*)&Mql[j * 64 + ig];
    float wv[4] = {w4.x, w4.y, w4.z, w4.w};
    float mv[4] = {m0.x, m0.y, m0.z, m0.w};
#pragma unroll
    for (int a = 0; a < 4; ++a)
#pragma unroll
      for (int b = 0; b < 4; ++b) ga[a][b] = fmaf(wv[a], mv[b], ga[a][b]);
  }
#pragma unroll
  for (int a = 0; a < 4; ++a) {
    const int d = dg + a;
    float4 p0 = *(const float4*)&pQg[(size_t)cid * 8192 + d * 64 + ig];
    float4 g0 = {p0.x - ga[a][0], p0.y - ga[a][1], p0.z - ga[a][2], p0.w - ga[a][3]};
    *(float4*)&Gtg[(size_t)cid * 8192 + d * 64 + ig] = g0;
  }
}

// ---------------------------------------------------------------------------
// scan_S v4: 128 blocks = 16 heads x 8 col-slices of 16, XCD-grouped
// (flat%8 == hv%8 so all 8 slices of a head share one L2 copy of M).
// M AND B both register-prefetched one chunk ahead (named double buffers).
// ---------------------------------------------------------------------------
__global__ __launch_bounds__(512) void scan_S(
    const u16* __restrict__ Mhi, const u16* __restrict__ Mlo,
    const float* __restrict__ Bg, float* __restrict__ Sg) {
  const int flat = blockIdx.x;
  const int hv = (flat & 7) + 8 * (flat >> 6);
  const int vs = (flat >> 3) & 7;
  const int tid = threadIdx.x;
  const int wave = tid >> 6, lane = tid & 63;
  const int fr = lane & 15, fq = lane >> 4;
  const int wr = wave * 16;       // this wave's 16 output rows
  const int m0 = vs * 16;         // col-slice base

  __shared__ u16 Sh[2][2048];     // [16 m][128 k] bf16-hi, XOR-swizzled
  __shared__ u16 Sl[2][2048];

  for (int i = tid; i < 2048; i += 512) { Sh[0][i] = 0; Sl[0][i] = 0; }
  {
    float* s0 = Sg + (size_t)hv * 16384 + m0;
#pragma unroll
    for (int it = 0; it < 4; ++it) {
      int idx = it * 512 + tid;          // 2048 = 128 d x 16 m
      s0[(size_t)(idx >> 4) * 128 + (idx & 15)] = 0.f;
    }
  }
  __syncthreads();

  bf16x8 MhA[4], MlA[4], MhB[4], MlB[4];
  float bvA[4], bvB[4];
  {
    const u16* Mh0 = Mhi + (size_t)hv * 16384;
    const u16* Ml0 = Mlo + (size_t)hv * 16384;
#pragma unroll
    for (int kt = 0; kt < 4; ++kt) {
      size_t off = (size_t)(wr + fr) * 128 + kt * 32 + fq * 8;
      MhA[kt] = *(const bf16x8*)&Mh0[off];
      MlA[kt] = *(const bf16x8*)&Ml0[off];
    }
    const float* Bc = Bg + (size_t)hv * 16384 + m0;
#pragma unroll
    for (int j = 0; j < 4; ++j)
      bvA[j] = Bc[(size_t)(wr + fq * 4 + j) * 128 + fr];
  }
  int p = 0;

  auto step = [&](int c, bf16x8 (&MhC)[4], bf16x8 (&MlC)[4], float (&bvC)[4],
                  bf16x8 (&MhN)[4], bf16x8 (&MlN)[4], float (&bvN)[4]) {
    // prefetch next chunk's M frags + B values (consumed next step)
    if (c + 1 < NC_ - 1) {
      const u16* MhP = Mhi + (size_t)((c + 1) * 16 + hv) * 16384;
      const u16* MlP = Mlo + (size_t)((c + 1) * 16 + hv) * 16384;
#pragma unroll
      for (int kt = 0; kt < 4; ++kt) {
        size_t off = (size_t)(wr + fr) * 128 + kt * 32 + fq * 8;
        MhN[kt] = *(const bf16x8*)&MhP[off];
        MlN[kt] = *(const bf16x8*)&MlP[off];
      }
      const float* BcN = Bg + (size_t)((c + 1) * 16 + hv) * 16384 + m0;
#pragma unroll
      for (int j = 0; j < 4; ++j)
        bvN[j] = BcN[(size_t)(wr + fq * 4 + j) * 128 + fr];
    }

    // acc = M_c @ S_c  (bf16 hi/lo x3), 16-col slice: single B fragment
    f32x4v acc = {};
#pragma unroll
    for (int kt = 0; kt < 4; ++kt) {
      const int m = fr;
      const int byte = m * 256 + ((kt * 64 + fq * 16) ^ ((m & 7) << 4));
      bf16x8 BhF = *(const bf16x8*)((const char*)&Sh[p][0] + byte);
      bf16x8 BlF = *(const bf16x8*)((const char*)&Sl[p][0] + byte);
      acc = __builtin_amdgcn_mfma_f32_16x16x32_bf16(MlC[kt], BhF, acc, 0, 0, 0);
      acc = __builtin_amdgcn_mfma_f32_16x16x32_bf16(MhC[kt], BlF, acc, 0, 0, 0);
      acc = __builtin_amdgcn_mfma_f32_16x16x32_bf16(MhC[kt], BhF, acc, 0, 0, 0);
    }

    // S_{c+1} = acc + B (B from registers, prefetched last step)
    float* Sn = Sg + (size_t)((c + 1) * 16 + hv) * 16384 + m0;
    const int k0 = wr + fq * 4;
    const int m = fr;
    us4 h4, l4;
#pragma unroll
    for (int j = 0; j < 4; ++j) {
      float v = acc[j] + bvC[j];
      Sn[(size_t)(k0 + j) * 128 + m] = v;
      u16 h = f2bf(v);
      h4[j] = h;
      l4[j] = f2bf(v - bf2f(h));
    }
    const int wbyte = m * 256 + ((k0 * 2) ^ ((m & 7) << 4));
    *(us4*)((char*)&Sh[p ^ 1][0] + wbyte) = h4;
    *(us4*)((char*)&Sl[p ^ 1][0] + wbyte) = l4;
    __syncthreads();
    p ^= 1;
  };

  for (int cc = 0; cc < NC_ - 1; cc += 2) {
    step(cc, MhA, MlA, bvA, MhB, MlB, bvB);
    if (cc + 1 < NC_ - 1) step(cc + 1, MhB, MlB, bvB, MhA, MlA, bvA);
  }
}

// ---------------------------------------------------------------------------
// chunk_out + fused gated rmsnorm (parallel, 256 blocks):
//   o_i[m] = sum_j Mq[j][i] U[j][m] + sum_d Gt[d][i] S[d][m]
//   h = o*silu(z); h *= rsqrt(mean_m(h^2)+eps)*norm_w; -> bf16 (permuted)
// ---------------------------------------------------------------------------
__global__ __launch_bounds__(256) void chunk_out(
    const float* __restrict__ Mqg, const float* __restrict__ Ug,
    const float* __restrict__ Gtg, const float* __restrict__ Sg,
    const float* __restrict__ zbuf, const float* __restrict__ norm_w,
    u16* __restrict__ h) {
  const int c = blockIdx.x, hv = blockIdx.y;
  const int cid = c * 16 + hv;
  const int tid = threadIdx.x;
  __shared__ float Mql[64 * 64];
  __shared__ float Ul[64 * 128];
  __shared__ float Gtl[128 * 64];
  __shared__ float Sl[128 * 128];
  __shared__ float red[64][16];
#pragma unroll
  for (int it = 0; it < 4; ++it) {
    int f = it * 1024 + tid * 4;
    *(float4*)&Mql[f] = *(const float4*)&Mqg[(size_t)cid * 4096 + f];
  }
#pragma unroll
  for (int it = 0; it < 8; ++it) {
    int f = it * 1024 + tid * 4;
    *(float4*)&Ul[f]  = *(const float4*)&Ug[(size_t)cid * 8192 + f];
    *(float4*)&Gtl[f] = *(const float4*)&Gtg[(size_t)cid * 8192 + f];
  }
#pragma unroll
  for (int it = 0; it < 16; ++it) {
    int f = it * 1024 + tid * 4;
    *(float4*)&Sl[f] = *(const float4*)&Sg[(size_t)cid * 16384 + f];
  }
  __syncthreads();

  const int i0 = (tid & 15) * 4, m0 = (tid >> 4) * 8;
  float oa[4][8] = {};
  for (int j = 0; j < 64; ++j) {
    float4 mq = *(const float4*)&Mql[j * 64 + i0];
    float4 u0 = *(const float4*)&Ul[j * 128 + m0];
    float4 u1 = *(const float4*)&Ul[j * 128 + m0 + 4];
    float mv[4] = {mq.x, mq.y, mq.z, mq.w};
    float uv[8] = {u0.x, u0.y, u0.z, u0.w, u1.x, u1.y, u1.z, u1.w};
#pragma unroll
    for (int a = 0; a < 4; ++a)
#pragma unroll
      for (int b = 0; b < 8; ++b) oa[a][b] = fmaf(mv[a], uv[b], oa[a][b]);
  }
  for (int d = 0; d < 128; ++d) {
    float4 gt = *(const float4*)&Gtl[d * 64 + i0];
    float4 s0 = *(const float4*)&Sl[d * 128 + m0];
    float4 s1 = *(const float4*)&Sl[d * 128 + m0 + 4];
    float gv[4] = {gt.x, gt.y, gt.z, gt.w};
    float sv[8] = {s0.x, s0.y, s0.z, s0.w, s1.x, s1.y, s1.z, s1.w};
#pragma unroll
    for (int a = 0; a < 4; ++a)
#pragma unroll
      for (int b = 0; b < 8; ++b) oa[a][b] = fmaf(gv[a], sv[b], oa[a][b]);
  }

  // ---- fused gated rmsnorm over the m-dimension (per row) ----
  float hva[4][8];
#pragma unroll
  for (int a = 0; a < 4; ++a) {
    const int t = c * 64 + i0 + a;
    float4 z0 = *(const float4*)&zbuf[(size_t)t * VD_ + hv * 128 + m0];
    float4 z1 = *(const float4*)&zbuf[(size_t)t * VD_ + hv * 128 + m0 + 4];
    float zv[8] = {z0.x, z0.y, z0.z, z0.w, z1.x, z1.y, z1.z, z1.w};
    float ss = 0.f;
#pragma unroll
    for (int b = 0; b < 8; ++b) {
      float hc = oa[a][b] * (zv[b] / (1.f + expf(-zv[b])));
      hva[a][b] = hc;
      ss = fmaf(hc, hc, ss);
    }
    red[i0 + a][tid >> 4] = ss;
  }
  __syncthreads();
  float4 nw0 = *(const float4*)&norm_w[m0];
  float4 nw1 = *(const float4*)&norm_w[m0 + 4];
  float nw[8] = {nw0.x, nw0.y, nw0.z, nw0.w, nw1.x, nw1.y, nw1.z, nw1.w};
#pragma unroll
  for (int a = 0; a < 4; ++a) {
    const int t = c * 64 + i0 + a;
    float tot = 0.f;
#pragma unroll
    for (int w = 0; w < 16; ++w) tot += red[i0 + a][w];
    float r = rsqrtf(tot * (1.f / 128.f) + 1e-6f);
    us8 hv8;
#pragma unroll
    for (int b = 0; b < 8; ++b) hv8[b] = f2bf(hva[a][b] * r * nw[b]);
    *(us8*)&h[(size_t)t * VD_ + permk3(t, hv * 128 + m0)] = hv8;
  }
}

// ---------------------------------------------------------------------------
extern "C" void kernel_launch(void* const* d_in, const int* in_sizes, int n_in,
                              void* d_out, int out_size, void* d_ws, size_t ws_size,
                              hipStream_t stream) {
  const float* x       = (const float*)d_in[0];
  const float* w_qkvz  = (const float*)d_in[1];
  const float* w_ba    = (const float*)d_in[2];
  const float* conv_w  = (const float*)d_in[3];
  const float* conv_b  = (const float*)d_in[4];
  const float* a_log   = (const float*)d_in[5];
  const float* dt_bias = (const float*)d_in[6];
  const float* norm_w  = (const float*)d_in[7];
  const float* w_o     = (const float*)d_in[8];
  float* out = (float*)d_out;

  float* ws = (float*)d_ws;
  float* qkvraw = ws;                  // 4,194,304  (-> Bg)
  float* zbuf   = ws + 4194304;        // 2,097,152
  float* qkvc   = ws + 6291456;        // 4,194,304  (-> Mhi|Mlo, -> wot)
  float* khat   = ws + 10485760;       // 1,048,576  (-> hb)
  float* gbuf   = ws + 11534336;       // 16,384
  float* bbuf   = ws + 11550720;       // 16,384
  float* cgbuf  = ws + 11567104;       // 16,384
  float* obuf   = ws + 11583488;       // 2,097,152  (xb early)
  float* Wtg    = ws + 13680640;       // 2,097,152 ┐ -> Sg (4,194,304)
  float* pQg    = ws + 15777792;       // 2,097,152 ┘
  float* Ug     = ws + 17874944;       // 2,097,152
  float* Mqg    = ws + 19972096;       // 1,048,576
  float* Gtg    = ws + 21020672;       // 2,097,152

  u16* xb   = (u16*)obuf;      // x bf16 (dead after gemm1)
  u16* wqt  = (u16*)Wtg;       // w_qkvz^T bf16 (dead after gemm1)
  u16* Mhi  = (u16*)qkvc;
  u16* Mlo  = (u16*)(qkvc + 2097152);
  float* Bg = qkvraw;
  float* Sg = Wtg;
  u16* wot  = (u16*)qkvc;      // after scan_S (Mhi dead)
  u16* hb   = (u16*)khat;      // after make_MBG (khat dead)

  // 0) casts (permuted staging layout)
  cast_bf16<<<1024, 256, 0, stream>>>(x, xb, 262144);
  transpose_bf16<<<dim3(32, 96), 256, 0, stream>>>(w_qkvz, wqt, H_, QN_);
  // 1) qkv|z = x @ w_qkvz
  gemm_bf16<128><<<768, 256, 0, stream>>>(xb, wqt, qkvraw, CD_, zbuf, VD_,
                                          CD_, T_, QN_, H_);
  // 2) beta / g
  ba_gbeta<<<T_, 256, 0, stream>>>(x, w_ba, a_log, dt_bias, gbuf, bbuf);
  // 3) fused conv + silu + k-l2norm
  conv_silu_k<<<T_, 512, 0, stream>>>(qkvraw, conv_w, conv_b, qkvc, khat);
  // 4) chunk-local precompute (parallel, 512 thr)
  chunk_prep<<<dim3(NC_, HV_), 512, 0, stream>>>(
      qkvc, khat, gbuf, bbuf, cgbuf, Wtg, Ug, Mqg, pQg);
  // 5) per-chunk transition/output operators (parallel, 512 thr)
  make_MBG<<<dim3(NC_, HV_), 512, 0, stream>>>(
      Wtg, pQg, Ug, Mqg, khat, cgbuf, Mhi, Mlo, Bg, Gtg);
  // 6) sequential state scan (128 blocks, M+B reg-prefetched)
  scan_S<<<128, 512, 0, stream>>>(Mhi, Mlo, Bg, Sg);
  // 7) w_o^T cast (Mhi region now dead)
  transpose_bf16<<<dim3(32, 32), 256, 0, stream>>>(w_o, wot, VD_, H_);
  // 8) per-chunk outputs + fused gated rmsnorm -> bf16 h (permuted)
  chunk_out<<<dim3(NC_, HV_), 256, 0, stream>>>(
      Mqg, Ug, Gtg, Sg, zbuf, norm_w, hb);
  // 9) out = h @ w_o  (BM=64: 512 blocks = 2/CU for latency hiding)
  gemm_bf16<64><<<512, 256, 0, stream>>>(hb, wot, out, VD_, out, VD_,
                                         VD_, T_, VD_, H_);
}

// Round 18
// 233.455 us; speedup vs baseline: 1.1568x; 1.0179x over previous
//
#include <hip/hip_runtime.h>
#include <math.h>

typedef unsigned short u16;
using us4  = __attribute__((ext_vector_type(4))) unsigned short;
using us8  = __attribute__((ext_vector_type(8))) unsigned short;
using bf16x8 = __attribute__((ext_vector_type(8))) __bf16;
using f32x4v = __attribute__((ext_vector_type(4))) float;

// Problem constants
#define T_    1024
#define H_    2048
#define HK_   8
#define HV_   16
#define KD_   1024
#define VD_   2048
#define CD_   4096
#define QN_   6144   // 2*KD + 2*VD
#define NC_   16     // number of chunks
#define C_    64     // chunk length

__device__ __forceinline__ u16 f2bf(float f) {
  unsigned u = __float_as_uint(f);
  u += 0x7fffu + ((u >> 16) & 1u);   // RNE
  return (u16)(u >> 16);
}
__device__ __forceinline__ float bf2f(u16 h) {
  return __uint_as_float(((unsigned)h) << 16);
}
// staging layout for gemm: within each 64-elem k-group, 8-elem chunk c of
// row r is stored at chunk position c ^ (r&7).
__device__ __forceinline__ int permk3(int r, int k) {
  return (k & ~63) | ((((k >> 3) & 7) ^ (r & 7)) << 3) | (k & 7);
}

// ---------------------------------------------------------------------------
// f32 [R][C] -> bf16 [C][R] transpose + cast + chunk permutation
// ---------------------------------------------------------------------------
__global__ __launch_bounds__(256) void transpose_bf16(
    const float* __restrict__ in, u16* __restrict__ out, int R, int C) {
  __shared__ float tile[64][65];
  const int r0 = blockIdx.x * 64, c0 = blockIdx.y * 64;
  const int t = threadIdx.x;
  const int tr = t >> 4, tc4 = (t & 15) * 4;
#pragma unroll
  for (int i = 0; i < 4; ++i) {
    float4 v = *(const float4*)&in[(size_t)(r0 + tr + i * 16) * C + c0 + tc4];
    tile[tr + i * 16][tc4 + 0] = v.x;
    tile[tr + i * 16][tc4 + 1] = v.y;
    tile[tr + i * 16][tc4 + 2] = v.z;
    tile[tr + i * 16][tc4 + 3] = v.w;
  }
  __syncthreads();
#pragma unroll
  for (int i = 0; i < 4; ++i) {
    int oc = tr + i * 16;
    int row = c0 + oc;
    int k = r0 + tc4;
    us4 w = {f2bf(tile[tc4 + 0][oc]), f2bf(tile[tc4 + 1][oc]),
             f2bf(tile[tc4 + 2][oc]), f2bf(tile[tc4 + 3][oc])};
    *(us4*)&out[(size_t)row * R + permk3(row, k)] = w;
  }
}

// ---------------------------------------------------------------------------
// bf16 MFMA GEMM: C = A[M,K] @ Bt[N,K]^T, f32 out. BMx64 tile, BK=64,
// 2-buffer counted-vmcnt pipeline, XCD-grouped 1D block mapping,
// 3-bit permuted staging. Output routed to Cq (cols < zsplit) or Cz.
// ---------------------------------------------------------------------------
__device__ __forceinline__ void gload_lds16(const void* g, void* l) {
  __builtin_amdgcn_global_load_lds(
      (const __attribute__((address_space(1))) void*)g,
      (__attribute__((address_space(3))) void*)l, 16, 0, 0);
}

template <int BM>
__global__ __launch_bounds__(256) void gemm_bf16(
    const u16* __restrict__ A, const u16* __restrict__ Bt,
    float* __restrict__ Cq, int ldq, float* __restrict__ Cz, int ldz,
    int zsplit, int M, int N, int K) {
  constexpr int MI = BM / 32;               // A-frags per wave
  __shared__ __align__(16) u16 As[2][BM * 64];
  __shared__ __align__(16) u16 Bs[2][4096];   // [64][64]
  const int tid  = threadIdx.x;
  const int wave = tid >> 6, lane = tid & 63;
  const int gy = N >> 6;
  const int ncolpx = gy >> 3;
  const int bid = blockIdx.x;
  const int xcd = bid & 7, idx = bid >> 3;
  const int row0 = (idx / ncolpx) * BM;
  const int col0 = (xcd * ncolpx + idx % ncolpx) * 64;
  const int wr = wave >> 1, wc = wave & 1;
  const int fr = lane & 15, fq = lane >> 4;

  const int sr8 = lane >> 3;
  const int sc8 = (lane & 7) * 8;
  const u16* gA = A  + (size_t)(row0 + wave * (BM / 4) + sr8) * K + sc8;
  const u16* gB = Bt + (size_t)(col0 + wave * 16 + sr8) * K + sc8;

  f32x4v acc[MI][2] = {};
  const int nt = K >> 6;

  auto stage = [&](int p, int k0) {
#pragma unroll
    for (int j = 0; j < BM / 32; ++j)
      gload_lds16(gA + (size_t)(j * 8) * K + k0,
                  &As[p][(wave * (BM / 4) + j * 8) * 64]);
#pragma unroll
    for (int j = 0; j < 2; ++j)
      gload_lds16(gB + (size_t)(j * 8) * K + k0,
                  &Bs[p][(wave * 16 + j * 8) * 64]);
  };

  stage(0, 0);

  int p = 0;
  for (int it = 0; it < nt; ++it) {
    if (it + 1 < nt) stage(p ^ 1, (it + 1) * 64);
    if (it + 1 < nt) {
      if constexpr (BM == 128)
        asm volatile("s_waitcnt vmcnt(6)" ::: "memory");
      else
        asm volatile("s_waitcnt vmcnt(4)" ::: "memory");
    } else {
      asm volatile("s_waitcnt vmcnt(0)" ::: "memory");
    }
    __builtin_amdgcn_s_barrier();

#pragma unroll
    for (int kt = 0; kt < 2; ++kt) {
      bf16x8 af[MI], bff[2];
#pragma unroll
      for (int mi = 0; mi < MI; ++mi) {
        const int r = wr * (BM / 2) + mi * 16 + fr;
        af[mi] = *(const bf16x8*)
            &As[p][r * 64 + kt * 32 + (((kt * 4 + fq) ^ (r & 7)) & 3) * 8
                   + ((((kt * 4 + fq) ^ (r & 7)) >> 2) - kt) * 32];
      }
#pragma unroll
      for (int ni = 0; ni < 2; ++ni) {
        const int r = wc * 32 + ni * 16 + fr;
        bff[ni] = *(const bf16x8*)
            &Bs[p][r * 64 + kt * 32 + (((kt * 4 + fq) ^ (r & 7)) & 3) * 8
                   + ((((kt * 4 + fq) ^ (r & 7)) >> 2) - kt) * 32];
      }
#pragma unroll
      for (int mi = 0; mi < MI; ++mi)
#pragma unroll
        for (int ni = 0; ni < 2; ++ni)
          acc[mi][ni] = __builtin_amdgcn_mfma_f32_16x16x32_bf16(
              af[mi], bff[ni], acc[mi][ni], 0, 0, 0);
    }
    if (it + 1 < nt) {
      asm volatile("s_waitcnt lgkmcnt(0)" ::: "memory");
      __builtin_amdgcn_s_barrier();
    }
    p ^= 1;
  }

  float* Cp; int ldc, cb;
  if (col0 < zsplit) { Cp = Cq; ldc = ldq; cb = col0; }
  else               { Cp = Cz; ldc = ldz; cb = col0 - zsplit; }
#pragma unroll
  for (int mi = 0; mi < MI; ++mi)
#pragma unroll
    for (int ni = 0; ni < 2; ++ni) {
      const int r  = row0 + wr * (BM / 2) + mi * 16 + fq * 4;
      const int cc = cb + wc * 32 + ni * 16 + fr;
#pragma unroll
      for (int j = 0; j < 4; ++j)
        Cp[(size_t)(r + j) * ldc + cc] = acc[mi][ni][j];
    }
}

// ---------------------------------------------------------------------------
// fused: xb = bf16(x) (permuted staging layout)  +
//        ba = x @ w_ba -> beta = sigmoid(b), g = -exp(a_log)*softplus(a+dt)
// ---------------------------------------------------------------------------
__global__ __launch_bounds__(256) void ba_gbeta_cast(
    const float* __restrict__ x, const float* __restrict__ w_ba,
    const float* __restrict__ a_log, const float* __restrict__ dt_bias,
    float* __restrict__ g, float* __restrict__ beta, u16* __restrict__ xb) {
  const int t = blockIdx.x;
  const int tid = threadIdx.x;
  __shared__ float xs[2048];
  __shared__ float red[8][32];
  {
    float4 v = *(const float4*)&x[(size_t)t * H_ + tid * 4];
    *(float4*)&xs[tid * 4] = v;
    float4 w = *(const float4*)&x[(size_t)t * H_ + 1024 + tid * 4];
    *(float4*)&xs[1024 + tid * 4] = w;
  }
  __syncthreads();
  // emit xb chunk (8 bf16) in permuted layout: chunk tid of row t
  {
    const float* src = &xs[tid * 8];
    us8 r = {f2bf(src[0]), f2bf(src[1]), f2bf(src[2]), f2bf(src[3]),
             f2bf(src[4]), f2bf(src[5]), f2bf(src[6]), f2bf(src[7])};
    const int ip = (tid & ~7) | ((tid & 7) ^ (t & 7));
    *(us8*)&xb[(size_t)t * H_ + ip * 8] = r;
  }
  const int c = tid & 31;
  const int chunk = tid >> 5;
  float p = 0.f;
  const int kb = chunk * 256;
#pragma unroll 4
  for (int k = kb; k < kb + 256; ++k) p = fmaf(xs[k], w_ba[k * 32 + c], p);
  red[chunk][c] = p;
  __syncthreads();
  if (tid < 32) {
    float s = 0.f;
#pragma unroll
    for (int i = 0; i < 8; ++i) s += red[i][c];
    if (c < 16) {
      beta[t * 16 + c] = 1.f / (1.f + expf(-s));
    } else {
      int h = c - 16;
      float xx = s + dt_bias[h];
      float sp = xx > 20.f ? xx : log1pf(expf(xx));
      g[t * 16 + h] = -expf(a_log[h]) * sp;
    }
  }
}

// ---------------------------------------------------------------------------
// fused causal depthwise conv1d (K=4) + SiLU + k-l2norm.
// ---------------------------------------------------------------------------
__global__ __launch_bounds__(512) void conv_silu_k(
    const float* __restrict__ qkvraw, const float* __restrict__ conv_w,
    const float* __restrict__ conv_b, float* __restrict__ qkvc,
    float* __restrict__ khat) {
  const int t = blockIdx.x;
  const int tid = threadIdx.x;
  const int c0 = tid * 8;
  float acc[8];
  float4 cb0 = *(const float4*)&conv_b[c0];
  float4 cb1 = *(const float4*)&conv_b[c0 + 4];
  acc[0] = cb0.x; acc[1] = cb0.y; acc[2] = cb0.z; acc[3] = cb0.w;
  acc[4] = cb1.x; acc[5] = cb1.y; acc[6] = cb1.z; acc[7] = cb1.w;
  float wv[8][4];
#pragma unroll
  for (int i = 0; i < 8; i += 2) {
    float4 w0 = *(const float4*)&conv_w[(c0 + i) * 4];
    float4 w1 = *(const float4*)&conv_w[(c0 + i + 1) * 4];
    wv[i][0] = w0.x; wv[i][1] = w0.y; wv[i][2] = w0.z; wv[i][3] = w0.w;
    wv[i+1][0] = w1.x; wv[i+1][1] = w1.y; wv[i+1][2] = w1.z; wv[i+1][3] = w1.w;
  }
#pragma unroll
  for (int j = 0; j < 4; ++j) {
    int tt = t - 3 + j;
    if (tt >= 0) {
      float4 a = *(const float4*)&qkvraw[(size_t)tt * CD_ + c0];
      float4 b = *(const float4*)&qkvraw[(size_t)tt * CD_ + c0 + 4];
      float xv[8] = {a.x, a.y, a.z, a.w, b.x, b.y, b.z, b.w};
#pragma unroll
      for (int i = 0; i < 8; ++i) acc[i] = fmaf(xv[i], wv[i][j], acc[i]);
    }
  }
  float y[8];
#pragma unroll
  for (int i = 0; i < 8; ++i) y[i] = acc[i] / (1.f + expf(-acc[i]));

  if (tid < 128 || tid >= 256) {
    float4 o0 = {y[0], y[1], y[2], y[3]};
    float4 o1 = {y[4], y[5], y[6], y[7]};
    *(float4*)&qkvc[(size_t)t * CD_ + c0]     = o0;
    *(float4*)&qkvc[(size_t)t * CD_ + c0 + 4] = o1;
  } else {
    float ss = 0.f;
#pragma unroll
    for (int i = 0; i < 8; ++i) ss = fmaf(y[i], y[i], ss);
#pragma unroll
    for (int off = 1; off < 16; off <<= 1) ss += __shfl_xor(ss, off);
    float rs = rsqrtf(ss + 1e-6f);
    const int head = (c0 - 1024) >> 7;
    const int d0 = (c0 - 1024) & 127;
    float4 o0 = {y[0] * rs, y[1] * rs, y[2] * rs, y[3] * rs};
    float4 o1 = {y[4] * rs, y[5] * rs, y[6] * rs, y[7] * rs};
    float* kout = &khat[((size_t)t * HK_ + head) * 128 + d0];
    *(float4*)&kout[0] = o0;
    *(float4*)&kout[4] = o1;
  }
}

// ---------------------------------------------------------------------------
// Chunked gated delta rule, phase A (parallel over 16 chunks x 16 heads).
// 512 threads (8 waves). Dot phase 4x2 tiles/thread; during the serial
// forward substitution (waves 0-3), waves 4-7 write Mqg and pQg.
// ---------------------------------------------------------------------------
#define SWZ(r) (((r) >> 2) & 7)

__device__ __forceinline__ float4 ldsw4(const float* base, int r, int dblk) {
  return *(const float4*)&base[r * 128 + ((dblk ^ SWZ(r)) << 2)];
}
__device__ __forceinline__ float ldsw1(const float* base, int r, int d) {
  return base[r * 128 + ((((d) >> 2) ^ SWZ(r)) << 2) + ((d) & 3)];
}

__global__ __launch_bounds__(512) void chunk_prep(
    const float* __restrict__ qkvc, const float* __restrict__ khat,
    const float* __restrict__ g, const float* __restrict__ beta,
    float* __restrict__ cgbuf, float* __restrict__ Wtg, float* __restrict__ Ug,
    float* __restrict__ Mqg, float* __restrict__ pQg) {
  const int c = blockIdx.x, hv = blockIdx.y, hk = hv >> 1;
  const int cid = c * 16 + hv;
  const int tid = threadIdx.x;
  __shared__ float Kl[8192], Ql[8192];   // swizzled [64][128]
  __shared__ float AM[8320];             // At[64][65] | Mq[64][65]; later Utr
  __shared__ float cgl[64], bl[64], bp[64], rsl[64];
  float* At = AM;
  float* Mq = AM + 4160;

#pragma unroll
  for (int it = 0; it < 4; ++it) {
    int flat = it * 2048 + tid * 4;
    int row = flat >> 7, d = flat & 127;
    int pb = ((d >> 2) ^ SWZ(row)) << 2;
    int gt = c * 64 + row;
    float4 kv = *(const float4*)&khat[((size_t)gt * HK_ + hk) * 128 + d];
    float4 qv = *(const float4*)&qkvc[(size_t)gt * CD_ + hk * 128 + d];
    *(float4*)&Kl[row * 128 + pb] = kv;
    *(float4*)&Ql[row * 128 + pb] = qv;
  }
  if (tid < 64) {
    float s = g[(size_t)(c * 64 + tid) * HV_ + hv];
#pragma unroll
    for (int off = 1; off < 64; off <<= 1) {
      float t = __shfl_up(s, off);
      if (tid >= off) s += t;
    }
    cgl[tid] = s;
    cgbuf[cid * 64 + tid] = s;
    bl[tid] = beta[(size_t)(c * 64 + tid) * HV_ + hv];
  }
  __syncthreads();
  if (tid < 64) {
    float sq = 0.f;
#pragma unroll
    for (int dblk = 0; dblk < 32; ++dblk) {
      float4 q4 = ldsw4(Ql, tid, dblk);
      sq = fmaf(q4.x, q4.x, sq); sq = fmaf(q4.y, q4.y, sq);
      sq = fmaf(q4.z, q4.z, sq); sq = fmaf(q4.w, q4.w, sq);
    }
    rsl[tid] = rsqrtf(sq + 1e-6f) * 0.08838834764831845f;
    bp[tid] = bl[tid] * expf(cgl[tid]);
  }
  __syncthreads();

  // dot phase: 4x2 tile of (i,j) pairs per thread (512 threads)
  const int i0 = (tid >> 5) * 4, j0 = (tid & 31) * 2;
  float kk[4][2], qk[4][2];
#pragma unroll
  for (int a = 0; a < 4; ++a)
#pragma unroll
    for (int b = 0; b < 2; ++b) { kk[a][b] = 0.f; qk[a][b] = 0.f; }
  for (int dblk = 0; dblk < 32; ++dblk) {
    float4 ka[4], qa[4], kb[2];
#pragma unroll
    for (int a = 0; a < 4; ++a) {
      ka[a] = ldsw4(Kl, i0 + a, dblk);
      qa[a] = ldsw4(Ql, i0 + a, dblk);
    }
#pragma unroll
    for (int b = 0; b < 2; ++b) kb[b] = ldsw4(Kl, j0 + b, dblk);
#pragma unroll
    for (int a = 0; a < 4; ++a)
#pragma unroll
      for (int b = 0; b < 2; ++b) {
        kk[a][b] = fmaf(ka[a].x, kb[b].x, kk[a][b]);
        kk[a][b] = fmaf(ka[a].y, kb[b].y, kk[a][b]);
        kk[a][b] = fmaf(ka[a].z, kb[b].z, kk[a][b]);
        kk[a][b] = fmaf(ka[a].w, kb[b].w, kk[a][b]);
        qk[a][b] = fmaf(qa[a].x, kb[b].x, qk[a][b]);
        qk[a][b] = fmaf(qa[a].y, kb[b].y, qk[a][b]);
        qk[a][b] = fmaf(qa[a].z, kb[b].z, qk[a][b]);
        qk[a][b] = fmaf(qa[a].w, kb[b].w, qk[a][b]);
      }
  }
#pragma unroll
  for (int a = 0; a < 4; ++a)
#pragma unroll
    for (int b = 0; b < 2; ++b) {
      int i = i0 + a, j = j0 + b;
      float e = expf(cgl[i] - cgl[j]);
      At[j * 65 + i] = (j < i) ? (-bl[i] * e * kk[a][b]) : 0.f;
      Mq[j * 65 + i] = (j <= i) ? (rsl[i] * e * qk[a][b]) : 0.f;
    }
  __syncthreads();

  float X[64];
  if (tid < 256) {
    // ---- waves 0-3: X init + forward substitution ----
    if (tid < 128) {
#pragma unroll
      for (int j = 0; j < 64; ++j) X[j] = bp[j] * ldsw1(Kl, j, tid);
    } else {
      const int m = tid - 128;
#pragma unroll
      for (int j = 0; j < 64; ++j)
        X[j] = bl[j] * qkvc[(size_t)(c * 64 + j) * CD_ + 2 * KD_ + hv * 128 + m];
    }
#pragma unroll
    for (int j = 0; j < 63; ++j) {
      float xj = X[j];
#pragma unroll
      for (int i = j + 1; i < 64; ++i) X[i] = fmaf(At[j * 65 + i], xj, X[i]);
    }
    if (tid < 128) {
      size_t baseo = ((size_t)cid * 128 + tid) * 64;
#pragma unroll
      for (int j4 = 0; j4 < 16; ++j4) {
        float4 v = {X[j4 * 4], X[j4 * 4 + 1], X[j4 * 4 + 2], X[j4 * 4 + 3]};
        *(float4*)&Wtg[baseo + j4 * 4] = v;
      }
    }
  } else {
    // ---- waves 4-7: Mqg + pQg writes (independent of solve) ----
    const int t2 = tid - 256;
#pragma unroll
    for (int it = 0; it < 16; ++it) {
      int f = it * 256 + t2;
      int j = f >> 6, i = f & 63;
      Mqg[(size_t)cid * 4096 + f] = Mq[j * 65 + i];
    }
    const int i = t2 & 63;
    const float ei = expf(cgl[i]) * rsl[i];
#pragma unroll
    for (int it = 0; it < 32; ++it) {
      int d = it * 4 + (t2 >> 6);
      pQg[(size_t)cid * 8192 + d * 64 + i] = ei * ldsw1(Ql, i, d);
    }
  }
  __syncthreads();   // At/Mq dead; X (U cols) ready

  if (tid >= 128 && tid < 256) {
    const int m = tid - 128;
    float* Utr = AM;
#pragma unroll
    for (int j = 0; j < 64; ++j) Utr[j * 128 + m] = X[j];
  }
  __syncthreads();
  {
    const float* Utr = AM;
#pragma unroll
    for (int it = 0; it < 4; ++it) {
      int flat = it * 2048 + tid * 4;
      *(float4*)&Ug[(size_t)cid * 8192 + flat] = *(const float4*)&Utr[flat];
    }
  }
}

// ---------------------------------------------------------------------------
// make_MBG (parallel, 256 blocks, 512 threads)
// ---------------------------------------------------------------------------
__global__ __launch_bounds__(512) void make_MBG(
    const float* __restrict__ Wtg, const float* __restrict__ pQg,
    const float* __restrict__ Ug, const float* __restrict__ Mqg,
    const float* __restrict__ khat, const float* __restrict__ cgbuf,
    u16* __restrict__ Mhi, u16* __restrict__ Mlo,
    float* __restrict__ Bg, float* __restrict__ Gtg) {
  const int c = blockIdx.x, hv = blockIdx.y, hk = hv >> 1;
  const int cid = c * 16 + hv;
  const int tid = threadIdx.x;
  __shared__ float Wl[64 * 128];   // W[j][d]
  __shared__ float Kel[64 * 128];  // esc_j * khat_j[d]
  __shared__ float Ul[64 * 128];
  __shared__ float Mql[64 * 64];
  const float cg63 = cgbuf[cid * 64 + 63];
  const float pC = expf(cg63);
#pragma unroll
  for (int it = 0; it < 4; ++it) {
    int f = it * 2048 + tid * 4;       // f = d*64 + j
    int d = f >> 6, j = f & 63;
    float4 w = *(const float4*)&Wtg[(size_t)cid * 8192 + f];
    Wl[(j + 0) * 128 + d] = w.x;
    Wl[(j + 1) * 128 + d] = w.y;
    Wl[(j + 2) * 128 + d] = w.z;
    Wl[(j + 3) * 128 + d] = w.w;
  }
#pragma unroll
  for (int it = 0; it < 4; ++it) {
    int f = it * 2048 + tid * 4;       // f = j*128 + d
    int j = f >> 7, d = f & 127;
    float esc = expf(cg63 - cgbuf[cid * 64 + j]);
    float4 kv = *(const float4*)&khat[((size_t)(c * 64 + j) * HK_ + hk) * 128 + d];
    float4 uv = *(const float4*)&Ug[(size_t)cid * 8192 + f];
    kv.x *= esc; kv.y *= esc; kv.z *= esc; kv.w *= esc;
    *(float4*)&Kel[f] = kv;
    *(float4*)&Ul[f] = uv;
  }
#pragma unroll
  for (int it = 0; it < 2; ++it) {
    int f = it * 2048 + tid * 4;
    *(float4*)&Mql[f] = *(const float4*)&Mqg[(size_t)cid * 4096 + f];
  }
  __syncthreads();

  // fused M+B: tile rows d0..d0+7, cols n0..n0+3
  const int d0 = (tid & 15) * 8, n0 = (tid >> 4) * 4;
  float ma[8][4] = {}, ba[8][4] = {};
  for (int j = 0; j < 64; ++j) {
    float4 k0 = *(const float4*)&Kel[j * 128 + d0];
    float4 k1 = *(const float4*)&Kel[j * 128 + d0 + 4];
    float4 w0 = *(const float4*)&Wl[j * 128 + n0];
    float4 u0 = *(const float4*)&Ul[j * 128 + n0];
    float ke[8] = {k0.x, k0.y, k0.z, k0.w, k1.x, k1.y, k1.z, k1.w};
    float wv[4] = {w0.x, w0.y, w0.z, w0.w};
    float uv[4] = {u0.x, u0.y, u0.z, u0.w};
#pragma unroll
    for (int a = 0; a < 8; ++a)
#pragma unroll
      for (int b = 0; b < 4; ++b) {
        ma[a][b] = fmaf(ke[a], wv[b], ma[a][b]);
        ba[a][b] = fmaf(ke[a], uv[b], ba[a][b]);
      }
  }
#pragma unroll
  for (int a = 0; a < 8; ++a) {
    const int d = d0 + a;
    us4 hi, lo;
#pragma unroll
    for (int b = 0; b < 4; ++b) {
      float m = ((d == n0 + b) ? pC : 0.f) - ma[a][b];
      u16 h = f2bf(m);
      hi[b] = h;
      lo[b] = f2bf(m - bf2f(h));
    }
    *(us4*)&Mhi[(size_t)cid * 16384 + d * 128 + n0] = hi;
    *(us4*)&Mlo[(size_t)cid * 16384 + d * 128 + n0] = lo;
    float4 b0 = {ba[a][0], ba[a][1], ba[a][2], ba[a][3]};
    *(float4*)&Bg[(size_t)cid * 16384 + d * 128 + n0] = b0;
  }

  // G phase: Gt[d][i] tile 4d x 4i
  const int dg = (tid & 31) * 4, ig = (tid >> 5) * 4;
  float ga[4][4] = {};
  for (int j = 0; j < 64; ++j) {
    float4 w4 = *(const float4*)&Wl[j * 128 + dg];
    float4 m0 = *(const float4*)&Mql[j * 64 + ig];
    float wv[4] = {w4.x, w4.y, w4.z, w4.w};
    float mv[4] = {m0.x, m0.y, m0.z, m0.w};
#pragma unroll
    for (int a = 0; a < 4; ++a)
#pragma unroll
      for (int b = 0; b < 4; ++b) ga[a][b] = fmaf(wv[a], mv[b], ga[a][b]);
  }
#pragma unroll
  for (int a = 0; a < 4; ++a) {
    const int d = dg + a;
    float4 p0 = *(const float4*)&pQg[(size_t)cid * 8192 + d * 64 + ig];
    float4 g0 = {p0.x - ga[a][0], p0.y - ga[a][1], p0.z - ga[a][2], p0.w - ga[a][3]};
    *(float4*)&Gtg[(size_t)cid * 8192 + d * 64 + ig] = g0;
  }
}

// ---------------------------------------------------------------------------
// scan_S v4: 128 blocks = 16 heads x 8 col-slices of 16, XCD-grouped
// (flat%8 == hv%8 so all 8 slices of a head share one L2 copy of M).
// M AND B both register-prefetched one chunk ahead (named double buffers).
// ---------------------------------------------------------------------------
__global__ __launch_bounds__(512) void scan_S(
    const u16* __restrict__ Mhi, const u16* __restrict__ Mlo,
    const float* __restrict__ Bg, float* __restrict__ Sg) {
  const int flat = blockIdx.x;
  const int hv = (flat & 7) + 8 * (flat >> 6);
  const int vs = (flat >> 3) & 7;
  const int tid = threadIdx.x;
  const int wave = tid >> 6, lane = tid & 63;
  const int fr = lane & 15, fq = lane >> 4;
  const int wr = wave * 16;       // this wave's 16 output rows
  const int m0 = vs * 16;         // col-slice base

  __shared__ u16 Sh[2][2048];     // [16 m][128 k] bf16-hi, XOR-swizzled
  __shared__ u16 Sl[2][2048];

  for (int i = tid; i < 2048; i += 512) { Sh[0][i] = 0; Sl[0][i] = 0; }
  {
    float* s0 = Sg + (size_t)hv * 16384 + m0;
#pragma unroll
    for (int it = 0; it < 4; ++it) {
      int idx = it * 512 + tid;          // 2048 = 128 d x 16 m
      s0[(size_t)(idx >> 4) * 128 + (idx & 15)] = 0.f;
    }
  }
  __syncthreads();

  bf16x8 MhA[4], MlA[4], MhB[4], MlB[4];
  float bvA[4], bvB[4];
  {
    const u16* Mh0 = Mhi + (size_t)hv * 16384;
    const u16* Ml0 = Mlo + (size_t)hv * 16384;
#pragma unroll
    for (int kt = 0; kt < 4; ++kt) {
      size_t off = (size_t)(wr + fr) * 128 + kt * 32 + fq * 8;
      MhA[kt] = *(const bf16x8*)&Mh0[off];
      MlA[kt] = *(const bf16x8*)&Ml0[off];
    }
    const float* Bc = Bg + (size_t)hv * 16384 + m0;
#pragma unroll
    for (int j = 0; j < 4; ++j)
      bvA[j] = Bc[(size_t)(wr + fq * 4 + j) * 128 + fr];
  }
  int p = 0;

  auto step = [&](int c, bf16x8 (&MhC)[4], bf16x8 (&MlC)[4], float (&bvC)[4],
                  bf16x8 (&MhN)[4], bf16x8 (&MlN)[4], float (&bvN)[4]) {
    // prefetch next chunk's M frags + B values (consumed next step)
    if (c + 1 < NC_ - 1) {
      const u16* MhP = Mhi + (size_t)((c + 1) * 16 + hv) * 16384;
      const u16* MlP = Mlo + (size_t)((c + 1) * 16 + hv) * 16384;
#pragma unroll
      for (int kt = 0; kt < 4; ++kt) {
        size_t off = (size_t)(wr + fr) * 128 + kt * 32 + fq * 8;
        MhN[kt] = *(const bf16x8*)&MhP[off];
        MlN[kt] = *(const bf16x8*)&MlP[off];
      }
      const float* BcN = Bg + (size_t)((c + 1) * 16 + hv) * 16384 + m0;
#pragma unroll
      for (int j = 0; j < 4; ++j)
        bvN[j] = BcN[(size_t)(wr + fq * 4 + j) * 128 + fr];
    }

    // acc = M_c @ S_c  (bf16 hi/lo x3), 16-col slice: single B fragment
    f32x4v acc = {};
#pragma unroll
    for (int kt = 0; kt < 4; ++kt) {
      const int m = fr;
      const int byte = m * 256 + ((kt * 64 + fq * 16) ^ ((m & 7) << 4));
      bf16x8 BhF = *(const bf16x8*)((const char*)&Sh[p][0] + byte);
      bf16x8 BlF = *(const bf16x8*)((const char*)&Sl[p][0] + byte);
      acc = __builtin_amdgcn_mfma_f32_16x16x32_bf16(MlC[kt], BhF, acc, 0, 0, 0);
      acc = __builtin_amdgcn_mfma_f32_16x16x32_bf16(MhC[kt], BlF, acc, 0, 0, 0);
      acc = __builtin_amdgcn_mfma_f32_16x16x32_bf16(MhC[kt], BhF, acc, 0, 0, 0);
    }

    // S_{c+1} = acc + B (B from registers, prefetched last step)
    float* Sn = Sg + (size_t)((c + 1) * 16 + hv) * 16384 + m0;
    const int k0 = wr + fq * 4;
    const int m = fr;
    us4 h4, l4;
#pragma unroll
    for (int j = 0; j < 4; ++j) {
      float v = acc[j] + bvC[j];
      Sn[(size_t)(k0 + j) * 128 + m] = v;
      u16 h = f2bf(v);
      h4[j] = h;
      l4[j] = f2bf(v - bf2f(h));
    }
    const int wbyte = m * 256 + ((k0 * 2) ^ ((m & 7) << 4));
    *(us4*)((char*)&Sh[p ^ 1][0] + wbyte) = h4;
    *(us4*)((char*)&Sl[p ^ 1][0] + wbyte) = l4;
    __syncthreads();
    p ^= 1;
  };

  for (int cc = 0; cc < NC_ - 1; cc += 2) {
    step(cc, MhA, MlA, bvA, MhB, MlB, bvB);
    if (cc + 1 < NC_ - 1) step(cc + 1, MhB, MlB, bvB, MhA, MlA, bvA);
  }
}

// ---------------------------------------------------------------------------
// chunk_out + fused gated rmsnorm (parallel, 256 blocks):
//   o_i[m] = sum_j Mq[j][i] U[j][m] + sum_d Gt[d][i] S[d][m]
//   h = o*silu(z); h *= rsqrt(mean_m(h^2)+eps)*norm_w; -> bf16 (permuted)
// ---------------------------------------------------------------------------
__global__ __launch_bounds__(256) void chunk_out(
    const float* __restrict__ Mqg, const float* __restrict__ Ug,
    const float* __restrict__ Gtg, const float* __restrict__ Sg,
    const float* __restrict__ zbuf, const float* __restrict__ norm_w,
    u16* __restrict__ h) {
  const int c = blockIdx.x, hv = blockIdx.y;
  const int cid = c * 16 + hv;
  const int tid = threadIdx.x;
  __shared__ float Mql[64 * 64];
  __shared__ float Ul[64 * 128];
  __shared__ float Gtl[128 * 64];
  __shared__ float Sl[128 * 128];
  __shared__ float red[64][16];
#pragma unroll
  for (int it = 0; it < 4; ++it) {
    int f = it * 1024 + tid * 4;
    *(float4*)&Mql[f] = *(const float4*)&Mqg[(size_t)cid * 4096 + f];
  }
#pragma unroll
  for (int it = 0; it < 8; ++it) {
    int f = it * 1024 + tid * 4;
    *(float4*)&Ul[f]  = *(const float4*)&Ug[(size_t)cid * 8192 + f];
    *(float4*)&Gtl[f] = *(const float4*)&Gtg[(size_t)cid * 8192 + f];
  }
#pragma unroll
  for (int it = 0; it < 16; ++it) {
    int f = it * 1024 + tid * 4;
    *(float4*)&Sl[f] = *(const float4*)&Sg[(size_t)cid * 16384 + f];
  }
  __syncthreads();

  const int i0 = (tid & 15) * 4, m0 = (tid >> 4) * 8;
  float oa[4][8] = {};
  for (int j = 0; j < 64; ++j) {
    float4 mq = *(const float4*)&Mql[j * 64 + i0];
    float4 u0 = *(const float4*)&Ul[j * 128 + m0];
    float4 u1 = *(const float4*)&Ul[j * 128 + m0 + 4];
    float mv[4] = {mq.x, mq.y, mq.z, mq.w};
    float uv[8] = {u0.x, u0.y, u0.z, u0.w, u1.x, u1.y, u1.z, u1.w};
#pragma unroll
    for (int a = 0; a < 4; ++a)
#pragma unroll
      for (int b = 0; b < 8; ++b) oa[a][b] = fmaf(mv[a], uv[b], oa[a][b]);
  }
  for (int d = 0; d < 128; ++d) {
    float4 gt = *(const float4*)&Gtl[d * 64 + i0];
    float4 s0 = *(const float4*)&Sl[d * 128 + m0];
    float4 s1 = *(const float4*)&Sl[d * 128 + m0 + 4];
    float gv[4] = {gt.x, gt.y, gt.z, gt.w};
    float sv[8] = {s0.x, s0.y, s0.z, s0.w, s1.x, s1.y, s1.z, s1.w};
#pragma unroll
    for (int a = 0; a < 4; ++a)
#pragma unroll
      for (int b = 0; b < 8; ++b) oa[a][b] = fmaf(gv[a], sv[b], oa[a][b]);
  }

  // ---- fused gated rmsnorm over the m-dimension (per row) ----
  float hva[4][8];
#pragma unroll
  for (int a = 0; a < 4; ++a) {
    const int t = c * 64 + i0 + a;
    float4 z0 = *(const float4*)&zbuf[(size_t)t * VD_ + hv * 128 + m0];
    float4 z1 = *(const float4*)&zbuf[(size_t)t * VD_ + hv * 128 + m0 + 4];
    float zv[8] = {z0.x, z0.y, z0.z, z0.w, z1.x, z1.y, z1.z, z1.w};
    float ss = 0.f;
#pragma unroll
    for (int b = 0; b < 8; ++b) {
      float hc = oa[a][b] * (zv[b] / (1.f + expf(-zv[b])));
      hva[a][b] = hc;
      ss = fmaf(hc, hc, ss);
    }
    red[i0 + a][tid >> 4] = ss;
  }
  __syncthreads();
  float4 nw0 = *(const float4*)&norm_w[m0];
  float4 nw1 = *(const float4*)&norm_w[m0 + 4];
  float nw[8] = {nw0.x, nw0.y, nw0.z, nw0.w, nw1.x, nw1.y, nw1.z, nw1.w};
#pragma unroll
  for (int a = 0; a < 4; ++a) {
    const int t = c * 64 + i0 + a;
    float tot = 0.f;
#pragma unroll
    for (int w = 0; w < 16; ++w) tot += red[i0 + a][w];
    float r = rsqrtf(tot * (1.f / 128.f) + 1e-6f);
    us8 hv8;
#pragma unroll
    for (int b = 0; b < 8; ++b) hv8[b] = f2bf(hva[a][b] * r * nw[b]);
    *(us8*)&h[(size_t)t * VD_ + permk3(t, hv * 128 + m0)] = hv8;
  }
}

// ---------------------------------------------------------------------------
extern "C" void kernel_launch(void* const* d_in, const int* in_sizes, int n_in,
                              void* d_out, int out_size, void* d_ws, size_t ws_size,
                              hipStream_t stream) {
  const float* x       = (const float*)d_in[0];
  const float* w_qkvz  = (const float*)d_in[1];
  const float* w_ba    = (const float*)d_in[2];
  const float* conv_w  = (const float*)d_in[3];
  const float* conv_b  = (const float*)d_in[4];
  const float* a_log   = (const float*)d_in[5];
  const float* dt_bias = (const float*)d_in[6];
  const float* norm_w  = (const float*)d_in[7];
  const float* w_o     = (const float*)d_in[8];
  float* out = (float*)d_out;

  float* ws = (float*)d_ws;
  float* qkvraw = ws;                  // 4,194,304  (-> Bg)
  float* zbuf   = ws + 4194304;        // 2,097,152
  float* qkvc   = ws + 6291456;        // 4,194,304  (-> Mhi|Mlo, -> wot)
  float* khat   = ws + 10485760;       // 1,048,576  (-> hb)
  float* gbuf   = ws + 11534336;       // 16,384
  float* bbuf   = ws + 11550720;       // 16,384
  float* cgbuf  = ws + 11567104;       // 16,384
  float* obuf   = ws + 11583488;       // 2,097,152  (xb early)
  float* Wtg    = ws + 13680640;       // 2,097,152 ┐ -> Sg (4,194,304)
  float* pQg    = ws + 15777792;       // 2,097,152 ┘
  float* Ug     = ws + 17874944;       // 2,097,152
  float* Mqg    = ws + 19972096;       // 1,048,576
  float* Gtg    = ws + 21020672;       // 2,097,152

  u16* xb   = (u16*)obuf;      // x bf16 (dead after gemm1)
  u16* wqt  = (u16*)Wtg;       // w_qkvz^T bf16 (dead after gemm1)
  u16* Mhi  = (u16*)qkvc;
  u16* Mlo  = (u16*)(qkvc + 2097152);
  float* Bg = qkvraw;
  float* Sg = Wtg;
  u16* wot  = (u16*)qkvc;      // after scan_S (Mhi dead)
  u16* hb   = (u16*)khat;      // after make_MBG (khat dead)

  // 0) fused beta/g + x->bf16 cast (permuted staging layout)
  ba_gbeta_cast<<<T_, 256, 0, stream>>>(x, w_ba, a_log, dt_bias,
                                        gbuf, bbuf, xb);
  transpose_bf16<<<dim3(32, 96), 256, 0, stream>>>(w_qkvz, wqt, H_, QN_);
  // 1) qkv|z = x @ w_qkvz
  gemm_bf16<128><<<768, 256, 0, stream>>>(xb, wqt, qkvraw, CD_, zbuf, VD_,
                                          CD_, T_, QN_, H_);
  // 2) fused conv + silu + k-l2norm
  conv_silu_k<<<T_, 512, 0, stream>>>(qkvraw, conv_w, conv_b, qkvc, khat);
  // 3) chunk-local precompute (parallel, 512 thr)
  chunk_prep<<<dim3(NC_, HV_), 512, 0, stream>>>(
      qkvc, khat, gbuf, bbuf, cgbuf, Wtg, Ug, Mqg, pQg);
  // 4) per-chunk transition/output operators (parallel, 512 thr)
  make_MBG<<<dim3(NC_, HV_), 512, 0, stream>>>(
      Wtg, pQg, Ug, Mqg, khat, cgbuf, Mhi, Mlo, Bg, Gtg);
  // 5) sequential state scan (128 blocks, M+B reg-prefetched)
  scan_S<<<128, 512, 0, stream>>>(Mhi, Mlo, Bg, Sg);
  // 6) w_o^T cast (Mhi region now dead)
  transpose_bf16<<<dim3(32, 32), 256, 0, stream>>>(w_o, wot, VD_, H_);
  // 7) per-chunk outputs + fused gated rmsnorm -> bf16 h (permuted)
  chunk_out<<<dim3(NC_, HV_), 256, 0, stream>>>(
      Mqg, Ug, Gtg, Sg, zbuf, norm_w, hb);
  // 8) out = h @ w_o  (BM=64: 512 blocks = 2/CU for latency hiding)
  gemm_bf16<64><<<512, 256, 0, stream>>>(hb, wot, out, VD_, out, VD_,
                                         VD_, T_, VD_, H_);
}

// Round 19
// 232.861 us; speedup vs baseline: 1.1597x; 1.0025x over previous
//
#include <hip/hip_runtime.h>
#include <math.h>

typedef unsigned short u16;
using us4  = __attribute__((ext_vector_type(4))) unsigned short;
using us8  = __attribute__((ext_vector_type(8))) unsigned short;
using bf16x8 = __attribute__((ext_vector_type(8))) __bf16;
using f32x4v = __attribute__((ext_vector_type(4))) float;

// Problem constants
#define T_    1024
#define H_    2048
#define HK_   8
#define HV_   16
#define KD_   1024
#define VD_   2048
#define CD_   4096
#define QN_   6144   // 2*KD + 2*VD
#define NC_   16     // number of chunks
#define C_    64     // chunk length

__device__ __forceinline__ u16 f2bf(float f) {
  unsigned u = __float_as_uint(f);
  u += 0x7fffu + ((u >> 16) & 1u);   // RNE
  return (u16)(u >> 16);
}
__device__ __forceinline__ float bf2f(u16 h) {
  return __uint_as_float(((unsigned)h) << 16);
}
// staging layout for gemm: within each 64-elem k-group, 8-elem chunk c of
// row r is stored at chunk position c ^ (r&7).
__device__ __forceinline__ int permk3(int r, int k) {
  return (k & ~63) | ((((k >> 3) & 7) ^ (r & 7)) << 3) | (k & 7);
}

// ---------------------------------------------------------------------------
// f32 [R][C] -> bf16 [C][R] transpose + cast + chunk permutation
// ---------------------------------------------------------------------------
__global__ __launch_bounds__(256) void transpose_bf16(
    const float* __restrict__ in, u16* __restrict__ out, int R, int C) {
  __shared__ float tile[64][65];
  const int r0 = blockIdx.x * 64, c0 = blockIdx.y * 64;
  const int t = threadIdx.x;
  const int tr = t >> 4, tc4 = (t & 15) * 4;
#pragma unroll
  for (int i = 0; i < 4; ++i) {
    float4 v = *(const float4*)&in[(size_t)(r0 + tr + i * 16) * C + c0 + tc4];
    tile[tr + i * 16][tc4 + 0] = v.x;
    tile[tr + i * 16][tc4 + 1] = v.y;
    tile[tr + i * 16][tc4 + 2] = v.z;
    tile[tr + i * 16][tc4 + 3] = v.w;
  }
  __syncthreads();
#pragma unroll
  for (int i = 0; i < 4; ++i) {
    int oc = tr + i * 16;
    int row = c0 + oc;
    int k = r0 + tc4;
    us4 w = {f2bf(tile[tc4 + 0][oc]), f2bf(tile[tc4 + 1][oc]),
             f2bf(tile[tc4 + 2][oc]), f2bf(tile[tc4 + 3][oc])};
    *(us4*)&out[(size_t)row * R + permk3(row, k)] = w;
  }
}

// ---------------------------------------------------------------------------
// bf16 MFMA GEMM helpers
// ---------------------------------------------------------------------------
__device__ __forceinline__ void gload_lds16(const void* g, void* l) {
  __builtin_amdgcn_global_load_lds(
      (const __attribute__((address_space(1))) void*)g,
      (__attribute__((address_space(3))) void*)l, 16, 0, 0);
}

// ---------------------------------------------------------------------------
// gemm1 variant: 128x64 tile, BK=64, 512 threads (8 waves as 4x2, each wave
// owns a 32x32 output). Same 48KB 2-buffer LDS -> 3 blocks/CU = 24 waves/CU.
// XCD-grouped 1D block mapping, 3-bit permuted staging, counted vmcnt.
// ---------------------------------------------------------------------------
__global__ __launch_bounds__(512) void gemm_bf16_w8(
    const u16* __restrict__ A, const u16* __restrict__ Bt,
    float* __restrict__ Cq, int ldq, float* __restrict__ Cz, int ldz,
    int zsplit, int M, int N, int K) {
  __shared__ __align__(16) u16 As[2][8192];   // [128][64]
  __shared__ __align__(16) u16 Bs[2][4096];   // [64][64]
  const int tid  = threadIdx.x;
  const int wave = tid >> 6, lane = tid & 63;
  const int gy = N >> 6;
  const int ncolpx = gy >> 3;
  const int bid = blockIdx.x;
  const int xcd = bid & 7, idx = bid >> 3;
  const int row0 = (idx / ncolpx) * 128;
  const int col0 = (xcd * ncolpx + idx % ncolpx) * 64;
  const int wr = wave >> 1, wc = wave & 1;   // 4x2 wave grid
  const int fr = lane & 15, fq = lane >> 4;

  const int sr8 = lane >> 3;
  const int sc8 = (lane & 7) * 8;
  const u16* gA = A  + (size_t)(row0 + wave * 16 + sr8) * K + sc8;
  const u16* gB = Bt + (size_t)(col0 + wave * 8 + sr8) * K + sc8;

  f32x4v acc[2][2] = {};
  const int nt = K >> 6;

  // one stage issues exactly 3 global_load_lds per wave (2 A + 1 B)
  auto stage = [&](int p, int k0) {
#pragma unroll
    for (int j = 0; j < 2; ++j)
      gload_lds16(gA + (size_t)(j * 8) * K + k0,
                  &As[p][(wave * 16 + j * 8) * 64]);
    gload_lds16(gB + k0, &Bs[p][(wave * 8) * 64]);
  };

  stage(0, 0);

  int p = 0;
  for (int it = 0; it < nt; ++it) {
    if (it + 1 < nt) stage(p ^ 1, (it + 1) * 64);
    if (it + 1 < nt) asm volatile("s_waitcnt vmcnt(3)" ::: "memory");
    else             asm volatile("s_waitcnt vmcnt(0)" ::: "memory");
    __builtin_amdgcn_s_barrier();

#pragma unroll
    for (int kt = 0; kt < 2; ++kt) {
      bf16x8 af[2], bff[2];
#pragma unroll
      for (int mi = 0; mi < 2; ++mi) {
        const int r = wr * 32 + mi * 16 + fr;
        af[mi] = *(const bf16x8*)
            &As[p][r * 64 + kt * 32 + (((kt * 4 + fq) ^ (r & 7)) & 3) * 8
                   + ((((kt * 4 + fq) ^ (r & 7)) >> 2) - kt) * 32];
      }
#pragma unroll
      for (int ni = 0; ni < 2; ++ni) {
        const int r = wc * 32 + ni * 16 + fr;
        bff[ni] = *(const bf16x8*)
            &Bs[p][r * 64 + kt * 32 + (((kt * 4 + fq) ^ (r & 7)) & 3) * 8
                   + ((((kt * 4 + fq) ^ (r & 7)) >> 2) - kt) * 32];
      }
#pragma unroll
      for (int mi = 0; mi < 2; ++mi)
#pragma unroll
        for (int ni = 0; ni < 2; ++ni)
          acc[mi][ni] = __builtin_amdgcn_mfma_f32_16x16x32_bf16(
              af[mi], bff[ni], acc[mi][ni], 0, 0, 0);
    }
    if (it + 1 < nt) {
      asm volatile("s_waitcnt lgkmcnt(0)" ::: "memory");
      __builtin_amdgcn_s_barrier();
    }
    p ^= 1;
  }

  float* Cp; int ldc, cb;
  if (col0 < zsplit) { Cp = Cq; ldc = ldq; cb = col0; }
  else               { Cp = Cz; ldc = ldz; cb = col0 - zsplit; }
#pragma unroll
  for (int mi = 0; mi < 2; ++mi)
#pragma unroll
    for (int ni = 0; ni < 2; ++ni) {
      const int r  = row0 + wr * 32 + mi * 16 + fq * 4;
      const int cc = cb + wc * 32 + ni * 16 + fr;
#pragma unroll
      for (int j = 0; j < 4; ++j)
        Cp[(size_t)(r + j) * ldc + cc] = acc[mi][ni][j];
    }
}

// ---------------------------------------------------------------------------
// bf16 MFMA GEMM (BM template, 256 thr, 4 waves): used for gemm2 (BM=64).
// ---------------------------------------------------------------------------
template <int BM>
__global__ __launch_bounds__(256) void gemm_bf16(
    const u16* __restrict__ A, const u16* __restrict__ Bt,
    float* __restrict__ Cq, int ldq, float* __restrict__ Cz, int ldz,
    int zsplit, int M, int N, int K) {
  constexpr int MI = BM / 32;               // A-frags per wave
  __shared__ __align__(16) u16 As[2][BM * 64];
  __shared__ __align__(16) u16 Bs[2][4096];   // [64][64]
  const int tid  = threadIdx.x;
  const int wave = tid >> 6, lane = tid & 63;
  const int gy = N >> 6;
  const int ncolpx = gy >> 3;
  const int bid = blockIdx.x;
  const int xcd = bid & 7, idx = bid >> 3;
  const int row0 = (idx / ncolpx) * BM;
  const int col0 = (xcd * ncolpx + idx % ncolpx) * 64;
  const int wr = wave >> 1, wc = wave & 1;
  const int fr = lane & 15, fq = lane >> 4;

  const int sr8 = lane >> 3;
  const int sc8 = (lane & 7) * 8;
  const u16* gA = A  + (size_t)(row0 + wave * (BM / 4) + sr8) * K + sc8;
  const u16* gB = Bt + (size_t)(col0 + wave * 16 + sr8) * K + sc8;

  f32x4v acc[MI][2] = {};
  const int nt = K >> 6;

  auto stage = [&](int p, int k0) {
#pragma unroll
    for (int j = 0; j < BM / 32; ++j)
      gload_lds16(gA + (size_t)(j * 8) * K + k0,
                  &As[p][(wave * (BM / 4) + j * 8) * 64]);
#pragma unroll
    for (int j = 0; j < 2; ++j)
      gload_lds16(gB + (size_t)(j * 8) * K + k0,
                  &Bs[p][(wave * 16 + j * 8) * 64]);
  };

  stage(0, 0);

  int p = 0;
  for (int it = 0; it < nt; ++it) {
    if (it + 1 < nt) stage(p ^ 1, (it + 1) * 64);
    if (it + 1 < nt) {
      if constexpr (BM == 128)
        asm volatile("s_waitcnt vmcnt(6)" ::: "memory");
      else
        asm volatile("s_waitcnt vmcnt(4)" ::: "memory");
    } else {
      asm volatile("s_waitcnt vmcnt(0)" ::: "memory");
    }
    __builtin_amdgcn_s_barrier();

#pragma unroll
    for (int kt = 0; kt < 2; ++kt) {
      bf16x8 af[MI], bff[2];
#pragma unroll
      for (int mi = 0; mi < MI; ++mi) {
        const int r = wr * (BM / 2) + mi * 16 + fr;
        af[mi] = *(const bf16x8*)
            &As[p][r * 64 + kt * 32 + (((kt * 4 + fq) ^ (r & 7)) & 3) * 8
                   + ((((kt * 4 + fq) ^ (r & 7)) >> 2) - kt) * 32];
      }
#pragma unroll
      for (int ni = 0; ni < 2; ++ni) {
        const int r = wc * 32 + ni * 16 + fr;
        bff[ni] = *(const bf16x8*)
            &Bs[p][r * 64 + kt * 32 + (((kt * 4 + fq) ^ (r & 7)) & 3) * 8
                   + ((((kt * 4 + fq) ^ (r & 7)) >> 2) - kt) * 32];
      }
#pragma unroll
      for (int mi = 0; mi < MI; ++mi)
#pragma unroll
        for (int ni = 0; ni < 2; ++ni)
          acc[mi][ni] = __builtin_amdgcn_mfma_f32_16x16x32_bf16(
              af[mi], bff[ni], acc[mi][ni], 0, 0, 0);
    }
    if (it + 1 < nt) {
      asm volatile("s_waitcnt lgkmcnt(0)" ::: "memory");
      __builtin_amdgcn_s_barrier();
    }
    p ^= 1;
  }

  float* Cp; int ldc, cb;
  if (col0 < zsplit) { Cp = Cq; ldc = ldq; cb = col0; }
  else               { Cp = Cz; ldc = ldz; cb = col0 - zsplit; }
#pragma unroll
  for (int mi = 0; mi < MI; ++mi)
#pragma unroll
    for (int ni = 0; ni < 2; ++ni) {
      const int r  = row0 + wr * (BM / 2) + mi * 16 + fq * 4;
      const int cc = cb + wc * 32 + ni * 16 + fr;
#pragma unroll
      for (int j = 0; j < 4; ++j)
        Cp[(size_t)(r + j) * ldc + cc] = acc[mi][ni][j];
    }
}

// ---------------------------------------------------------------------------
// fused: xb = bf16(x) (permuted staging layout)  +
//        ba = x @ w_ba -> beta = sigmoid(b), g = -exp(a_log)*softplus(a+dt)
// ---------------------------------------------------------------------------
__global__ __launch_bounds__(256) void ba_gbeta_cast(
    const float* __restrict__ x, const float* __restrict__ w_ba,
    const float* __restrict__ a_log, const float* __restrict__ dt_bias,
    float* __restrict__ g, float* __restrict__ beta, u16* __restrict__ xb) {
  const int t = blockIdx.x;
  const int tid = threadIdx.x;
  __shared__ float xs[2048];
  __shared__ float red[8][32];
  {
    float4 v = *(const float4*)&x[(size_t)t * H_ + tid * 4];
    *(float4*)&xs[tid * 4] = v;
    float4 w = *(const float4*)&x[(size_t)t * H_ + 1024 + tid * 4];
    *(float4*)&xs[1024 + tid * 4] = w;
  }
  __syncthreads();
  // emit xb chunk (8 bf16) in permuted layout: chunk tid of row t
  {
    const float* src = &xs[tid * 8];
    us8 r = {f2bf(src[0]), f2bf(src[1]), f2bf(src[2]), f2bf(src[3]),
             f2bf(src[4]), f2bf(src[5]), f2bf(src[6]), f2bf(src[7])};
    const int ip = (tid & ~7) | ((tid & 7) ^ (t & 7));
    *(us8*)&xb[(size_t)t * H_ + ip * 8] = r;
  }
  const int c = tid & 31;
  const int chunk = tid >> 5;
  float p = 0.f;
  const int kb = chunk * 256;
#pragma unroll 4
  for (int k = kb; k < kb + 256; ++k) p = fmaf(xs[k], w_ba[k * 32 + c], p);
  red[chunk][c] = p;
  __syncthreads();
  if (tid < 32) {
    float s = 0.f;
#pragma unroll
    for (int i = 0; i < 8; ++i) s += red[i][c];
    if (c < 16) {
      beta[t * 16 + c] = 1.f / (1.f + expf(-s));
    } else {
      int h = c - 16;
      float xx = s + dt_bias[h];
      float sp = xx > 20.f ? xx : log1pf(expf(xx));
      g[t * 16 + h] = -expf(a_log[h]) * sp;
    }
  }
}

// ---------------------------------------------------------------------------
// fused causal depthwise conv1d (K=4) + SiLU + k-l2norm.
// ---------------------------------------------------------------------------
__global__ __launch_bounds__(512) void conv_silu_k(
    const float* __restrict__ qkvraw, const float* __restrict__ conv_w,
    const float* __restrict__ conv_b, float* __restrict__ qkvc,
    float* __restrict__ khat) {
  const int t = blockIdx.x;
  const int tid = threadIdx.x;
  const int c0 = tid * 8;
  float acc[8];
  float4 cb0 = *(const float4*)&conv_b[c0];
  float4 cb1 = *(const float4*)&conv_b[c0 + 4];
  acc[0] = cb0.x; acc[1] = cb0.y; acc[2] = cb0.z; acc[3] = cb0.w;
  acc[4] = cb1.x; acc[5] = cb1.y; acc[6] = cb1.z; acc[7] = cb1.w;
  float wv[8][4];
#pragma unroll
  for (int i = 0; i < 8; i += 2) {
    float4 w0 = *(const float4*)&conv_w[(c0 + i) * 4];
    float4 w1 = *(const float4*)&conv_w[(c0 + i + 1) * 4];
    wv[i][0] = w0.x; wv[i][1] = w0.y; wv[i][2] = w0.z; wv[i][3] = w0.w;
    wv[i+1][0] = w1.x; wv[i+1][1] = w1.y; wv[i+1][2] = w1.z; wv[i+1][3] = w1.w;
  }
#pragma unroll
  for (int j = 0; j < 4; ++j) {
    int tt = t - 3 + j;
    if (tt >= 0) {
      float4 a = *(const float4*)&qkvraw[(size_t)tt * CD_ + c0];
      float4 b = *(const float4*)&qkvraw[(size_t)tt * CD_ + c0 + 4];
      float xv[8] = {a.x, a.y, a.z, a.w, b.x, b.y, b.z, b.w};
#pragma unroll
      for (int i = 0; i < 8; ++i) acc[i] = fmaf(xv[i], wv[i][j], acc[i]);
    }
  }
  float y[8];
#pragma unroll
  for (int i = 0; i < 8; ++i) y[i] = acc[i] / (1.f + expf(-acc[i]));

  if (tid < 128 || tid >= 256) {
    float4 o0 = {y[0], y[1], y[2], y[3]};
    float4 o1 = {y[4], y[5], y[6], y[7]};
    *(float4*)&qkvc[(size_t)t * CD_ + c0]     = o0;
    *(float4*)&qkvc[(size_t)t * CD_ + c0 + 4] = o1;
  } else {
    float ss = 0.f;
#pragma unroll
    for (int i = 0; i < 8; ++i) ss = fmaf(y[i], y[i], ss);
#pragma unroll
    for (int off = 1; off < 16; off <<= 1) ss += __shfl_xor(ss, off);
    float rs = rsqrtf(ss + 1e-6f);
    const int head = (c0 - 1024) >> 7;
    const int d0 = (c0 - 1024) & 127;
    float4 o0 = {y[0] * rs, y[1] * rs, y[2] * rs, y[3] * rs};
    float4 o1 = {y[4] * rs, y[5] * rs, y[6] * rs, y[7] * rs};
    float* kout = &khat[((size_t)t * HK_ + head) * 128 + d0];
    *(float4*)&kout[0] = o0;
    *(float4*)&kout[4] = o1;
  }
}

// ---------------------------------------------------------------------------
// Chunked gated delta rule, phase A (parallel over 16 chunks x 16 heads).
// 512 threads (8 waves). Dot phase 4x2 tiles/thread; during the serial
// forward substitution (waves 0-3), waves 4-7 write Mqg and pQg.
// ---------------------------------------------------------------------------
#define SWZ(r) (((r) >> 2) & 7)

__device__ __forceinline__ float4 ldsw4(const float* base, int r, int dblk) {
  return *(const float4*)&base[r * 128 + ((dblk ^ SWZ(r)) << 2)];
}
__device__ __forceinline__ float ldsw1(const float* base, int r, int d) {
  return base[r * 128 + ((((d) >> 2) ^ SWZ(r)) << 2) + ((d) & 3)];
}

__global__ __launch_bounds__(512) void chunk_prep(
    const float* __restrict__ qkvc, const float* __restrict__ khat,
    const float* __restrict__ g, const float* __restrict__ beta,
    float* __restrict__ cgbuf, float* __restrict__ Wtg, float* __restrict__ Ug,
    float* __restrict__ Mqg, float* __restrict__ pQg) {
  const int c = blockIdx.x, hv = blockIdx.y, hk = hv >> 1;
  const int cid = c * 16 + hv;
  const int tid = threadIdx.x;
  __shared__ float Kl[8192], Ql[8192];   // swizzled [64][128]
  __shared__ float AM[8320];             // At[64][65] | Mq[64][65]; later Utr
  __shared__ float cgl[64], bl[64], bp[64], rsl[64];
  float* At = AM;
  float* Mq = AM + 4160;

#pragma unroll
  for (int it = 0; it < 4; ++it) {
    int flat = it * 2048 + tid * 4;
    int row = flat >> 7, d = flat & 127;
    int pb = ((d >> 2) ^ SWZ(row)) << 2;
    int gt = c * 64 + row;
    float4 kv = *(const float4*)&khat[((size_t)gt * HK_ + hk) * 128 + d];
    float4 qv = *(const float4*)&qkvc[(size_t)gt * CD_ + hk * 128 + d];
    *(float4*)&Kl[row * 128 + pb] = kv;
    *(float4*)&Ql[row * 128 + pb] = qv;
  }
  if (tid < 64) {
    float s = g[(size_t)(c * 64 + tid) * HV_ + hv];
#pragma unroll
    for (int off = 1; off < 64; off <<= 1) {
      float t = __shfl_up(s, off);
      if (tid >= off) s += t;
    }
    cgl[tid] = s;
    cgbuf[cid * 64 + tid] = s;
    bl[tid] = beta[(size_t)(c * 64 + tid) * HV_ + hv];
  }
  __syncthreads();
  if (tid < 64) {
    float sq = 0.f;
#pragma unroll
    for (int dblk = 0; dblk < 32; ++dblk) {
      float4 q4 = ldsw4(Ql, tid, dblk);
      sq = fmaf(q4.x, q4.x, sq); sq = fmaf(q4.y, q4.y, sq);
      sq = fmaf(q4.z, q4.z, sq); sq = fmaf(q4.w, q4.w, sq);
    }
    rsl[tid] = rsqrtf(sq + 1e-6f) * 0.08838834764831845f;
    bp[tid] = bl[tid] * expf(cgl[tid]);
  }
  __syncthreads();

  // dot phase: 4x2 tile of (i,j) pairs per thread (512 threads)
  const int i0 = (tid >> 5) * 4, j0 = (tid & 31) * 2;
  float kk[4][2], qk[4][2];
#pragma unroll
  for (int a = 0; a < 4; ++a)
#pragma unroll
    for (int b = 0; b < 2; ++b) { kk[a][b] = 0.f; qk[a][b] = 0.f; }
  for (int dblk = 0; dblk < 32; ++dblk) {
    float4 ka[4], qa[4], kb[2];
#pragma unroll
    for (int a = 0; a < 4; ++a) {
      ka[a] = ldsw4(Kl, i0 + a, dblk);
      qa[a] = ldsw4(Ql, i0 + a, dblk);
    }
#pragma unroll
    for (int b = 0; b < 2; ++b) kb[b] = ldsw4(Kl, j0 + b, dblk);
#pragma unroll
    for (int a = 0; a < 4; ++a)
#pragma unroll
      for (int b = 0; b < 2; ++b) {
        kk[a][b] = fmaf(ka[a].x, kb[b].x, kk[a][b]);
        kk[a][b] = fmaf(ka[a].y, kb[b].y, kk[a][b]);
        kk[a][b] = fmaf(ka[a].z, kb[b].z, kk[a][b]);
        kk[a][b] = fmaf(ka[a].w, kb[b].w, kk[a][b]);
        qk[a][b] = fmaf(qa[a].x, kb[b].x, qk[a][b]);
        qk[a][b] = fmaf(qa[a].y, kb[b].y, qk[a][b]);
        qk[a][b] = fmaf(qa[a].z, kb[b].z, qk[a][b]);
        qk[a][b] = fmaf(qa[a].w, kb[b].w, qk[a][b]);
      }
  }
#pragma unroll
  for (int a = 0; a < 4; ++a)
#pragma unroll
    for (int b = 0; b < 2; ++b) {
      int i = i0 + a, j = j0 + b;
      float e = expf(cgl[i] - cgl[j]);
      At[j * 65 + i] = (j < i) ? (-bl[i] * e * kk[a][b]) : 0.f;
      Mq[j * 65 + i] = (j <= i) ? (rsl[i] * e * qk[a][b]) : 0.f;
    }
  __syncthreads();

  float X[64];
  if (tid < 256) {
    // ---- waves 0-3: X init + forward substitution ----
    if (tid < 128) {
#pragma unroll
      for (int j = 0; j < 64; ++j) X[j] = bp[j] * ldsw1(Kl, j, tid);
    } else {
      const int m = tid - 128;
#pragma unroll
      for (int j = 0; j < 64; ++j)
        X[j] = bl[j] * qkvc[(size_t)(c * 64 + j) * CD_ + 2 * KD_ + hv * 128 + m];
    }
#pragma unroll
    for (int j = 0; j < 63; ++j) {
      float xj = X[j];
#pragma unroll
      for (int i = j + 1; i < 64; ++i) X[i] = fmaf(At[j * 65 + i], xj, X[i]);
    }
    if (tid < 128) {
      size_t baseo = ((size_t)cid * 128 + tid) * 64;
#pragma unroll
      for (int j4 = 0; j4 < 16; ++j4) {
        float4 v = {X[j4 * 4], X[j4 * 4 + 1], X[j4 * 4 + 2], X[j4 * 4 + 3]};
        *(float4*)&Wtg[baseo + j4 * 4] = v;
      }
    }
  } else {
    // ---- waves 4-7: Mqg + pQg writes (independent of solve) ----
    const int t2 = tid - 256;
#pragma unroll
    for (int it = 0; it < 16; ++it) {
      int f = it * 256 + t2;
      int j = f >> 6, i = f & 63;
      Mqg[(size_t)cid * 4096 + f] = Mq[j * 65 + i];
    }
    const int i = t2 & 63;
    const float ei = expf(cgl[i]) * rsl[i];
#pragma unroll
    for (int it = 0; it < 32; ++it) {
      int d = it * 4 + (t2 >> 6);
      pQg[(size_t)cid * 8192 + d * 64 + i] = ei * ldsw1(Ql, i, d);
    }
  }
  __syncthreads();   // At/Mq dead; X (U cols) ready

  if (tid >= 128 && tid < 256) {
    const int m = tid - 128;
    float* Utr = AM;
#pragma unroll
    for (int j = 0; j < 64; ++j) Utr[j * 128 + m] = X[j];
  }
  __syncthreads();
  {
    const float* Utr = AM;
#pragma unroll
    for (int it = 0; it < 4; ++it) {
      int flat = it * 2048 + tid * 4;
      *(float4*)&Ug[(size_t)cid * 8192 + flat] = *(const float4*)&Utr[flat];
    }
  }
}

// ---------------------------------------------------------------------------
// make_MBG (parallel, 256 blocks, 512 threads)
// ---------------------------------------------------------------------------
__global__ __launch_bounds__(512) void make_MBG(
    const float* __restrict__ Wtg, const float* __restrict__ pQg,
    const float* __restrict__ Ug, const float* __restrict__ Mqg,
    const float* __restrict__ khat, const float* __restrict__ cgbuf,
    u16* __restrict__ Mhi, u16* __restrict__ Mlo,
    float* __restrict__ Bg, float* __restrict__ Gtg) {
  const int c = blockIdx.x, hv = blockIdx.y, hk = hv >> 1;
  const int cid = c * 16 + hv;
  const int tid = threadIdx.x;
  __shared__ float Wl[64 * 128];   // W[j][d]
  __shared__ float Kel[64 * 128];  // esc_j * khat_j[d]
  __shared__ float Ul[64 * 128];
  __shared__ float Mql[64 * 64];
  const float cg63 = cgbuf[cid * 64 + 63];
  const float pC = expf(cg63);
#pragma unroll
  for (int it = 0; it < 4; ++it) {
    int f = it * 2048 + tid * 4;       // f = d*64 + j
    int d = f >> 6, j = f & 63;
    float4 w = *(const float4*)&Wtg[(size_t)cid * 8192 + f];
    Wl[(j + 0) * 128 + d] = w.x;
    Wl[(j + 1) * 128 + d] = w.y;
    Wl[(j + 2) * 128 + d] = w.z;
    Wl[(j + 3) * 128 + d] = w.w;
  }
#pragma unroll
  for (int it = 0; it < 4; ++it) {
    int f = it * 2048 + tid * 4;       // f = j*128 + d
    int j = f >> 7, d = f & 127;
    float esc = expf(cg63 - cgbuf[cid * 64 + j]);
    float4 kv = *(const float4*)&khat[((size_t)(c * 64 + j) * HK_ + hk) * 128 + d];
    float4 uv = *(const float4*)&Ug[(size_t)cid * 8192 + f];
    kv.x *= esc; kv.y *= esc; kv.z *= esc; kv.w *= esc;
    *(float4*)&Kel[f] = kv;
    *(float4*)&Ul[f] = uv;
  }
#pragma unroll
  for (int it = 0; it < 2; ++it) {
    int f = it * 2048 + tid * 4;
    *(float4*)&Mql[f] = *(const float4*)&Mqg[(size_t)cid * 4096 + f];
  }
  __syncthreads();

  // fused M+B: tile rows d0..d0+7, cols n0..n0+3
  const int d0 = (tid & 15) * 8, n0 = (tid >> 4) * 4;
  float ma[8][4] = {}, ba[8][4] = {};
  for (int j = 0; j < 64; ++j) {
    float4 k0 = *(const float4*)&Kel[j * 128 + d0];
    float4 k1 = *(const float4*)&Kel[j * 128 + d0 + 4];
    float4 w0 = *(const float4*)&Wl[j * 128 + n0];
    float4 u0 = *(const float4*)&Ul[j * 128 + n0];
    float ke[8] = {k0.x, k0.y, k0.z, k0.w, k1.x, k1.y, k1.z, k1.w};
    float wv[4] = {w0.x, w0.y, w0.z, w0.w};
    float uv[4] = {u0.x, u0.y, u0.z, u0.w};
#pragma unroll
    for (int a = 0; a < 8; ++a)
#pragma unroll
      for (int b = 0; b < 4; ++b) {
        ma[a][b] = fmaf(ke[a], wv[b], ma[a][b]);
        ba[a][b] = fmaf(ke[a], uv[b], ba[a][b]);
      }
  }
#pragma unroll
  for (int a = 0; a < 8; ++a) {
    const int d = d0 + a;
    us4 hi, lo;
#pragma unroll
    for (int b = 0; b < 4; ++b) {
      float m = ((d == n0 + b) ? pC : 0.f) - ma[a][b];
      u16 h = f2bf(m);
      hi[b] = h;
      lo[b] = f2bf(m - bf2f(h));
    }
    *(us4*)&Mhi[(size_t)cid * 16384 + d * 128 + n0] = hi;
    *(us4*)&Mlo[(size_t)cid * 16384 + d * 128 + n0] = lo;
    float4 b0 = {ba[a][0], ba[a][1], ba[a][2], ba[a][3]};
    *(float4*)&Bg[(size_t)cid * 16384 + d * 128 + n0] = b0;
  }

  // G phase: Gt[d][i] tile 4d x 4i
  const int dg = (tid & 31) * 4, ig = (tid >> 5) * 4;
  float ga[4][4] = {};
  for (int j = 0; j < 64; ++j) {
    float4 w4 = *(const float4*)&Wl[j * 128 + dg];
    float4 m0 = *(const float4*)&Mql[j * 64 + ig];
    float wv[4] = {w4.x, w4.y, w4.z, w4.w};
    float mv[4] = {m0.x, m0.y, m0.z, m0.w};
#pragma unroll
    for (int a = 0; a < 4; ++a)
#pragma unroll
      for (int b = 0; b < 4; ++b) ga[a][b] = fmaf(wv[a], mv[b], ga[a][b]);
  }
#pragma unroll
  for (int a = 0; a < 4; ++a) {
    const int d = dg + a;
    float4 p0 = *(const float4*)&pQg[(size_t)cid * 8192 + d * 64 + ig];
    float4 g0 = {p0.x - ga[a][0], p0.y - ga[a][1], p0.z - ga[a][2], p0.w - ga[a][3]};
    *(float4*)&Gtg[(size_t)cid * 8192 + d * 64 + ig] = g0;
  }
}

// ---------------------------------------------------------------------------
// scan_S v4: 128 blocks = 16 heads x 8 col-slices of 16, XCD-grouped
// (flat%8 == hv%8 so all 8 slices of a head share one L2 copy of M).
// M AND B both register-prefetched one chunk ahead (named double buffers).
// ---------------------------------------------------------------------------
__global__ __launch_bounds__(512) void scan_S(
    const u16* __restrict__ Mhi, const u16* __restrict__ Mlo,
    const float* __restrict__ Bg, float* __restrict__ Sg) {
  const int flat = blockIdx.x;
  const int hv = (flat & 7) + 8 * (flat >> 6);
  const int vs = (flat >> 3) & 7;
  const int tid = threadIdx.x;
  const int wave = tid >> 6, lane = tid & 63;
  const int fr = lane & 15, fq = lane >> 4;
  const int wr = wave * 16;       // this wave's 16 output rows
  const int m0 = vs * 16;         // col-slice base

  __shared__ u16 Sh[2][2048];     // [16 m][128 k] bf16-hi, XOR-swizzled
  __shared__ u16 Sl[2][2048];

  for (int i = tid; i < 2048; i += 512) { Sh[0][i] = 0; Sl[0][i] = 0; }
  {
    float* s0 = Sg + (size_t)hv * 16384 + m0;
#pragma unroll
    for (int it = 0; it < 4; ++it) {
      int idx = it * 512 + tid;          // 2048 = 128 d x 16 m
      s0[(size_t)(idx >> 4) * 128 + (idx & 15)] = 0.f;
    }
  }
  __syncthreads();

  bf16x8 MhA[4], MlA[4], MhB[4], MlB[4];
  float bvA[4], bvB[4];
  {
    const u16* Mh0 = Mhi + (size_t)hv * 16384;
    const u16* Ml0 = Mlo + (size_t)hv * 16384;
#pragma unroll
    for (int kt = 0; kt < 4; ++kt) {
      size_t off = (size_t)(wr + fr) * 128 + kt * 32 + fq * 8;
      MhA[kt] = *(const bf16x8*)&Mh0[off];
      MlA[kt] = *(const bf16x8*)&Ml0[off];
    }
    const float* Bc = Bg + (size_t)hv * 16384 + m0;
#pragma unroll
    for (int j = 0; j < 4; ++j)
      bvA[j] = Bc[(size_t)(wr + fq * 4 + j) * 128 + fr];
  }
  int p = 0;

  auto step = [&](int c, bf16x8 (&MhC)[4], bf16x8 (&MlC)[4], float (&bvC)[4],
                  bf16x8 (&MhN)[4], bf16x8 (&MlN)[4], float (&bvN)[4]) {
    // prefetch next chunk's M frags + B values (consumed next step)
    if (c + 1 < NC_ - 1) {
      const u16* MhP = Mhi + (size_t)((c + 1) * 16 + hv) * 16384;
      const u16* MlP = Mlo + (size_t)((c + 1) * 16 + hv) * 16384;
#pragma unroll
      for (int kt = 0; kt < 4; ++kt) {
        size_t off = (size_t)(wr + fr) * 128 + kt * 32 + fq * 8;
        MhN[kt] = *(const bf16x8*)&MhP[off];
        MlN[kt] = *(const bf16x8*)&MlP[off];
      }
      const float* BcN = Bg + (size_t)((c + 1) * 16 + hv) * 16384 + m0;
#pragma unroll
      for (int j = 0; j < 4; ++j)
        bvN[j] = BcN[(size_t)(wr + fq * 4 + j) * 128 + fr];
    }

    // acc = M_c @ S_c  (bf16 hi/lo x3), 16-col slice: single B fragment
    f32x4v acc = {};
#pragma unroll
    for (int kt = 0; kt < 4; ++kt) {
      const int m = fr;
      const int byte = m * 256 + ((kt * 64 + fq * 16) ^ ((m & 7) << 4));
      bf16x8 BhF = *(const bf16x8*)((const char*)&Sh[p][0] + byte);
      bf16x8 BlF = *(const bf16x8*)((const char*)&Sl[p][0] + byte);
      acc = __builtin_amdgcn_mfma_f32_16x16x32_bf16(MlC[kt], BhF, acc, 0, 0, 0);
      acc = __builtin_amdgcn_mfma_f32_16x16x32_bf16(MhC[kt], BlF, acc, 0, 0, 0);
      acc = __builtin_amdgcn_mfma_f32_16x16x32_bf16(MhC[kt], BhF, acc, 0, 0, 0);
    }

    // S_{c+1} = acc + B (B from registers, prefetched last step)
    float* Sn = Sg + (size_t)((c + 1) * 16 + hv) * 16384 + m0;
    const int k0 = wr + fq * 4;
    const int m = fr;
    us4 h4, l4;
#pragma unroll
    for (int j = 0; j < 4; ++j) {
      float v = acc[j] + bvC[j];
      Sn[(size_t)(k0 + j) * 128 + m] = v;
      u16 h = f2bf(v);
      h4[j] = h;
      l4[j] = f2bf(v - bf2f(h));
    }
    const int wbyte = m * 256 + ((k0 * 2) ^ ((m & 7) << 4));
    *(us4*)((char*)&Sh[p ^ 1][0] + wbyte) = h4;
    *(us4*)((char*)&Sl[p ^ 1][0] + wbyte) = l4;
    __syncthreads();
    p ^= 1;
  };

  for (int cc = 0; cc < NC_ - 1; cc += 2) {
    step(cc, MhA, MlA, bvA, MhB, MlB, bvB);
    if (cc + 1 < NC_ - 1) step(cc + 1, MhB, MlB, bvB, MhA, MlA, bvA);
  }
}

// ---------------------------------------------------------------------------
// chunk_out + fused gated rmsnorm (parallel, 256 blocks):
//   o_i[m] = sum_j Mq[j][i] U[j][m] + sum_d Gt[d][i] S[d][m]
//   h = o*silu(z); h *= rsqrt(mean_m(h^2)+eps)*norm_w; -> bf16 (permuted)
// ---------------------------------------------------------------------------
__global__ __launch_bounds__(256) void chunk_out(
    const float* __restrict__ Mqg, const float* __restrict__ Ug,
    const float* __restrict__ Gtg, const float* __restrict__ Sg,
    const float* __restrict__ zbuf, const float* __restrict__ norm_w,
    u16* __restrict__ h) {
  const int c = blockIdx.x, hv = blockIdx.y;
  const int cid = c * 16 + hv;
  const int tid = threadIdx.x;
  __shared__ float Mql[64 * 64];
  __shared__ float Ul[64 * 128];
  __shared__ float Gtl[128 * 64];
  __shared__ float Sl[128 * 128];
  __shared__ float red[64][16];
#pragma unroll
  for (int it = 0; it < 4; ++it) {
    int f = it * 1024 + tid * 4;
    *(float4*)&Mql[f] = *(const float4*)&Mqg[(size_t)cid * 4096 + f];
  }
#pragma unroll
  for (int it = 0; it < 8; ++it) {
    int f = it * 1024 + tid * 4;
    *(float4*)&Ul[f]  = *(const float4*)&Ug[(size_t)cid * 8192 + f];
    *(float4*)&Gtl[f] = *(const float4*)&Gtg[(size_t)cid * 8192 + f];
  }
#pragma unroll
  for (int it = 0; it < 16; ++it) {
    int f = it * 1024 + tid * 4;
    *(float4*)&Sl[f] = *(const float4*)&Sg[(size_t)cid * 16384 + f];
  }
  __syncthreads();

  const int i0 = (tid & 15) * 4, m0 = (tid >> 4) * 8;
  float oa[4][8] = {};
  for (int j = 0; j < 64; ++j) {
    float4 mq = *(const float4*)&Mql[j * 64 + i0];
    float4 u0 = *(const float4*)&Ul[j * 128 + m0];
    float4 u1 = *(const float4*)&Ul[j * 128 + m0 + 4];
    float mv[4] = {mq.x, mq.y, mq.z, mq.w};
    float uv[8] = {u0.x, u0.y, u0.z, u0.w, u1.x, u1.y, u1.z, u1.w};
#pragma unroll
    for (int a = 0; a < 4; ++a)
#pragma unroll
      for (int b = 0; b < 8; ++b) oa[a][b] = fmaf(mv[a], uv[b], oa[a][b]);
  }
  for (int d = 0; d < 128; ++d) {
    float4 gt = *(const float4*)&Gtl[d * 64 + i0];
    float4 s0 = *(const float4*)&Sl[d * 128 + m0];
    float4 s1 = *(const float4*)&Sl[d * 128 + m0 + 4];
    float gv[4] = {gt.x, gt.y, gt.z, gt.w};
    float sv[8] = {s0.x, s0.y, s0.z, s0.w, s1.x, s1.y, s1.z, s1.w};
#pragma unroll
    for (int a = 0; a < 4; ++a)
#pragma unroll
      for (int b = 0; b < 8; ++b) oa[a][b] = fmaf(gv[a], sv[b], oa[a][b]);
  }

  // ---- fused gated rmsnorm over the m-dimension (per row) ----
  float hva[4][8];
#pragma unroll
  for (int a = 0; a < 4; ++a) {
    const int t = c * 64 + i0 + a;
    float4 z0 = *(const float4*)&zbuf[(size_t)t * VD_ + hv * 128 + m0];
    float4 z1 = *(const float4*)&zbuf[(size_t)t * VD_ + hv * 128 + m0 + 4];
    float zv[8] = {z0.x, z0.y, z0.z, z0.w, z1.x, z1.y, z1.z, z1.w};
    float ss = 0.f;
#pragma unroll
    for (int b = 0; b < 8; ++b) {
      float hc = oa[a][b] * (zv[b] / (1.f + expf(-zv[b])));
      hva[a][b] = hc;
      ss = fmaf(hc, hc, ss);
    }
    red[i0 + a][tid >> 4] = ss;
  }
  __syncthreads();
  float4 nw0 = *(const float4*)&norm_w[m0];
  float4 nw1 = *(const float4*)&norm_w[m0 + 4];
  float nw[8] = {nw0.x, nw0.y, nw0.z, nw0.w, nw1.x, nw1.y, nw1.z, nw1.w};
#pragma unroll
  for (int a = 0; a < 4; ++a) {
    const int t = c * 64 + i0 + a;
    float tot = 0.f;
#pragma unroll
    for (int w = 0; w < 16; ++w) tot += red[i0 + a][w];
    float r = rsqrtf(tot * (1.f / 128.f) + 1e-6f);
    us8 hv8;
#pragma unroll
    for (int b = 0; b < 8; ++b) hv8[b] = f2bf(hva[a][b] * r * nw[b]);
    *(us8*)&h[(size_t)t * VD_ + permk3(t, hv * 128 + m0)] = hv8;
  }
}

// ---------------------------------------------------------------------------
extern "C" void kernel_launch(void* const* d_in, const int* in_sizes, int n_in,
                              void* d_out, int out_size, void* d_ws, size_t ws_size,
                              hipStream_t stream) {
  const float* x       = (const float*)d_in[0];
  const float* w_qkvz  = (const float*)d_in[1];
  const float* w_ba    = (const float*)d_in[2];
  const float* conv_w  = (const float*)d_in[3];
  const float* conv_b  = (const float*)d_in[4];
  const float* a_log   = (const float*)d_in[5];
  const float* dt_bias = (const float*)d_in[6];
  const float* norm_w  = (const float*)d_in[7];
  const float* w_o     = (const float*)d_in[8];
  float* out = (float*)d_out;

  float* ws = (float*)d_ws;
  float* qkvraw = ws;                  // 4,194,304  (-> Bg)
  float* zbuf   = ws + 4194304;        // 2,097,152
  float* qkvc   = ws + 6291456;        // 4,194,304  (-> Mhi|Mlo, -> wot)
  float* khat   = ws + 10485760;       // 1,048,576  (-> hb)
  float* gbuf   = ws + 11534336;       // 16,384
  float* bbuf   = ws + 11550720;       // 16,384
  float* cgbuf  = ws + 11567104;       // 16,384
  float* obuf   = ws + 11583488;       // 2,097,152  (xb early)
  float* Wtg    = ws + 13680640;       // 2,097,152 ┐ -> Sg (4,194,304)
  float* pQg    = ws + 15777792;       // 2,097,152 ┘
  float* Ug     = ws + 17874944;       // 2,097,152
  float* Mqg    = ws + 19972096;       // 1,048,576
  float* Gtg    = ws + 21020672;       // 2,097,152

  u16* xb   = (u16*)obuf;      // x bf16 (dead after gemm1)
  u16* wqt  = (u16*)Wtg;       // w_qkvz^T bf16 (dead after gemm1)
  u16* Mhi  = (u16*)qkvc;
  u16* Mlo  = (u16*)(qkvc + 2097152);
  float* Bg = qkvraw;
  float* Sg = Wtg;
  u16* wot  = (u16*)qkvc;      // after scan_S (Mhi dead)
  u16* hb   = (u16*)khat;      // after make_MBG (khat dead)

  // 0) fused beta/g + x->bf16 cast (permuted staging layout)
  ba_gbeta_cast<<<T_, 256, 0, stream>>>(x, w_ba, a_log, dt_bias,
                                        gbuf, bbuf, xb);
  transpose_bf16<<<dim3(32, 96), 256, 0, stream>>>(w_qkvz, wqt, H_, QN_);
  // 1) qkv|z = x @ w_qkvz   (8-wave: 24 waves/CU for latency hiding)
  gemm_bf16_w8<<<768, 512, 0, stream>>>(xb, wqt, qkvraw, CD_, zbuf, VD_,
                                        CD_, T_, QN_, H_);
  // 2) fused conv + silu + k-l2norm
  conv_silu_k<<<T_, 512, 0, stream>>>(qkvraw, conv_w, conv_b, qkvc, khat);
  // 3) chunk-local precompute (parallel, 512 thr)
  chunk_prep<<<dim3(NC_, HV_), 512, 0, stream>>>(
      qkvc, khat, gbuf, bbuf, cgbuf, Wtg, Ug, Mqg, pQg);
  // 4) per-chunk transition/output operators (parallel, 512 thr)
  make_MBG<<<dim3(NC_, HV_), 512, 0, stream>>>(
      Wtg, pQg, Ug, Mqg, khat, cgbuf, Mhi, Mlo, Bg, Gtg);
  // 5) sequential state scan (128 blocks, M+B reg-prefetched)
  scan_S<<<128, 512, 0, stream>>>(Mhi, Mlo, Bg, Sg);
  // 6) w_o^T cast (Mhi region now dead)
  transpose_bf16<<<dim3(32, 32), 256, 0, stream>>>(w_o, wot, VD_, H_);
  // 7) per-chunk outputs + fused gated rmsnorm -> bf16 h (permuted)
  chunk_out<<<dim3(NC_, HV_), 256, 0, stream>>>(
      Mqg, Ug, Gtg, Sg, zbuf, norm_w, hb);
  // 8) out = h @ w_o  (BM=64: 512 blocks = 2/CU for latency hiding)
  gemm_bf16<64><<<512, 256, 0, stream>>>(hb, wot, out, VD_, out, VD_,
                                         VD_, T_, VD_, H_);
}

// Round 20
// 231.942 us; speedup vs baseline: 1.1643x; 1.0040x over previous
//
#include <hip/hip_runtime.h>
#include <math.h>

typedef unsigned short u16;
using us4  = __attribute__((ext_vector_type(4))) unsigned short;
using us8  = __attribute__((ext_vector_type(8))) unsigned short;
using bf16x8 = __attribute__((ext_vector_type(8))) __bf16;
using f32x4v = __attribute__((ext_vector_type(4))) float;

// Problem constants
#define T_    1024
#define H_    2048
#define HK_   8
#define HV_   16
#define KD_   1024
#define VD_   2048
#define CD_   4096
#define QN_   6144   // 2*KD + 2*VD
#define NC_   16     // number of chunks
#define C_    64     // chunk length

__device__ __forceinline__ u16 f2bf(float f) {
  unsigned u = __float_as_uint(f);
  u += 0x7fffu + ((u >> 16) & 1u);   // RNE
  return (u16)(u >> 16);
}
__device__ __forceinline__ float bf2f(u16 h) {
  return __uint_as_float(((unsigned)h) << 16);
}
// staging layout for gemm: within each 64-elem k-group, 8-elem chunk c of
// row r is stored at chunk position c ^ (r&7).
__device__ __forceinline__ int permk3(int r, int k) {
  return (k & ~63) | ((((k >> 3) & 7) ^ (r & 7)) << 3) | (k & 7);
}

// ---------------------------------------------------------------------------
// f32 [R][C] -> bf16 [C][R] transpose + cast + chunk permutation
// ---------------------------------------------------------------------------
__global__ __launch_bounds__(256) void transpose_bf16(
    const float* __restrict__ in, u16* __restrict__ out, int R, int C) {
  __shared__ float tile[64][65];
  const int r0 = blockIdx.x * 64, c0 = blockIdx.y * 64;
  const int t = threadIdx.x;
  const int tr = t >> 4, tc4 = (t & 15) * 4;
#pragma unroll
  for (int i = 0; i < 4; ++i) {
    float4 v = *(const float4*)&in[(size_t)(r0 + tr + i * 16) * C + c0 + tc4];
    tile[tr + i * 16][tc4 + 0] = v.x;
    tile[tr + i * 16][tc4 + 1] = v.y;
    tile[tr + i * 16][tc4 + 2] = v.z;
    tile[tr + i * 16][tc4 + 3] = v.w;
  }
  __syncthreads();
#pragma unroll
  for (int i = 0; i < 4; ++i) {
    int oc = tr + i * 16;
    int row = c0 + oc;
    int k = r0 + tc4;
    us4 w = {f2bf(tile[tc4 + 0][oc]), f2bf(tile[tc4 + 1][oc]),
             f2bf(tile[tc4 + 2][oc]), f2bf(tile[tc4 + 3][oc])};
    *(us4*)&out[(size_t)row * R + permk3(row, k)] = w;
  }
}

// ---------------------------------------------------------------------------
// bf16 MFMA GEMM helpers
// ---------------------------------------------------------------------------
__device__ __forceinline__ void gload_lds16(const void* g, void* l) {
  __builtin_amdgcn_global_load_lds(
      (const __attribute__((address_space(1))) void*)g,
      (__attribute__((address_space(3))) void*)l, 16, 0, 0);
}

// ---------------------------------------------------------------------------
// gemm1: 128x64 tile, BK=64, 512 threads (8 waves as 4x2, 32x32 out each).
// 48KB 2-buffer LDS -> 3 blocks/CU = 24 waves/CU. XCD-grouped mapping,
// 3-bit permuted staging, counted vmcnt.
// ---------------------------------------------------------------------------
__global__ __launch_bounds__(512) void gemm_bf16_w8(
    const u16* __restrict__ A, const u16* __restrict__ Bt,
    float* __restrict__ Cq, int ldq, float* __restrict__ Cz, int ldz,
    int zsplit, int M, int N, int K) {
  __shared__ __align__(16) u16 As[2][8192];   // [128][64]
  __shared__ __align__(16) u16 Bs[2][4096];   // [64][64]
  const int tid  = threadIdx.x;
  const int wave = tid >> 6, lane = tid & 63;
  const int gy = N >> 6;
  const int ncolpx = gy >> 3;
  const int bid = blockIdx.x;
  const int xcd = bid & 7, idx = bid >> 3;
  const int row0 = (idx / ncolpx) * 128;
  const int col0 = (xcd * ncolpx + idx % ncolpx) * 64;
  const int wr = wave >> 1, wc = wave & 1;   // 4x2 wave grid
  const int fr = lane & 15, fq = lane >> 4;

  const int sr8 = lane >> 3;
  const int sc8 = (lane & 7) * 8;
  const u16* gA = A  + (size_t)(row0 + wave * 16 + sr8) * K + sc8;
  const u16* gB = Bt + (size_t)(col0 + wave * 8 + sr8) * K + sc8;

  f32x4v acc[2][2] = {};
  const int nt = K >> 6;

  auto stage = [&](int p, int k0) {
#pragma unroll
    for (int j = 0; j < 2; ++j)
      gload_lds16(gA + (size_t)(j * 8) * K + k0,
                  &As[p][(wave * 16 + j * 8) * 64]);
    gload_lds16(gB + k0, &Bs[p][(wave * 8) * 64]);
  };

  stage(0, 0);

  int p = 0;
  for (int it = 0; it < nt; ++it) {
    if (it + 1 < nt) stage(p ^ 1, (it + 1) * 64);
    if (it + 1 < nt) asm volatile("s_waitcnt vmcnt(3)" ::: "memory");
    else             asm volatile("s_waitcnt vmcnt(0)" ::: "memory");
    __builtin_amdgcn_s_barrier();

#pragma unroll
    for (int kt = 0; kt < 2; ++kt) {
      bf16x8 af[2], bff[2];
#pragma unroll
      for (int mi = 0; mi < 2; ++mi) {
        const int r = wr * 32 + mi * 16 + fr;
        af[mi] = *(const bf16x8*)
            &As[p][r * 64 + kt * 32 + (((kt * 4 + fq) ^ (r & 7)) & 3) * 8
                   + ((((kt * 4 + fq) ^ (r & 7)) >> 2) - kt) * 32];
      }
#pragma unroll
      for (int ni = 0; ni < 2; ++ni) {
        const int r = wc * 32 + ni * 16 + fr;
        bff[ni] = *(const bf16x8*)
            &Bs[p][r * 64 + kt * 32 + (((kt * 4 + fq) ^ (r & 7)) & 3) * 8
                   + ((((kt * 4 + fq) ^ (r & 7)) >> 2) - kt) * 32];
      }
#pragma unroll
      for (int mi = 0; mi < 2; ++mi)
#pragma unroll
        for (int ni = 0; ni < 2; ++ni)
          acc[mi][ni] = __builtin_amdgcn_mfma_f32_16x16x32_bf16(
              af[mi], bff[ni], acc[mi][ni], 0, 0, 0);
    }
    if (it + 1 < nt) {
      asm volatile("s_waitcnt lgkmcnt(0)" ::: "memory");
      __builtin_amdgcn_s_barrier();
    }
    p ^= 1;
  }

  float* Cp; int ldc, cb;
  if (col0 < zsplit) { Cp = Cq; ldc = ldq; cb = col0; }
  else               { Cp = Cz; ldc = ldz; cb = col0 - zsplit; }
#pragma unroll
  for (int mi = 0; mi < 2; ++mi)
#pragma unroll
    for (int ni = 0; ni < 2; ++ni) {
      const int r  = row0 + wr * 32 + mi * 16 + fq * 4;
      const int cc = cb + wc * 32 + ni * 16 + fr;
#pragma unroll
      for (int j = 0; j < 4; ++j)
        Cp[(size_t)(r + j) * ldc + cc] = acc[mi][ni][j];
    }
}

// ---------------------------------------------------------------------------
// gemm2: 64x64 tile, BK=64, 512 threads (8 waves as 2x4, 32x16 out each).
// 32KB 2-buffer LDS -> 2 blocks/CU = 16 waves/CU (512 blocks).
// ---------------------------------------------------------------------------
__global__ __launch_bounds__(512) void gemm_bf16_w8_64(
    const u16* __restrict__ A, const u16* __restrict__ Bt,
    float* __restrict__ C, int ldc, int M, int N, int K) {
  __shared__ __align__(16) u16 As[2][4096];   // [64][64]
  __shared__ __align__(16) u16 Bs[2][4096];   // [64][64]
  const int tid  = threadIdx.x;
  const int wave = tid >> 6, lane = tid & 63;
  const int gy = N >> 6;
  const int ncolpx = gy >> 3;
  const int bid = blockIdx.x;
  const int xcd = bid & 7, idx = bid >> 3;
  const int row0 = (idx / ncolpx) * 64;
  const int col0 = (xcd * ncolpx + idx % ncolpx) * 64;
  const int wr = wave >> 2, wc = wave & 3;   // 2x4 wave grid
  const int fr = lane & 15, fq = lane >> 4;

  const int sr8 = lane >> 3;
  const int sc8 = (lane & 7) * 8;
  const u16* gA = A  + (size_t)(row0 + wave * 8 + sr8) * K + sc8;
  const u16* gB = Bt + (size_t)(col0 + wave * 8 + sr8) * K + sc8;

  f32x4v acc[2] = {};
  const int nt = K >> 6;

  // 2 global_load_lds per wave per stage
  auto stage = [&](int p, int k0) {
    gload_lds16(gA + k0, &As[p][(wave * 8) * 64]);
    gload_lds16(gB + k0, &Bs[p][(wave * 8) * 64]);
  };

  stage(0, 0);

  int p = 0;
  for (int it = 0; it < nt; ++it) {
    if (it + 1 < nt) stage(p ^ 1, (it + 1) * 64);
    if (it + 1 < nt) asm volatile("s_waitcnt vmcnt(2)" ::: "memory");
    else             asm volatile("s_waitcnt vmcnt(0)" ::: "memory");
    __builtin_amdgcn_s_barrier();

#pragma unroll
    for (int kt = 0; kt < 2; ++kt) {
      bf16x8 af[2], bff;
#pragma unroll
      for (int mi = 0; mi < 2; ++mi) {
        const int r = wr * 32 + mi * 16 + fr;
        af[mi] = *(const bf16x8*)
            &As[p][r * 64 + kt * 32 + (((kt * 4 + fq) ^ (r & 7)) & 3) * 8
                   + ((((kt * 4 + fq) ^ (r & 7)) >> 2) - kt) * 32];
      }
      {
        const int r = wc * 16 + fr;
        bff = *(const bf16x8*)
            &Bs[p][r * 64 + kt * 32 + (((kt * 4 + fq) ^ (r & 7)) & 3) * 8
                   + ((((kt * 4 + fq) ^ (r & 7)) >> 2) - kt) * 32];
      }
#pragma unroll
      for (int mi = 0; mi < 2; ++mi)
        acc[mi] = __builtin_amdgcn_mfma_f32_16x16x32_bf16(
            af[mi], bff, acc[mi], 0, 0, 0);
    }
    if (it + 1 < nt) {
      asm volatile("s_waitcnt lgkmcnt(0)" ::: "memory");
      __builtin_amdgcn_s_barrier();
    }
    p ^= 1;
  }

#pragma unroll
  for (int mi = 0; mi < 2; ++mi) {
    const int r  = row0 + wr * 32 + mi * 16 + fq * 4;
    const int cc = col0 + wc * 16 + fr;
#pragma unroll
    for (int j = 0; j < 4; ++j)
      C[(size_t)(r + j) * ldc + cc] = acc[mi][j];
  }
}

// ---------------------------------------------------------------------------
// fused: xb = bf16(x) (permuted staging layout)  +
//        ba = x @ w_ba -> beta = sigmoid(b), g = -exp(a_log)*softplus(a+dt)
// ---------------------------------------------------------------------------
__global__ __launch_bounds__(256) void ba_gbeta_cast(
    const float* __restrict__ x, const float* __restrict__ w_ba,
    const float* __restrict__ a_log, const float* __restrict__ dt_bias,
    float* __restrict__ g, float* __restrict__ beta, u16* __restrict__ xb) {
  const int t = blockIdx.x;
  const int tid = threadIdx.x;
  __shared__ float xs[2048];
  __shared__ float red[8][32];
  {
    float4 v = *(const float4*)&x[(size_t)t * H_ + tid * 4];
    *(float4*)&xs[tid * 4] = v;
    float4 w = *(const float4*)&x[(size_t)t * H_ + 1024 + tid * 4];
    *(float4*)&xs[1024 + tid * 4] = w;
  }
  __syncthreads();
  {
    const float* src = &xs[tid * 8];
    us8 r = {f2bf(src[0]), f2bf(src[1]), f2bf(src[2]), f2bf(src[3]),
             f2bf(src[4]), f2bf(src[5]), f2bf(src[6]), f2bf(src[7])};
    const int ip = (tid & ~7) | ((tid & 7) ^ (t & 7));
    *(us8*)&xb[(size_t)t * H_ + ip * 8] = r;
  }
  const int c = tid & 31;
  const int chunk = tid >> 5;
  float p = 0.f;
  const int kb = chunk * 256;
#pragma unroll 4
  for (int k = kb; k < kb + 256; ++k) p = fmaf(xs[k], w_ba[k * 32 + c], p);
  red[chunk][c] = p;
  __syncthreads();
  if (tid < 32) {
    float s = 0.f;
#pragma unroll
    for (int i = 0; i < 8; ++i) s += red[i][c];
    if (c < 16) {
      beta[t * 16 + c] = 1.f / (1.f + expf(-s));
    } else {
      int h = c - 16;
      float xx = s + dt_bias[h];
      float sp = xx > 20.f ? xx : log1pf(expf(xx));
      g[t * 16 + h] = -expf(a_log[h]) * sp;
    }
  }
}

// ---------------------------------------------------------------------------
// fused causal depthwise conv1d (K=4) + SiLU + k-l2norm.
// ---------------------------------------------------------------------------
__global__ __launch_bounds__(512) void conv_silu_k(
    const float* __restrict__ qkvraw, const float* __restrict__ conv_w,
    const float* __restrict__ conv_b, float* __restrict__ qkvc,
    float* __restrict__ khat) {
  const int t = blockIdx.x;
  const int tid = threadIdx.x;
  const int c0 = tid * 8;
  float acc[8];
  float4 cb0 = *(const float4*)&conv_b[c0];
  float4 cb1 = *(const float4*)&conv_b[c0 + 4];
  acc[0] = cb0.x; acc[1] = cb0.y; acc[2] = cb0.z; acc[3] = cb0.w;
  acc[4] = cb1.x; acc[5] = cb1.y; acc[6] = cb1.z; acc[7] = cb1.w;
  float wv[8][4];
#pragma unroll
  for (int i = 0; i < 8; i += 2) {
    float4 w0 = *(const float4*)&conv_w[(c0 + i) * 4];
    float4 w1 = *(const float4*)&conv_w[(c0 + i + 1) * 4];
    wv[i][0] = w0.x; wv[i][1] = w0.y; wv[i][2] = w0.z; wv[i][3] = w0.w;
    wv[i+1][0] = w1.x; wv[i+1][1] = w1.y; wv[i+1][2] = w1.z; wv[i+1][3] = w1.w;
  }
#pragma unroll
  for (int j = 0; j < 4; ++j) {
    int tt = t - 3 + j;
    if (tt >= 0) {
      float4 a = *(const float4*)&qkvraw[(size_t)tt * CD_ + c0];
      float4 b = *(const float4*)&qkvraw[(size_t)tt * CD_ + c0 + 4];
      float xv[8] = {a.x, a.y, a.z, a.w, b.x, b.y, b.z, b.w};
#pragma unroll
      for (int i = 0; i < 8; ++i) acc[i] = fmaf(xv[i], wv[i][j], acc[i]);
    }
  }
  float y[8];
#pragma unroll
  for (int i = 0; i < 8; ++i) y[i] = acc[i] / (1.f + expf(-acc[i]));

  if (tid < 128 || tid >= 256) {
    float4 o0 = {y[0], y[1], y[2], y[3]};
    float4 o1 = {y[4], y[5], y[6], y[7]};
    *(float4*)&qkvc[(size_t)t * CD_ + c0]     = o0;
    *(float4*)&qkvc[(size_t)t * CD_ + c0 + 4] = o1;
  } else {
    float ss = 0.f;
#pragma unroll
    for (int i = 0; i < 8; ++i) ss = fmaf(y[i], y[i], ss);
#pragma unroll
    for (int off = 1; off < 16; off <<= 1) ss += __shfl_xor(ss, off);
    float rs = rsqrtf(ss + 1e-6f);
    const int head = (c0 - 1024) >> 7;
    const int d0 = (c0 - 1024) & 127;
    float4 o0 = {y[0] * rs, y[1] * rs, y[2] * rs, y[3] * rs};
    float4 o1 = {y[4] * rs, y[5] * rs, y[6] * rs, y[7] * rs};
    float* kout = &khat[((size_t)t * HK_ + head) * 128 + d0];
    *(float4*)&kout[0] = o0;
    *(float4*)&kout[4] = o1;
  }
}

// ---------------------------------------------------------------------------
// Chunked gated delta rule, phase A (parallel over 16 chunks x 16 heads).
// 512 threads (8 waves). Dot phase 4x2 tiles/thread; during the serial
// forward substitution (waves 0-3), waves 4-7 write Mqg and pQg.
// ---------------------------------------------------------------------------
#define SWZ(r) (((r) >> 2) & 7)

__device__ __forceinline__ float4 ldsw4(const float* base, int r, int dblk) {
  return *(const float4*)&base[r * 128 + ((dblk ^ SWZ(r)) << 2)];
}
__device__ __forceinline__ float ldsw1(const float* base, int r, int d) {
  return base[r * 128 + ((((d) >> 2) ^ SWZ(r)) << 2) + ((d) & 3)];
}

__global__ __launch_bounds__(512) void chunk_prep(
    const float* __restrict__ qkvc, const float* __restrict__ khat,
    const float* __restrict__ g, const float* __restrict__ beta,
    float* __restrict__ cgbuf, float* __restrict__ Wtg, float* __restrict__ Ug,
    float* __restrict__ Mqg, float* __restrict__ pQg) {
  const int c = blockIdx.x, hv = blockIdx.y, hk = hv >> 1;
  const int cid = c * 16 + hv;
  const int tid = threadIdx.x;
  __shared__ float Kl[8192], Ql[8192];   // swizzled [64][128]
  __shared__ float AM[8320];             // At[64][65] | Mq[64][65]; later Utr
  __shared__ float cgl[64], bl[64], bp[64], rsl[64];
  float* At = AM;
  float* Mq = AM + 4160;

#pragma unroll
  for (int it = 0; it < 4; ++it) {
    int flat = it * 2048 + tid * 4;
    int row = flat >> 7, d = flat & 127;
    int pb = ((d >> 2) ^ SWZ(row)) << 2;
    int gt = c * 64 + row;
    float4 kv = *(const float4*)&khat[((size_t)gt * HK_ + hk) * 128 + d];
    float4 qv = *(const float4*)&qkvc[(size_t)gt * CD_ + hk * 128 + d];
    *(float4*)&Kl[row * 128 + pb] = kv;
    *(float4*)&Ql[row * 128 + pb] = qv;
  }
  if (tid < 64) {
    float s = g[(size_t)(c * 64 + tid) * HV_ + hv];
#pragma unroll
    for (int off = 1; off < 64; off <<= 1) {
      float t = __shfl_up(s, off);
      if (tid >= off) s += t;
    }
    cgl[tid] = s;
    cgbuf[cid * 64 + tid] = s;
    bl[tid] = beta[(size_t)(c * 64 + tid) * HV_ + hv];
  }
  __syncthreads();
  if (tid < 64) {
    float sq = 0.f;
#pragma unroll
    for (int dblk = 0; dblk < 32; ++dblk) {
      float4 q4 = ldsw4(Ql, tid, dblk);
      sq = fmaf(q4.x, q4.x, sq); sq = fmaf(q4.y, q4.y, sq);
      sq = fmaf(q4.z, q4.z, sq); sq = fmaf(q4.w, q4.w, sq);
    }
    rsl[tid] = rsqrtf(sq + 1e-6f) * 0.08838834764831845f;
    bp[tid] = bl[tid] * expf(cgl[tid]);
  }
  __syncthreads();

  // dot phase: 4x2 tile of (i,j) pairs per thread (512 threads)
  const int i0 = (tid >> 5) * 4, j0 = (tid & 31) * 2;
  float kk[4][2], qk[4][2];
#pragma unroll
  for (int a = 0; a < 4; ++a)
#pragma unroll
    for (int b = 0; b < 2; ++b) { kk[a][b] = 0.f; qk[a][b] = 0.f; }
  for (int dblk = 0; dblk < 32; ++dblk) {
    float4 ka[4], qa[4], kb[2];
#pragma unroll
    for (int a = 0; a < 4; ++a) {
      ka[a] = ldsw4(Kl, i0 + a, dblk);
      qa[a] = ldsw4(Ql, i0 + a, dblk);
    }
#pragma unroll
    for (int b = 0; b < 2; ++b) kb[b] = ldsw4(Kl, j0 + b, dblk);
#pragma unroll
    for (int a = 0; a < 4; ++a)
#pragma unroll
      for (int b = 0; b < 2; ++b) {
        kk[a][b] = fmaf(ka[a].x, kb[b].x, kk[a][b]);
        kk[a][b] = fmaf(ka[a].y, kb[b].y, kk[a][b]);
        kk[a][b] = fmaf(ka[a].z, kb[b].z, kk[a][b]);
        kk[a][b] = fmaf(ka[a].w, kb[b].w, kk[a][b]);
        qk[a][b] = fmaf(qa[a].x, kb[b].x, qk[a][b]);
        qk[a][b] = fmaf(qa[a].y, kb[b].y, qk[a][b]);
        qk[a][b] = fmaf(qa[a].z, kb[b].z, qk[a][b]);
        qk[a][b] = fmaf(qa[a].w, kb[b].w, qk[a][b]);
      }
  }
#pragma unroll
  for (int a = 0; a < 4; ++a)
#pragma unroll
    for (int b = 0; b < 2; ++b) {
      int i = i0 + a, j = j0 + b;
      float e = expf(cgl[i] - cgl[j]);
      At[j * 65 + i] = (j < i) ? (-bl[i] * e * kk[a][b]) : 0.f;
      Mq[j * 65 + i] = (j <= i) ? (rsl[i] * e * qk[a][b]) : 0.f;
    }
  __syncthreads();

  float X[64];
  if (tid < 256) {
    // ---- waves 0-3: X init + forward substitution ----
    if (tid < 128) {
#pragma unroll
      for (int j = 0; j < 64; ++j) X[j] = bp[j] * ldsw1(Kl, j, tid);
    } else {
      const int m = tid - 128;
#pragma unroll
      for (int j = 0; j < 64; ++j)
        X[j] = bl[j] * qkvc[(size_t)(c * 64 + j) * CD_ + 2 * KD_ + hv * 128 + m];
    }
#pragma unroll
    for (int j = 0; j < 63; ++j) {
      float xj = X[j];
#pragma unroll
      for (int i = j + 1; i < 64; ++i) X[i] = fmaf(At[j * 65 + i], xj, X[i]);
    }
    if (tid < 128) {
      size_t baseo = ((size_t)cid * 128 + tid) * 64;
#pragma unroll
      for (int j4 = 0; j4 < 16; ++j4) {
        float4 v = {X[j4 * 4], X[j4 * 4 + 1], X[j4 * 4 + 2], X[j4 * 4 + 3]};
        *(float4*)&Wtg[baseo + j4 * 4] = v;
      }
    }
  } else {
    // ---- waves 4-7: Mqg + pQg writes (independent of solve) ----
    const int t2 = tid - 256;
#pragma unroll
    for (int it = 0; it < 16; ++it) {
      int f = it * 256 + t2;
      int j = f >> 6, i = f & 63;
      Mqg[(size_t)cid * 4096 + f] = Mq[j * 65 + i];
    }
    const int i = t2 & 63;
    const float ei = expf(cgl[i]) * rsl[i];
#pragma unroll
    for (int it = 0; it < 32; ++it) {
      int d = it * 4 + (t2 >> 6);
      pQg[(size_t)cid * 8192 + d * 64 + i] = ei * ldsw1(Ql, i, d);
    }
  }
  __syncthreads();   // At/Mq dead; X (U cols) ready

  if (tid >= 128 && tid < 256) {
    const int m = tid - 128;
    float* Utr = AM;
#pragma unroll
    for (int j = 0; j < 64; ++j) Utr[j * 128 + m] = X[j];
  }
  __syncthreads();
  {
    const float* Utr = AM;
#pragma unroll
    for (int it = 0; it < 4; ++it) {
      int flat = it * 2048 + tid * 4;
      *(float4*)&Ug[(size_t)cid * 8192 + flat] = *(const float4*)&Utr[flat];
    }
  }
}

// ---------------------------------------------------------------------------
// make_MBG (parallel, 256 blocks, 1024 threads: 16 waves/CU latency hiding)
// ---------------------------------------------------------------------------
__global__ __launch_bounds__(1024) void make_MBG(
    const float* __restrict__ Wtg, const float* __restrict__ pQg,
    const float* __restrict__ Ug, const float* __restrict__ Mqg,
    const float* __restrict__ khat, const float* __restrict__ cgbuf,
    u16* __restrict__ Mhi, u16* __restrict__ Mlo,
    float* __restrict__ Bg, float* __restrict__ Gtg) {
  const int c = blockIdx.x, hv = blockIdx.y, hk = hv >> 1;
  const int cid = c * 16 + hv;
  const int tid = threadIdx.x;
  __shared__ float Wl[64 * 128];   // W[j][d]
  __shared__ float Kel[64 * 128];  // esc_j * khat_j[d]
  __shared__ float Ul[64 * 128];
  __shared__ float Mql[64 * 64];
  const float cg63 = cgbuf[cid * 64 + 63];
  const float pC = expf(cg63);
#pragma unroll
  for (int it = 0; it < 2; ++it) {
    int f = it * 4096 + tid * 4;       // f = d*64 + j
    int d = f >> 6, j = f & 63;
    float4 w = *(const float4*)&Wtg[(size_t)cid * 8192 + f];
    Wl[(j + 0) * 128 + d] = w.x;
    Wl[(j + 1) * 128 + d] = w.y;
    Wl[(j + 2) * 128 + d] = w.z;
    Wl[(j + 3) * 128 + d] = w.w;
  }
#pragma unroll
  for (int it = 0; it < 2; ++it) {
    int f = it * 4096 + tid * 4;       // f = j*128 + d
    int j = f >> 7, d = f & 127;
    float esc = expf(cg63 - cgbuf[cid * 64 + j]);
    float4 kv = *(const float4*)&khat[((size_t)(c * 64 + j) * HK_ + hk) * 128 + d];
    float4 uv = *(const float4*)&Ug[(size_t)cid * 8192 + f];
    kv.x *= esc; kv.y *= esc; kv.z *= esc; kv.w *= esc;
    *(float4*)&Kel[f] = kv;
    *(float4*)&Ul[f] = uv;
  }
  {
    int f = tid * 4;                   // 4096 = 1024*4
    *(float4*)&Mql[f] = *(const float4*)&Mqg[(size_t)cid * 4096 + f];
  }
  __syncthreads();

  // fused M+B: tile rows d0..d0+3, cols n0..n0+3 (1024 threads)
  const int d0 = (tid & 31) * 4, n0 = (tid >> 5) * 4;
  float ma[4][4] = {}, ba[4][4] = {};
  for (int j = 0; j < 64; ++j) {
    float4 k0 = *(const float4*)&Kel[j * 128 + d0];
    float4 w0 = *(const float4*)&Wl[j * 128 + n0];
    float4 u0 = *(const float4*)&Ul[j * 128 + n0];
    float ke[4] = {k0.x, k0.y, k0.z, k0.w};
    float wv[4] = {w0.x, w0.y, w0.z, w0.w};
    float uv[4] = {u0.x, u0.y, u0.z, u0.w};
#pragma unroll
    for (int a = 0; a < 4; ++a)
#pragma unroll
      for (int b = 0; b < 4; ++b) {
        ma[a][b] = fmaf(ke[a], wv[b], ma[a][b]);
        ba[a][b] = fmaf(ke[a], uv[b], ba[a][b]);
      }
  }
#pragma unroll
  for (int a = 0; a < 4; ++a) {
    const int d = d0 + a;
    us4 hi, lo;
#pragma unroll
    for (int b = 0; b < 4; ++b) {
      float m = ((d == n0 + b) ? pC : 0.f) - ma[a][b];
      u16 h = f2bf(m);
      hi[b] = h;
      lo[b] = f2bf(m - bf2f(h));
    }
    *(us4*)&Mhi[(size_t)cid * 16384 + d * 128 + n0] = hi;
    *(us4*)&Mlo[(size_t)cid * 16384 + d * 128 + n0] = lo;
    float4 b0 = {ba[a][0], ba[a][1], ba[a][2], ba[a][3]};
    *(float4*)&Bg[(size_t)cid * 16384 + d * 128 + n0] = b0;
  }

  // G phase: Gt[d][i] tile 2d x 4i (1024 threads)
  const int dg = (tid & 63) * 2, ig = (tid >> 6) * 4;
  float ga[2][4] = {};
  for (int j = 0; j < 64; ++j) {
    float2 w2 = *(const float2*)&Wl[j * 128 + dg];
    float4 m0 = *(const float4*)&Mql[j * 64 + ig];
    float wv[2] = {w2.x, w2.y};
    float mv[4] = {m0.x, m0.y, m0.z, m0.w};
#pragma unroll
    for (int a = 0; a < 2; ++a)
#pragma unroll
      for (int b = 0; b < 4; ++b) ga[a][b] = fmaf(wv[a], mv[b], ga[a][b]);
  }
#pragma unroll
  for (int a = 0; a < 2; ++a) {
    const int d = dg + a;
    float4 p0 = *(const float4*)&pQg[(size_t)cid * 8192 + d * 64 + ig];
    float4 g0 = {p0.x - ga[a][0], p0.y - ga[a][1], p0.z - ga[a][2], p0.w - ga[a][3]};
    *(float4*)&Gtg[(size_t)cid * 8192 + d * 64 + ig] = g0;
  }
}

// ---------------------------------------------------------------------------
// scan_S v4: 128 blocks = 16 heads x 8 col-slices of 16, XCD-grouped
// (flat%8 == hv%8 so all 8 slices of a head share one L2 copy of M).
// M AND B both register-prefetched one chunk ahead (named double buffers).
// ---------------------------------------------------------------------------
__global__ __launch_bounds__(512) void scan_S(
    const u16* __restrict__ Mhi, const u16* __restrict__ Mlo,
    const float* __restrict__ Bg, float* __restrict__ Sg) {
  const int flat = blockIdx.x;
  const int hv = (flat & 7) + 8 * (flat >> 6);
  const int vs = (flat >> 3) & 7;
  const int tid = threadIdx.x;
  const int wave = tid >> 6, lane = tid & 63;
  const int fr = lane & 15, fq = lane >> 4;
  const int wr = wave * 16;       // this wave's 16 output rows
  const int m0 = vs * 16;         // col-slice base

  __shared__ u16 Sh[2][2048];     // [16 m][128 k] bf16-hi, XOR-swizzled
  __shared__ u16 Sl[2][2048];

  for (int i = tid; i < 2048; i += 512) { Sh[0][i] = 0; Sl[0][i] = 0; }
  {
    float* s0 = Sg + (size_t)hv * 16384 + m0;
#pragma unroll
    for (int it = 0; it < 4; ++it) {
      int idx = it * 512 + tid;          // 2048 = 128 d x 16 m
      s0[(size_t)(idx >> 4) * 128 + (idx & 15)] = 0.f;
    }
  }
  __syncthreads();

  bf16x8 MhA[4], MlA[4], MhB[4], MlB[4];
  float bvA[4], bvB[4];
  {
    const u16* Mh0 = Mhi + (size_t)hv * 16384;
    const u16* Ml0 = Mlo + (size_t)hv * 16384;
#pragma unroll
    for (int kt = 0; kt < 4; ++kt) {
      size_t off = (size_t)(wr + fr) * 128 + kt * 32 + fq * 8;
      MhA[kt] = *(const bf16x8*)&Mh0[off];
      MlA[kt] = *(const bf16x8*)&Ml0[off];
    }
    const float* Bc = Bg + (size_t)hv * 16384 + m0;
#pragma unroll
    for (int j = 0; j < 4; ++j)
      bvA[j] = Bc[(size_t)(wr + fq * 4 + j) * 128 + fr];
  }
  int p = 0;

  auto step = [&](int c, bf16x8 (&MhC)[4], bf16x8 (&MlC)[4], float (&bvC)[4],
                  bf16x8 (&MhN)[4], bf16x8 (&MlN)[4], float (&bvN)[4]) {
    // prefetch next chunk's M frags + B values (consumed next step)
    if (c + 1 < NC_ - 1) {
      const u16* MhP = Mhi + (size_t)((c + 1) * 16 + hv) * 16384;
      const u16* MlP = Mlo + (size_t)((c + 1) * 16 + hv) * 16384;
#pragma unroll
      for (int kt = 0; kt < 4; ++kt) {
        size_t off = (size_t)(wr + fr) * 128 + kt * 32 + fq * 8;
        MhN[kt] = *(const bf16x8*)&MhP[off];
        MlN[kt] = *(const bf16x8*)&MlP[off];
      }
      const float* BcN = Bg + (size_t)((c + 1) * 16 + hv) * 16384 + m0;
#pragma unroll
      for (int j = 0; j < 4; ++j)
        bvN[j] = BcN[(size_t)(wr + fq * 4 + j) * 128 + fr];
    }

    // acc = M_c @ S_c  (bf16 hi/lo x3), 16-col slice: single B fragment
    f32x4v acc = {};
#pragma unroll
    for (int kt = 0; kt < 4; ++kt) {
      const int m = fr;
      const int byte = m * 256 + ((kt * 64 + fq * 16) ^ ((m & 7) << 4));
      bf16x8 BhF = *(const bf16x8*)((const char*)&Sh[p][0] + byte);
      bf16x8 BlF = *(const bf16x8*)((const char*)&Sl[p][0] + byte);
      acc = __builtin_amdgcn_mfma_f32_16x16x32_bf16(MlC[kt], BhF, acc, 0, 0, 0);
      acc = __builtin_amdgcn_mfma_f32_16x16x32_bf16(MhC[kt], BlF, acc, 0, 0, 0);
      acc = __builtin_amdgcn_mfma_f32_16x16x32_bf16(MhC[kt], BhF, acc, 0, 0, 0);
    }

    // S_{c+1} = acc + B (B from registers, prefetched last step)
    float* Sn = Sg + (size_t)((c + 1) * 16 + hv) * 16384 + m0;
    const int k0 = wr + fq * 4;
    const int m = fr;
    us4 h4, l4;
#pragma unroll
    for (int j = 0; j < 4; ++j) {
      float v = acc[j] + bvC[j];
      Sn[(size_t)(k0 + j) * 128 + m] = v;
      u16 h = f2bf(v);
      h4[j] = h;
      l4[j] = f2bf(v - bf2f(h));
    }
    const int wbyte = m * 256 + ((k0 * 2) ^ ((m & 7) << 4));
    *(us4*)((char*)&Sh[p ^ 1][0] + wbyte) = h4;
    *(us4*)((char*)&Sl[p ^ 1][0] + wbyte) = l4;
    __syncthreads();
    p ^= 1;
  };

  for (int cc = 0; cc < NC_ - 1; cc += 2) {
    step(cc, MhA, MlA, bvA, MhB, MlB, bvB);
    if (cc + 1 < NC_ - 1) step(cc + 1, MhB, MlB, bvB, MhA, MlA, bvA);
  }
}

// ---------------------------------------------------------------------------
// chunk_out + fused gated rmsnorm (parallel, 256 blocks):
//   o_i[m] = sum_j Mq[j][i] U[j][m] + sum_d Gt[d][i] S[d][m]
//   h = o*silu(z); h *= rsqrt(mean_m(h^2)+eps)*norm_w; -> bf16 (permuted)
// ---------------------------------------------------------------------------
__global__ __launch_bounds__(256) void chunk_out(
    const float* __restrict__ Mqg, const float* __restrict__ Ug,
    const float* __restrict__ Gtg, const float* __restrict__ Sg,
    const float* __restrict__ zbuf, const float* __restrict__ norm_w,
    u16* __restrict__ h) {
  const int c = blockIdx.x, hv = blockIdx.y;
  const int cid = c * 16 + hv;
  const int tid = threadIdx.x;
  __shared__ float Mql[64 * 64];
  __shared__ float Ul[64 * 128];
  __shared__ float Gtl[128 * 64];
  __shared__ float Sl[128 * 128];
  __shared__ float red[64][16];
#pragma unroll
  for (int it = 0; it < 4; ++it) {
    int f = it * 1024 + tid * 4;
    *(float4*)&Mql[f] = *(const float4*)&Mqg[(size_t)cid * 4096 + f];
  }
#pragma unroll
  for (int it = 0; it < 8; ++it) {
    int f = it * 1024 + tid * 4;
    *(float4*)&Ul[f]  = *(const float4*)&Ug[(size_t)cid * 8192 + f];
    *(float4*)&Gtl[f] = *(const float4*)&Gtg[(size_t)cid * 8192 + f];
  }
#pragma unroll
  for (int it = 0; it < 16; ++it) {
    int f = it * 1024 + tid * 4;
    *(float4*)&Sl[f] = *(const float4*)&Sg[(size_t)cid * 16384 + f];
  }
  __syncthreads();

  const int i0 = (tid & 15) * 4, m0 = (tid >> 4) * 8;
  float oa[4][8] = {};
  for (int j = 0; j < 64; ++j) {
    float4 mq = *(const float4*)&Mql[j * 64 + i0];
    float4 u0 = *(const float4*)&Ul[j * 128 + m0];
    float4 u1 = *(const float4*)&Ul[j * 128 + m0 + 4];
    float mv[4] = {mq.x, mq.y, mq.z, mq.w};
    float uv[8] = {u0.x, u0.y, u0.z, u0.w, u1.x, u1.y, u1.z, u1.w};
#pragma unroll
    for (int a = 0; a < 4; ++a)
#pragma unroll
      for (int b = 0; b < 8; ++b) oa[a][b] = fmaf(mv[a], uv[b], oa[a][b]);
  }
  for (int d = 0; d < 128; ++d) {
    float4 gt = *(const float4*)&Gtl[d * 64 + i0];
    float4 s0 = *(const float4*)&Sl[d * 128 + m0];
    float4 s1 = *(const float4*)&Sl[d * 128 + m0 + 4];
    float gv[4] = {gt.x, gt.y, gt.z, gt.w};
    float sv[8] = {s0.x, s0.y, s0.z, s0.w, s1.x, s1.y, s1.z, s1.w};
#pragma unroll
    for (int a = 0; a < 4; ++a)
#pragma unroll
      for (int b = 0; b < 8; ++b) oa[a][b] = fmaf(gv[a], sv[b], oa[a][b]);
  }

  // ---- fused gated rmsnorm over the m-dimension (per row) ----
  float hva[4][8];
#pragma unroll
  for (int a = 0; a < 4; ++a) {
    const int t = c * 64 + i0 + a;
    float4 z0 = *(const float4*)&zbuf[(size_t)t * VD_ + hv * 128 + m0];
    float4 z1 = *(const float4*)&zbuf[(size_t)t * VD_ + hv * 128 + m0 + 4];
    float zv[8] = {z0.x, z0.y, z0.z, z0.w, z1.x, z1.y, z1.z, z1.w};
    float ss = 0.f;
#pragma unroll
    for (int b = 0; b < 8; ++b) {
      float hc = oa[a][b] * (zv[b] / (1.f + expf(-zv[b])));
      hva[a][b] = hc;
      ss = fmaf(hc, hc, ss);
    }
    red[i0 + a][tid >> 4] = ss;
  }
  __syncthreads();
  float4 nw0 = *(const float4*)&norm_w[m0];
  float4 nw1 = *(const float4*)&norm_w[m0 + 4];
  float nw[8] = {nw0.x, nw0.y, nw0.z, nw0.w, nw1.x, nw1.y, nw1.z, nw1.w};
#pragma unroll
  for (int a = 0; a < 4; ++a) {
    const int t = c * 64 + i0 + a;
    float tot = 0.f;
#pragma unroll
    for (int w = 0; w < 16; ++w) tot += red[i0 + a][w];
    float r = rsqrtf(tot * (1.f / 128.f) + 1e-6f);
    us8 hv8;
#pragma unroll
    for (int b = 0; b < 8; ++b) hv8[b] = f2bf(hva[a][b] * r * nw[b]);
    *(us8*)&h[(size_t)t * VD_ + permk3(t, hv * 128 + m0)] = hv8;
  }
}

// ---------------------------------------------------------------------------
extern "C" void kernel_launch(void* const* d_in, const int* in_sizes, int n_in,
                              void* d_out, int out_size, void* d_ws, size_t ws_size,
                              hipStream_t stream) {
  const float* x       = (const float*)d_in[0];
  const float* w_qkvz  = (const float*)d_in[1];
  const float* w_ba    = (const float*)d_in[2];
  const float* conv_w  = (const float*)d_in[3];
  const float* conv_b  = (const float*)d_in[4];
  const float* a_log   = (const float*)d_in[5];
  const float* dt_bias = (const float*)d_in[6];
  const float* norm_w  = (const float*)d_in[7];
  const float* w_o     = (const float*)d_in[8];
  float* out = (float*)d_out;

  float* ws = (float*)d_ws;
  float* qkvraw = ws;                  // 4,194,304  (-> Bg)
  float* zbuf   = ws + 4194304;        // 2,097,152
  float* qkvc   = ws + 6291456;        // 4,194,304  (-> Mhi|Mlo, -> wot)
  float* khat   = ws + 10485760;       // 1,048,576  (-> hb)
  float* gbuf   = ws + 11534336;       // 16,384
  float* bbuf   = ws + 11550720;       // 16,384
  float* cgbuf  = ws + 11567104;       // 16,384
  float* obuf   = ws + 11583488;       // 2,097,152  (xb early)
  float* Wtg    = ws + 13680640;       // 2,097,152 ┐ -> Sg (4,194,304)
  float* pQg    = ws + 15777792;       // 2,097,152 ┘
  float* Ug     = ws + 17874944;       // 2,097,152
  float* Mqg    = ws + 19972096;       // 1,048,576
  float* Gtg    = ws + 21020672;       // 2,097,152

  u16* xb   = (u16*)obuf;      // x bf16 (dead after gemm1)
  u16* wqt  = (u16*)Wtg;       // w_qkvz^T bf16 (dead after gemm1)
  u16* Mhi  = (u16*)qkvc;
  u16* Mlo  = (u16*)(qkvc + 2097152);
  float* Bg = qkvraw;
  float* Sg = Wtg;
  u16* wot  = (u16*)qkvc;      // after scan_S (Mhi dead)
  u16* hb   = (u16*)khat;      // after make_MBG (khat dead)

  // 0) fused beta/g + x->bf16 cast (permuted staging layout)
  ba_gbeta_cast<<<T_, 256, 0, stream>>>(x, w_ba, a_log, dt_bias,
                                        gbuf, bbuf, xb);
  transpose_bf16<<<dim3(32, 96), 256, 0, stream>>>(w_qkvz, wqt, H_, QN_);
  // 1) qkv|z = x @ w_qkvz   (8-wave: 24 waves/CU)
  gemm_bf16_w8<<<768, 512, 0, stream>>>(xb, wqt, qkvraw, CD_, zbuf, VD_,
                                        CD_, T_, QN_, H_);
  // 2) fused conv + silu + k-l2norm
  conv_silu_k<<<T_, 512, 0, stream>>>(qkvraw, conv_w, conv_b, qkvc, khat);
  // 3) chunk-local precompute (parallel, 512 thr)
  chunk_prep<<<dim3(NC_, HV_), 512, 0, stream>>>(
      qkvc, khat, gbuf, bbuf, cgbuf, Wtg, Ug, Mqg, pQg);
  // 4) per-chunk transition/output operators (parallel, 1024 thr)
  make_MBG<<<dim3(NC_, HV_), 1024, 0, stream>>>(
      Wtg, pQg, Ug, Mqg, khat, cgbuf, Mhi, Mlo, Bg, Gtg);
  // 5) sequential state scan (128 blocks, M+B reg-prefetched)
  scan_S<<<128, 512, 0, stream>>>(Mhi, Mlo, Bg, Sg);
  // 6) w_o^T cast (Mhi region now dead)
  transpose_bf16<<<dim3(32, 32), 256, 0, stream>>>(w_o, wot, VD_, H_);
  // 7) per-chunk outputs + fused gated rmsnorm -> bf16 h (permuted)
  chunk_out<<<dim3(NC_, HV_), 256, 0, stream>>>(
      Mqg, Ug, Gtg, Sg, zbuf, norm_w, hb);
  // 8) out = h @ w_o  (64x64 8-wave: 512 blocks, 16 waves/CU)
  gemm_bf16_w8_64<<<512, 512, 0, stream>>>(hb, wot, out, VD_, T_, VD_, H_);
}